// Round 16
// baseline (255.087 us; speedup 1.0000x reference)
//
#include <hip/hip_runtime.h>

static inline int idiv(int a, int b) { return (a + b - 1) / b; }

// bijective XCD-chunk swizzle (8 XCDs)
__device__ __forceinline__ int swz8(int bid, int nb) {
    int q = nb >> 3, r = nb & 7;
    int x = bid & 7, c = bid >> 3;
    return (x < r ? x * (q + 1) : r * (q + 1) + (x - r) * q) + c;
}

__global__ void k_zero(float4* __restrict__ p, long n4) {
    long t = (long)blockIdx.x * blockDim.x + threadIdx.x;
    long stride = (long)gridDim.x * blockDim.x;
    for (; t < n4; t += stride) p[t] = make_float4(0.f, 0.f, 0.f, 0.f);
}

// ---- layer1 prep: up-run bounds + smaller-neighbor histogram ----
__global__ void k_prep1(const int* __restrict__ src, const int* __restrict__ dst,
                        int* __restrict__ ust, int* __restrict__ uen,
                        int* __restrict__ cntS, int E) {
    int e = blockIdx.x * blockDim.x + threadIdx.x;
    if (e >= E) return;
    int s = src[e], d = dst[e];
    if (s >= d) return;
    atomicAdd(&cntS[d], 1);
    bool prevup = false; int ps = -1;
    if (e > 0) { ps = src[e - 1]; prevup = (ps < dst[e - 1]); }
    if (e == 0 || !prevup || ps != s) ust[s] = e;
    bool nextup = false; int ns = -1;
    if (e + 1 < E) { ns = src[e + 1]; nextup = (ns < dst[e + 1]); }
    if (e + 1 == E || !nextup || ns != s) uen[s] = e + 1;
}

__global__ void k_bounds2(const int* __restrict__ src, int* __restrict__ rs,
                          int* __restrict__ re, int E) {
    int e = blockIdx.x * blockDim.x + threadIdx.x;
    if (e >= E) return;
    int s = src[e];
    if (e == 0 || src[e - 1] != s) rs[s] = e;
    if (e + 1 == E || src[e + 1] != s) re[s] = e + 1;
}

__global__ void k_dinv2(const int* __restrict__ rs, const int* __restrict__ re,
                        float* __restrict__ dinv, int n) {
    int t = blockIdx.x * blockDim.x + threadIdx.x;
    if (t < n) {
        int deg = re[t] - rs[t];
        dinv[t] = (deg > 0) ? rsqrtf((float)deg) : 0.0f;
    }
}

__global__ void k_scan_blk(const int* __restrict__ cnt, int* __restrict__ offs,
                           int* __restrict__ blksum, int n) {
    __shared__ int ts[256];
    int blk = blockIdx.x;
    int tid = threadIdx.x;
    int i0 = blk * 1024 + tid * 4;
    int a0 = 0, a1 = 0, a2 = 0, a3 = 0;
    if (i0 + 3 < n) {
        int4 v = *(const int4*)&cnt[i0];
        a0 = v.x; a1 = v.y; a2 = v.z; a3 = v.w;
    } else {
        if (i0 + 0 < n) a0 = cnt[i0 + 0];
        if (i0 + 1 < n) a1 = cnt[i0 + 1];
        if (i0 + 2 < n) a2 = cnt[i0 + 2];
    }
    int tsum = a0 + a1 + a2 + a3;
    ts[tid] = tsum;
    __syncthreads();
    for (int off = 1; off < 256; off <<= 1) {
        int v = (tid >= off) ? ts[tid - off] : 0;
        __syncthreads();
        ts[tid] += v;
        __syncthreads();
    }
    int ex = ts[tid] - tsum;
    if (tid == 255) blksum[blk] = ts[255];
    int p0 = ex, p1 = ex + a0, p2 = p1 + a1, p3 = p2 + a2;
    if (i0 + 3 < n) {
        *(int4*)&offs[i0] = make_int4(p0, p1, p2, p3);
    } else {
        if (i0 + 0 < n) offs[i0 + 0] = p0;
        if (i0 + 1 < n) offs[i0 + 1] = p1;
        if (i0 + 2 < n) offs[i0 + 2] = p2;
    }
}

__global__ void k_scan_tot(int* __restrict__ blksum, int nblk) {
    __shared__ int s[1024];
    int tid = threadIdx.x;
    int v = (tid < nblk) ? blksum[tid] : 0;
    s[tid] = v;
    __syncthreads();
    for (int off = 1; off < 1024; off <<= 1) {
        int t = (tid >= off) ? s[tid - off] : 0;
        __syncthreads();
        s[tid] += t;
        __syncthreads();
    }
    if (tid < nblk) blksum[tid] = s[tid] - v;
}

__global__ void k_scan_add_dinv(int* __restrict__ offs, int* __restrict__ cursor,
                                const int* __restrict__ blksum, const int* __restrict__ cntS,
                                const int* __restrict__ ust, const int* __restrict__ uen,
                                float* __restrict__ dinv, int n) {
    int t = blockIdx.x * blockDim.x + threadIdx.x;
    if (t < n) {
        int v = offs[t] + blksum[t >> 10];
        offs[t] = v;
        cursor[t] = v;
        int deg = cntS[t] + uen[t] - ust[t];
        dinv[t] = (deg > 0) ? rsqrtf((float)deg) : 0.0f;
    }
}

__global__ void k_fillS(const int* __restrict__ src, const int* __restrict__ dst,
                        int* __restrict__ cursor, int* __restrict__ csr, int E) {
    int e = blockIdx.x * blockDim.x + threadIdx.x;
    if (e >= E) return;
    int s = src[e], d = dst[e];
    if (s < d) {
        int pos = atomicAdd(&cursor[d], 1);
        csr[pos] = s;
    }
}

// ---- gather1 (F=16): 4-lane group per node; shuffle-shared indices ----
__global__ void k_gather1v(const int* __restrict__ ust, const int* __restrict__ uen,
                           const int* __restrict__ dst1, const int* __restrict__ offsS,
                           const int* __restrict__ cntS, const int* __restrict__ csrS,
                           const float* __restrict__ dinv, const float* __restrict__ xin,
                           float* __restrict__ tx, int n) {
    int vb = swz8(blockIdx.x, gridDim.x);
    int t = vb * blockDim.x + threadIdx.x;
    int d = t >> 2, ln = t & 3, fo = ln << 2;
    if (d >= n) return;
    float ax = 0.f, ay = 0.f, az = 0.f, aw = 0.f;
    // up-run (larger nbrs from dst1)
    int e0 = ust[d], e1 = uen[d];
    for (int j = e0; j < e1; j += 4) {
        int myj = j + ln;
        int s = 0; float w = 0.f;
        if (myj < e1) { s = dst1[myj]; w = dinv[s]; }
#pragma unroll
        for (int k = 0; k < 4; k++) {
            if (j + k >= e1) break;
            int sk = __shfl(s, k, 4);
            float wk = __shfl(w, k, 4);
            float4 v = *(const float4*)&xin[((long)sk << 4) + fo];
            ax += wk * v.x; ay += wk * v.y; az += wk * v.z; aw += wk * v.w;
        }
    }
    // smaller nbrs from csrS
    int i0 = offsS[d], i1 = i0 + cntS[d];
    for (int j = i0; j < i1; j += 4) {
        int myj = j + ln;
        int s = 0; float w = 0.f;
        if (myj < i1) { s = csrS[myj]; w = dinv[s]; }
#pragma unroll
        for (int k = 0; k < 4; k++) {
            if (j + k >= i1) break;
            int sk = __shfl(s, k, 4);
            float wk = __shfl(w, k, 4);
            float4 v = *(const float4*)&xin[((long)sk << 4) + fo];
            ax += wk * v.x; ay += wk * v.y; az += wk * v.z; aw += wk * v.w;
        }
    }
    float wd = -dinv[d];
    *(float4*)&tx[((long)d << 4) + fo] = make_float4(wd * ax, wd * ay, wd * az, wd * aw);
}

// ---- gather2 (F=32): 8-lane group per node; shuffle-shared indices ----
__global__ void k_gather2v(const int* __restrict__ rs, const int* __restrict__ re,
                           const int* __restrict__ dst2, const float* __restrict__ dinv,
                           const float* __restrict__ xin, float* __restrict__ tx, int n) {
    int vb = swz8(blockIdx.x, gridDim.x);
    int t = vb * blockDim.x + threadIdx.x;
    int d = t >> 3, ln = t & 7, fo = ln << 2;
    if (d >= n) return;
    float ax = 0.f, ay = 0.f, az = 0.f, aw = 0.f;
    int j0 = rs[d], j1 = re[d];
    for (int j = j0; j < j1; j += 8) {
        int myj = j + ln;
        int s = 0; float w = 0.f;
        if (myj < j1) { s = dst2[myj]; w = dinv[s]; }
#pragma unroll
        for (int k = 0; k < 8; k++) {
            if (j + k >= j1) break;
            int sk = __shfl(s, k, 8);
            float wk = __shfl(w, k, 8);
            float4 v = *(const float4*)&xin[((long)sk << 5) + fo];
            ax += wk * v.x; ay += wk * v.y; az += wk * v.z; aw += wk * v.w;
        }
    }
    float wd = -dinv[d];
    *(float4*)&tx[((long)d << 5) + fo] = make_float4(wd * ax, wd * ay, wd * az, wd * aw);
}

// ---- layer1 dense+pool: 4 outputs/thread, float4 loads, atomicMax into hp[cl1[n]] ----
__global__ void k_cheb1_max(const float* __restrict__ x, const float* __restrict__ tx,
                            const float* __restrict__ W0, const float* __restrict__ W1,
                            const float* __restrict__ b, const int* __restrict__ cl,
                            float* __restrict__ hp, int N) {
    int t = blockIdx.x * blockDim.x + threadIdx.x;
    int n = t >> 3, jj = (t & 7) << 2;
    if (n >= N) return;
    const float4* xr = (const float4*)(x + (long)n * 16);
    const float4* tr = (const float4*)(tx + (long)n * 16);
    float4 bv = *(const float4*)(b + jj);
    float a0 = bv.x, a1 = bv.y, a2 = bv.z, a3 = bv.w;
#pragma unroll
    for (int k4 = 0; k4 < 4; k4++) {
        float4 xv = xr[k4];
        float4 tv = tr[k4];
        float xs[4] = {xv.x, xv.y, xv.z, xv.w};
        float ts[4] = {tv.x, tv.y, tv.z, tv.w};
#pragma unroll
        for (int c = 0; c < 4; c++) {
            int k = k4 * 4 + c;
            float4 w0 = *(const float4*)(W0 + k * 32 + jj);
            float4 w1 = *(const float4*)(W1 + k * 32 + jj);
            a0 += xs[c] * w0.x + ts[c] * w1.x;
            a1 += xs[c] * w0.y + ts[c] * w1.y;
            a2 += xs[c] * w0.z + ts[c] * w1.z;
            a3 += xs[c] * w0.w + ts[c] * w1.w;
        }
    }
    long o = ((long)cl[n] << 5) + jj;   // relu >= 0 -> int-punned max on zero-init exact
    atomicMax((int*)&hp[o + 0], __float_as_int(fmaxf(a0, 0.f)));
    atomicMax((int*)&hp[o + 1], __float_as_int(fmaxf(a1, 0.f)));
    atomicMax((int*)&hp[o + 2], __float_as_int(fmaxf(a2, 0.f)));
    atomicMax((int*)&hp[o + 3], __float_as_int(fmaxf(a3, 0.f)));
}

// ---- layer2 dense+pool: 4 outputs/thread, atomicMax into h3[cl2[n]] ----
__global__ void k_cheb2_max(const float* __restrict__ xp, const float* __restrict__ tx,
                            const float* __restrict__ W0, const float* __restrict__ W1,
                            const float* __restrict__ b, const int* __restrict__ cl,
                            float* __restrict__ h3, int n1) {
    int t = blockIdx.x * blockDim.x + threadIdx.x;
    int n = t >> 4, jj = (t & 15) << 2;
    if (n >= n1) return;
    const float4* xr = (const float4*)(xp + (long)n * 32);
    const float4* tr = (const float4*)(tx + (long)n * 32);
    float4 bv = *(const float4*)(b + jj);
    float a0 = bv.x, a1 = bv.y, a2 = bv.z, a3 = bv.w;
#pragma unroll
    for (int k4 = 0; k4 < 8; k4++) {
        float4 xv = xr[k4];
        float4 tv = tr[k4];
        float xs[4] = {xv.x, xv.y, xv.z, xv.w};
        float ts[4] = {tv.x, tv.y, tv.z, tv.w};
#pragma unroll
        for (int c = 0; c < 4; c++) {
            int k = k4 * 4 + c;
            float4 w0 = *(const float4*)(W0 + k * 64 + jj);
            float4 w1 = *(const float4*)(W1 + k * 64 + jj);
            a0 += xs[c] * w0.x + ts[c] * w1.x;
            a1 += xs[c] * w0.y + ts[c] * w1.y;
            a2 += xs[c] * w0.z + ts[c] * w1.z;
            a3 += xs[c] * w0.w + ts[c] * w1.w;
        }
    }
    long o = ((long)cl[n] << 6) + jj;
    atomicMax((int*)&h3[o + 0], __float_as_int(fmaxf(a0, 0.f)));
    atomicMax((int*)&h3[o + 1], __float_as_int(fmaxf(a1, 0.f)));
    atomicMax((int*)&h3[o + 2], __float_as_int(fmaxf(a2, 0.f)));
    atomicMax((int*)&h3[o + 3], __float_as_int(fmaxf(a3, 0.f)));
}

// ---- gsum: linear float4 read of h3, LDS partials, per-graph accumulate ----
__global__ void k_gsum3(const float* __restrict__ h3, const int* __restrict__ batch,
                        float* __restrict__ gsum, float* __restrict__ gcnt, int n2) {
    __shared__ float s[8 * 64];
    __shared__ float sc[8];
    for (int i = threadIdx.x; i < 512; i += blockDim.x) s[i] = 0.0f;
    if (threadIdx.x < 8) sc[threadIdx.x] = 0.0f;
    __syncthreads();
    long total = (long)n2 * 16;  // float4 granularity
    long stride = (long)gridDim.x * blockDim.x;
    for (long t = (long)blockIdx.x * blockDim.x + threadIdx.x; t < total; t += stride) {
        int c = (int)(t >> 4), f4 = (int)(t & 15);
        float4 v = *(const float4*)&h3[((long)c << 6) + (f4 << 2)];
        int g = batch[c];
        atomicAdd(&s[g * 64 + f4 * 4 + 0], v.x);
        atomicAdd(&s[g * 64 + f4 * 4 + 1], v.y);
        atomicAdd(&s[g * 64 + f4 * 4 + 2], v.z);
        atomicAdd(&s[g * 64 + f4 * 4 + 3], v.w);
        if (f4 == 0) atomicAdd(&sc[g], 1.0f);
    }
    __syncthreads();
    for (int i = threadIdx.x; i < 512; i += blockDim.x) atomicAdd(&gsum[i], s[i]);
    if (threadIdx.x < 8) atomicAdd(&gcnt[threadIdx.x], sc[threadIdx.x]);
}

// ---- fc1+fc2 fused: each block recomputes g1 (L2-resident fcw1), then its out slice ----
__global__ void k_fc12(const float* __restrict__ gsum, const float* __restrict__ gcnt,
                       const float* __restrict__ fcw1, const float* __restrict__ fcb1,
                       const float* __restrict__ fcw2, const float* __restrict__ fcb2,
                       float* __restrict__ out, int OUT) {
    __shared__ float sm[8 * 64];
    __shared__ float sg[8 * 128];
    int tid = threadIdx.x;
    for (int i = tid; i < 512; i += blockDim.x) {
        float c = gcnt[i >> 6];
        sm[i] = (c > 0.0f) ? gsum[i] / c : 0.0f;
    }
    __syncthreads();
    for (int e = tid; e < 1024; e += blockDim.x) {
        int gi = e >> 7, j = e & 127;
        float acc = fcb1[j];
#pragma unroll 8
        for (int k = 0; k < 64; k++) acc += sm[gi * 64 + k] * fcw1[k * 128 + j];
        sg[e] = fmaxf(acc, 0.0f);
    }
    __syncthreads();
    int o = blockIdx.x * blockDim.x + tid;
    if (o >= OUT) return;
    float bias = fcb2[o];
    float acc[8];
#pragma unroll
    for (int gi = 0; gi < 8; gi++) acc[gi] = bias;
    for (int k = 0; k < 128; k++) {
        float w = fcw2[(long)k * OUT + o];
#pragma unroll
        for (int gi = 0; gi < 8; gi++) acc[gi] += sg[gi * 128 + k] * w;
    }
#pragma unroll
    for (int gi = 0; gi < 8; gi++) out[(long)gi * OUT + o] = acc[gi];
}

extern "C" void kernel_launch(void* const* d_in, const int* in_sizes, int n_in,
                              void* d_out, int out_size, void* d_ws, size_t ws_size,
                              hipStream_t stream) {
    const float* x    = (const float*)d_in[0];
    const float* W0a  = (const float*)d_in[1];
    const float* W1a  = (const float*)d_in[2];
    const float* b1   = (const float*)d_in[3];
    const float* W0b  = (const float*)d_in[4];
    const float* W1b  = (const float*)d_in[5];
    const float* b2   = (const float*)d_in[6];
    const float* fcw1 = (const float*)d_in[7];
    const float* fcb1 = (const float*)d_in[8];
    const float* fcw2 = (const float*)d_in[9];
    const float* fcb2 = (const float*)d_in[10];
    const int* ei1    = (const int*)d_in[11];
    const int* cl1    = (const int*)d_in[12];
    const int* ei2    = (const int*)d_in[13];
    const int* cl2    = (const int*)d_in[14];
    const int* b3     = (const int*)d_in[15];

    const int N  = in_sizes[12];
    const int E1 = in_sizes[11] / 2;
    const int E2 = in_sizes[13] / 2;
    const int n1 = in_sizes[14];
    const int n2 = in_sizes[15];
    const int G  = 8;
    const int OUT = out_size / G;

    const int nmax = (N > n1) ? N : n1;

    // ---- ws: [zeroed: cntS|ust|uen|rs2|re2|hp|h3|small] [offs|cursor|csr|dinv|blk|txA]
    auto rnd = [](size_t b) { return (b + 255) & ~(size_t)255; };
    size_t cntB  = rnd((size_t)N * 4);
    size_t ustB  = rnd((size_t)N * 4);
    size_t uenB  = rnd((size_t)N * 4);
    size_t rs2B  = rnd((size_t)n1 * 4);
    size_t re2B  = rnd((size_t)n1 * 4);
    size_t hpB   = rnd((size_t)n1 * 32 * 4);
    size_t h3B   = rnd((size_t)n2 * 64 * 4);
    size_t smlB  = rnd((512 + 8) * 4);
    size_t offB  = rnd((size_t)N * 4);
    size_t curB  = rnd((size_t)N * 4);
    size_t csrB  = rnd((size_t)(E1 / 2 + 64) * 4);
    size_t dinvB = rnd((size_t)nmax * 4);
    size_t blkB  = rnd((size_t)1024 * 4);

    char* base = (char*)d_ws;
    char* p = base;
    int*   cntS   = (int*)p;           p += cntB;
    int*   ust    = (int*)p;           p += ustB;
    int*   uen    = (int*)p;           p += uenB;
    int*   rs2    = (int*)p;           p += rs2B;
    int*   re2    = (int*)p;           p += re2B;
    float* hp     = (float*)p;         p += hpB;
    float* h3     = (float*)p;         p += h3B;
    float* gsum   = (float*)p;         p += smlB;
    float* gcnt   = gsum + 512;
    size_t zeroB  = (size_t)(p - base);
    int*   offsS  = (int*)p;           p += offB;
    int*   cursorS= (int*)p;           p += curB;
    int*   csrS   = (int*)p;           p += csrB;
    float* dinv   = (float*)p;         p += dinvB;
    int*   blksum = (int*)p;           p += blkB;
    float* txA    = (float*)p;
    (void)ws_size;

    dim3 B(256);
    {
        long n4 = (long)(zeroB / 16);
        int g = idiv((int)((n4 < 1048576) ? n4 : 1048576), 256);
        if (g < 1) g = 1;
        if (g > 4096) g = 4096;
        k_zero<<<g, B, 0, stream>>>((float4*)base, n4);
    }

    // ---- layer 1 ----
    {
        int nblk = idiv(N, 1024);
        k_prep1<<<idiv(E1, 256), B, 0, stream>>>(ei1, ei1 + E1, ust, uen, cntS, E1);
        k_scan_blk<<<nblk, B, 0, stream>>>(cntS, offsS, blksum, N);
        k_scan_tot<<<1, 1024, 0, stream>>>(blksum, nblk);
        k_scan_add_dinv<<<idiv(N, 256), B, 0, stream>>>(offsS, cursorS, blksum, cntS, ust, uen,
                                                        dinv, N);
        k_fillS<<<idiv(E1, 256), B, 0, stream>>>(ei1, ei1 + E1, cursorS, csrS, E1);
        k_gather1v<<<idiv(N * 4, 256), B, 0, stream>>>(ust, uen, ei1 + E1, offsS, cntS, csrS,
                                                       dinv, x, txA, N);
        k_cheb1_max<<<idiv(N * 8, 256), B, 0, stream>>>(x, txA, W0a, W1a, b1, cl1, hp, N);
    }

    // ---- layer 2 ----
    {
        k_bounds2<<<idiv(E2, 256), B, 0, stream>>>(ei2, rs2, re2, E2);
        k_dinv2<<<idiv(n1, 256), B, 0, stream>>>(rs2, re2, dinv, n1);
        k_gather2v<<<idiv(n1 * 8, 256), B, 0, stream>>>(rs2, re2, ei2 + E2, dinv, hp, txA, n1);
        k_cheb2_max<<<idiv(n1 * 16, 256), B, 0, stream>>>(hp, txA, W0b, W1b, b2, cl2, h3, n1);
    }

    // ---- readout ----
    int gb = idiv(n2 * 16, 256);
    if (gb > 256) gb = 256;
    k_gsum3<<<gb, B, 0, stream>>>(h3, b3, gsum, gcnt, n2);
    k_fc12<<<idiv(OUT, 256), B, 0, stream>>>(gsum, gcnt, fcw1, fcb1, fcw2, fcb2,
                                             (float*)d_out, OUT);
}

// Round 17
// 225.840 us; speedup vs baseline: 1.1295x; 1.1295x over previous
//
#include <hip/hip_runtime.h>

static inline int idiv(int a, int b) { return (a + b - 1) / b; }

// bijective XCD-chunk swizzle (8 XCDs)
__device__ __forceinline__ int swz8(int bid, int nb) {
    int q = nb >> 3, r = nb & 7;
    int x = bid & 7, c = bid >> 3;
    return (x < r ? x * (q + 1) : r * (q + 1) + (x - r) * q) + c;
}

__global__ void k_zero(float4* __restrict__ p, long n4) {
    long t = (long)blockIdx.x * blockDim.x + threadIdx.x;
    long stride = (long)gridDim.x * blockDim.x;
    for (; t < n4; t += stride) p[t] = make_float4(0.f, 0.f, 0.f, 0.f);
}

// ---- layer1 prep + members1 fused (independent index spaces, one launch) ----
__global__ void k_prep1m(const int* __restrict__ src, const int* __restrict__ dst,
                         int* __restrict__ ust, int* __restrict__ uen,
                         int* __restrict__ cntS, const int* __restrict__ cl,
                         int* __restrict__ mcnt, int* __restrict__ mem, int E, int N) {
    int e = blockIdx.x * blockDim.x + threadIdx.x;
    if (e < N) {  // members for node e
        int c = cl[e];
        int slot = atomicAdd(&mcnt[c], 1);
        if (slot < 2) mem[2 * c + slot] = e;
    }
    if (e >= E) return;
    int s = src[e], d = dst[e];
    if (s >= d) return;
    atomicAdd(&cntS[d], 1);
    bool prevup = false; int ps = -1;
    if (e > 0) { ps = src[e - 1]; prevup = (ps < dst[e - 1]); }
    if (e == 0 || !prevup || ps != s) ust[s] = e;
    bool nextup = false; int ns = -1;
    if (e + 1 < E) { ns = src[e + 1]; nextup = (ns < dst[e + 1]); }
    if (e + 1 == E || !nextup || ns != s) uen[s] = e + 1;
}

// ---- layer2 bounds + members2 fused ----
__global__ void k_bounds2m(const int* __restrict__ src, int* __restrict__ rs,
                           int* __restrict__ re, const int* __restrict__ cl,
                           int* __restrict__ mcnt, int* __restrict__ mem, int E, int n1) {
    int e = blockIdx.x * blockDim.x + threadIdx.x;
    if (e < n1) {
        int c = cl[e];
        int slot = atomicAdd(&mcnt[c], 1);
        if (slot < 2) mem[2 * c + slot] = e;
    }
    if (e >= E) return;
    int s = src[e];
    if (e == 0 || src[e - 1] != s) rs[s] = e;
    if (e + 1 == E || src[e + 1] != s) re[s] = e + 1;
}

__global__ void k_dinv2(const int* __restrict__ rs, const int* __restrict__ re,
                        float* __restrict__ dinv, int n) {
    int t = blockIdx.x * blockDim.x + threadIdx.x;
    if (t < n) {
        int deg = re[t] - rs[t];
        dinv[t] = (deg > 0) ? rsqrtf((float)deg) : 0.0f;
    }
}

__global__ void k_scan_blk(const int* __restrict__ cnt, int* __restrict__ offs,
                           int* __restrict__ blksum, int n) {
    __shared__ int ts[256];
    int blk = blockIdx.x;
    int tid = threadIdx.x;
    int i0 = blk * 1024 + tid * 4;
    int a0 = 0, a1 = 0, a2 = 0, a3 = 0;
    if (i0 + 3 < n) {
        int4 v = *(const int4*)&cnt[i0];
        a0 = v.x; a1 = v.y; a2 = v.z; a3 = v.w;
    } else {
        if (i0 + 0 < n) a0 = cnt[i0 + 0];
        if (i0 + 1 < n) a1 = cnt[i0 + 1];
        if (i0 + 2 < n) a2 = cnt[i0 + 2];
    }
    int tsum = a0 + a1 + a2 + a3;
    ts[tid] = tsum;
    __syncthreads();
    for (int off = 1; off < 256; off <<= 1) {
        int v = (tid >= off) ? ts[tid - off] : 0;
        __syncthreads();
        ts[tid] += v;
        __syncthreads();
    }
    int ex = ts[tid] - tsum;
    if (tid == 255) blksum[blk] = ts[255];
    int p0 = ex, p1 = ex + a0, p2 = p1 + a1, p3 = p2 + a2;
    if (i0 + 3 < n) {
        *(int4*)&offs[i0] = make_int4(p0, p1, p2, p3);
    } else {
        if (i0 + 0 < n) offs[i0 + 0] = p0;
        if (i0 + 1 < n) offs[i0 + 1] = p1;
        if (i0 + 2 < n) offs[i0 + 2] = p2;
    }
}

__global__ void k_scan_tot(int* __restrict__ blksum, int nblk) {
    __shared__ int s[1024];
    int tid = threadIdx.x;
    int v = (tid < nblk) ? blksum[tid] : 0;
    s[tid] = v;
    __syncthreads();
    for (int off = 1; off < 1024; off <<= 1) {
        int t = (tid >= off) ? s[tid - off] : 0;
        __syncthreads();
        s[tid] += t;
        __syncthreads();
    }
    if (tid < nblk) blksum[tid] = s[tid] - v;
}

__global__ void k_scan_add_dinv(int* __restrict__ offs, int* __restrict__ cursor,
                                const int* __restrict__ blksum, const int* __restrict__ cntS,
                                const int* __restrict__ ust, const int* __restrict__ uen,
                                float* __restrict__ dinv, int n) {
    int t = blockIdx.x * blockDim.x + threadIdx.x;
    if (t < n) {
        int v = offs[t] + blksum[t >> 10];
        offs[t] = v;
        cursor[t] = v;
        int deg = cntS[t] + uen[t] - ust[t];
        dinv[t] = (deg > 0) ? rsqrtf((float)deg) : 0.0f;
    }
}

__global__ void k_fillS(const int* __restrict__ src, const int* __restrict__ dst,
                        int* __restrict__ cursor, int* __restrict__ csr, int E) {
    int e = blockIdx.x * blockDim.x + threadIdx.x;
    if (e >= E) return;
    int s = src[e], d = dst[e];
    if (s < d) {
        int pos = atomicAdd(&cursor[d], 1);
        csr[pos] = s;
    }
}

// ---- gather1 (F=16): thread owns (node, 4-feature quarter); float4 row loads ----
__global__ void k_gather1v(const int* __restrict__ ust, const int* __restrict__ uen,
                           const int* __restrict__ dst1, const int* __restrict__ offsS,
                           const int* __restrict__ cntS, const int* __restrict__ csrS,
                           const float* __restrict__ dinv, const float* __restrict__ xin,
                           float* __restrict__ tx, int n) {
    int vb = swz8(blockIdx.x, gridDim.x);
    int t = vb * blockDim.x + threadIdx.x;
    int d = t >> 2, fo = (t & 3) << 2;
    if (d >= n) return;
    float ax = 0.f, ay = 0.f, az = 0.f, aw = 0.f;
    int e = ust[d], e1 = uen[d];
    for (; e + 1 < e1; e += 2) {
        int s0 = dst1[e], s1 = dst1[e + 1];
        float w0 = dinv[s0], w1 = dinv[s1];
        float4 v0 = *(const float4*)&xin[((long)s0 << 4) + fo];
        float4 v1 = *(const float4*)&xin[((long)s1 << 4) + fo];
        ax += w0 * v0.x + w1 * v1.x;
        ay += w0 * v0.y + w1 * v1.y;
        az += w0 * v0.z + w1 * v1.z;
        aw += w0 * v0.w + w1 * v1.w;
    }
    for (; e < e1; e++) {
        int s = dst1[e];
        float w = dinv[s];
        float4 v = *(const float4*)&xin[((long)s << 4) + fo];
        ax += w * v.x; ay += w * v.y; az += w * v.z; aw += w * v.w;
    }
    int i = offsS[d], i1 = i + cntS[d];
    for (; i + 1 < i1; i += 2) {
        int s0 = csrS[i], s1 = csrS[i + 1];
        float w0 = dinv[s0], w1 = dinv[s1];
        float4 v0 = *(const float4*)&xin[((long)s0 << 4) + fo];
        float4 v1 = *(const float4*)&xin[((long)s1 << 4) + fo];
        ax += w0 * v0.x + w1 * v1.x;
        ay += w0 * v0.y + w1 * v1.y;
        az += w0 * v0.z + w1 * v1.z;
        aw += w0 * v0.w + w1 * v1.w;
    }
    for (; i < i1; i++) {
        int s = csrS[i];
        float w = dinv[s];
        float4 v = *(const float4*)&xin[((long)s << 4) + fo];
        ax += w * v.x; ay += w * v.y; az += w * v.z; aw += w * v.w;
    }
    float wd = -dinv[d];
    *(float4*)&tx[((long)d << 4) + fo] = make_float4(wd * ax, wd * ay, wd * az, wd * aw);
}

// ---- gather2 (F=32): thread owns (node, 4-feature quarter) ----
__global__ void k_gather2v(const int* __restrict__ rs, const int* __restrict__ re,
                           const int* __restrict__ dst2, const float* __restrict__ dinv,
                           const float* __restrict__ xin, float* __restrict__ tx, int n) {
    int vb = swz8(blockIdx.x, gridDim.x);
    int t = vb * blockDim.x + threadIdx.x;
    int d = t >> 3, fo = (t & 7) << 2;
    if (d >= n) return;
    float ax = 0.f, ay = 0.f, az = 0.f, aw = 0.f;
    int j = rs[d], j1 = re[d];
    for (; j + 1 < j1; j += 2) {
        int s0 = dst2[j], s1 = dst2[j + 1];
        float w0 = dinv[s0], w1 = dinv[s1];
        float4 v0 = *(const float4*)&xin[((long)s0 << 5) + fo];
        float4 v1 = *(const float4*)&xin[((long)s1 << 5) + fo];
        ax += w0 * v0.x + w1 * v1.x;
        ay += w0 * v0.y + w1 * v1.y;
        az += w0 * v0.z + w1 * v1.z;
        aw += w0 * v0.w + w1 * v1.w;
    }
    for (; j < j1; j++) {
        int s = dst2[j];
        float w = dinv[s];
        float4 v = *(const float4*)&xin[((long)s << 5) + fo];
        ax += w * v.x; ay += w * v.y; az += w * v.z; aw += w * v.w;
    }
    float wd = -dinv[d];
    *(float4*)&tx[((long)d << 5) + fo] = make_float4(wd * ax, wd * ay, wd * az, wd * aw);
}

// ---- layer1 dense (16->32): 4 outputs/thread, float4 loads, plain store ----
__global__ void k_cheb1(const float* __restrict__ x, const float* __restrict__ tx,
                        const float* __restrict__ W0, const float* __restrict__ W1,
                        const float* __restrict__ b, float* __restrict__ h, int N) {
    int t = blockIdx.x * blockDim.x + threadIdx.x;
    int n = t >> 3, jj = (t & 7) << 2;
    if (n >= N) return;
    const float4* xr = (const float4*)(x + (long)n * 16);
    const float4* tr = (const float4*)(tx + (long)n * 16);
    float4 bv = *(const float4*)(b + jj);
    float a0 = bv.x, a1 = bv.y, a2 = bv.z, a3 = bv.w;
#pragma unroll
    for (int k4 = 0; k4 < 4; k4++) {
        float4 xv = xr[k4];
        float4 tv = tr[k4];
        float xs[4] = {xv.x, xv.y, xv.z, xv.w};
        float ts[4] = {tv.x, tv.y, tv.z, tv.w};
#pragma unroll
        for (int c = 0; c < 4; c++) {
            int k = k4 * 4 + c;
            float4 w0 = *(const float4*)(W0 + k * 32 + jj);
            float4 w1 = *(const float4*)(W1 + k * 32 + jj);
            a0 += xs[c] * w0.x + ts[c] * w1.x;
            a1 += xs[c] * w0.y + ts[c] * w1.y;
            a2 += xs[c] * w0.z + ts[c] * w1.z;
            a3 += xs[c] * w0.w + ts[c] * w1.w;
        }
    }
    *(float4*)(h + ((long)n << 5) + jj) =
        make_float4(fmaxf(a0, 0.f), fmaxf(a1, 0.f), fmaxf(a2, 0.f), fmaxf(a3, 0.f));
}

// ---- pool1 (F=32): float4, plain writes ----
__global__ void k_pool1(const int* __restrict__ mcnt, const int* __restrict__ mem,
                        const float* __restrict__ h, float* __restrict__ hp, int n1) {
    int t = blockIdx.x * blockDim.x + threadIdx.x;
    int c = t >> 3, fo = (t & 7) << 2;
    if (c >= n1) return;
    int m0 = mem[2 * c];
    float4 v = *(const float4*)&h[((long)m0 << 5) + fo];
    if (mcnt[c] > 1) {
        int m1 = mem[2 * c + 1];
        float4 u = *(const float4*)&h[((long)m1 << 5) + fo];
        v.x = fmaxf(v.x, u.x); v.y = fmaxf(v.y, u.y);
        v.z = fmaxf(v.z, u.z); v.w = fmaxf(v.w, u.w);
    }
    *(float4*)&hp[((long)c << 5) + fo] = v;
}

// ---- layer2 dense (32->64): 4 outputs/thread, plain store ----
__global__ void k_cheb2(const float* __restrict__ xp, const float* __restrict__ tx,
                        const float* __restrict__ W0, const float* __restrict__ W1,
                        const float* __restrict__ b, float* __restrict__ h2, int n1) {
    int t = blockIdx.x * blockDim.x + threadIdx.x;
    int n = t >> 4, jj = (t & 15) << 2;
    if (n >= n1) return;
    const float4* xr = (const float4*)(xp + (long)n * 32);
    const float4* tr = (const float4*)(tx + (long)n * 32);
    float4 bv = *(const float4*)(b + jj);
    float a0 = bv.x, a1 = bv.y, a2 = bv.z, a3 = bv.w;
#pragma unroll
    for (int k4 = 0; k4 < 8; k4++) {
        float4 xv = xr[k4];
        float4 tv = tr[k4];
        float xs[4] = {xv.x, xv.y, xv.z, xv.w};
        float ts[4] = {tv.x, tv.y, tv.z, tv.w};
#pragma unroll
        for (int c = 0; c < 4; c++) {
            int k = k4 * 4 + c;
            float4 w0 = *(const float4*)(W0 + k * 64 + jj);
            float4 w1 = *(const float4*)(W1 + k * 64 + jj);
            a0 += xs[c] * w0.x + ts[c] * w1.x;
            a1 += xs[c] * w0.y + ts[c] * w1.y;
            a2 += xs[c] * w0.z + ts[c] * w1.z;
            a3 += xs[c] * w0.w + ts[c] * w1.w;
        }
    }
    *(float4*)(h2 + ((long)n << 6) + jj) =
        make_float4(fmaxf(a0, 0.f), fmaxf(a1, 0.f), fmaxf(a2, 0.f), fmaxf(a3, 0.f));
}

// ---- gsum fused with pool2 (member-gather reads of h2) ----
__global__ void k_gsum2(const float* __restrict__ h2, const int* __restrict__ mcnt,
                        const int* __restrict__ mem, const int* __restrict__ batch,
                        float* __restrict__ gsum, float* __restrict__ gcnt, int n2) {
    __shared__ float s[8 * 64];
    __shared__ float sc[8];
    for (int i = threadIdx.x; i < 512; i += blockDim.x) s[i] = 0.0f;
    if (threadIdx.x < 8) sc[threadIdx.x] = 0.0f;
    __syncthreads();
    long total = (long)n2 * 64;
    long stride = (long)gridDim.x * blockDim.x;
    for (long t = (long)blockIdx.x * blockDim.x + threadIdx.x; t < total; t += stride) {
        int c = (int)(t >> 6), f = (int)(t & 63);
        int m0 = mem[2 * c];
        float v = h2[((long)m0 << 6) + f];
        if (mcnt[c] > 1) {
            int m1 = mem[2 * c + 1];
            v = fmaxf(v, h2[((long)m1 << 6) + f]);
        }
        int g = batch[c];
        atomicAdd(&s[g * 64 + f], v);
        if (f == 0) atomicAdd(&sc[g], 1.0f);
    }
    __syncthreads();
    for (int i = threadIdx.x; i < 512; i += blockDim.x) atomicAdd(&gsum[i], s[i]);
    if (threadIdx.x < 8) atomicAdd(&gcnt[threadIdx.x], sc[threadIdx.x]);
}

// ---- fc1+fc2 fused ----
__global__ void k_fc12(const float* __restrict__ gsum, const float* __restrict__ gcnt,
                       const float* __restrict__ fcw1, const float* __restrict__ fcb1,
                       const float* __restrict__ fcw2, const float* __restrict__ fcb2,
                       float* __restrict__ out, int OUT) {
    __shared__ float sm[8 * 64];
    __shared__ float sg[8 * 128];
    int tid = threadIdx.x;
    for (int i = tid; i < 512; i += blockDim.x) {
        float c = gcnt[i >> 6];
        sm[i] = (c > 0.0f) ? gsum[i] / c : 0.0f;
    }
    __syncthreads();
    for (int e = tid; e < 1024; e += blockDim.x) {
        int gi = e >> 7, j = e & 127;
        float acc = fcb1[j];
#pragma unroll 8
        for (int k = 0; k < 64; k++) acc += sm[gi * 64 + k] * fcw1[k * 128 + j];
        sg[e] = fmaxf(acc, 0.0f);
    }
    __syncthreads();
    int o = blockIdx.x * blockDim.x + tid;
    if (o >= OUT) return;
    float bias = fcb2[o];
    float acc[8];
#pragma unroll
    for (int gi = 0; gi < 8; gi++) acc[gi] = bias;
    for (int k = 0; k < 128; k++) {
        float w = fcw2[(long)k * OUT + o];
#pragma unroll
        for (int gi = 0; gi < 8; gi++) acc[gi] += sg[gi * 128 + k] * w;
    }
#pragma unroll
    for (int gi = 0; gi < 8; gi++) out[(long)gi * OUT + o] = acc[gi];
}

extern "C" void kernel_launch(void* const* d_in, const int* in_sizes, int n_in,
                              void* d_out, int out_size, void* d_ws, size_t ws_size,
                              hipStream_t stream) {
    const float* x    = (const float*)d_in[0];
    const float* W0a  = (const float*)d_in[1];
    const float* W1a  = (const float*)d_in[2];
    const float* b1   = (const float*)d_in[3];
    const float* W0b  = (const float*)d_in[4];
    const float* W1b  = (const float*)d_in[5];
    const float* b2   = (const float*)d_in[6];
    const float* fcw1 = (const float*)d_in[7];
    const float* fcb1 = (const float*)d_in[8];
    const float* fcw2 = (const float*)d_in[9];
    const float* fcb2 = (const float*)d_in[10];
    const int* ei1    = (const int*)d_in[11];
    const int* cl1    = (const int*)d_in[12];
    const int* ei2    = (const int*)d_in[13];
    const int* cl2    = (const int*)d_in[14];
    const int* b3     = (const int*)d_in[15];

    const int N  = in_sizes[12];
    const int E1 = in_sizes[11] / 2;
    const int E2 = in_sizes[13] / 2;
    const int n1 = in_sizes[14];
    const int n2 = in_sizes[15];
    const int G  = 8;
    const int OUT = out_size / G;

    const int nmax = (N > n1) ? N : n1;
    long hElems = (long)N * 32;
    if ((long)n1 * 64 > hElems) hElems = (long)n1 * 64;

    auto rnd = [](size_t b) { return (b + 255) & ~(size_t)255; };
    size_t cntB  = rnd((size_t)N * 4);
    size_t ustB  = rnd((size_t)N * 4);
    size_t uenB  = rnd((size_t)N * 4);
    size_t rs2B  = rnd((size_t)n1 * 4);
    size_t re2B  = rnd((size_t)n1 * 4);
    size_t mc1B  = rnd((size_t)n1 * 4);
    size_t mc2B  = rnd((size_t)n2 * 4);
    size_t smlB  = rnd((512 + 8) * 4);
    size_t offB  = rnd((size_t)N * 4);
    size_t curB  = rnd((size_t)N * 4);
    size_t csrB  = rnd((size_t)(E1 / 2 + 64) * 4);
    size_t dinvB = rnd((size_t)nmax * 4);
    size_t blkB  = rnd((size_t)1024 * 4);
    size_t mem1B = rnd((size_t)n1 * 2 * 4);
    size_t mem2B = rnd((size_t)n2 * 2 * 4);
    size_t hpB   = rnd((size_t)n1 * 32 * 4);
    size_t txB   = rnd((size_t)(((long)N * 16 > (long)n1 * 32) ? (long)N * 16 : (long)n1 * 32) * 4);

    char* base = (char*)d_ws;
    char* p = base;
    int*   cntS   = (int*)p;           p += cntB;
    int*   ust    = (int*)p;           p += ustB;
    int*   uen    = (int*)p;           p += uenB;
    int*   rs2    = (int*)p;           p += rs2B;
    int*   re2    = (int*)p;           p += re2B;
    int*   mcnt1  = (int*)p;           p += mc1B;
    int*   mcnt2  = (int*)p;           p += mc2B;
    float* gsum   = (float*)p;         p += smlB;
    float* gcnt   = gsum + 512;
    size_t zeroB  = (size_t)(p - base);
    int*   offsS  = (int*)p;           p += offB;
    int*   cursorS= (int*)p;           p += curB;
    int*   csrS   = (int*)p;           p += csrB;
    float* dinv   = (float*)p;         p += dinvB;
    int*   blksum = (int*)p;           p += blkB;
    int*   mem1   = (int*)p;           p += mem1B;
    int*   mem2   = (int*)p;           p += mem2B;
    float* hp     = (float*)p;         p += hpB;
    float* txA    = (float*)p;         p += txB;
    float* hbuf   = (float*)p;         // reused: h1 (N*32) then h2 (n1*64)
    (void)ws_size; (void)hElems;

    dim3 B(256);
    {
        long n4 = (long)(zeroB / 16);
        int g = idiv((int)((n4 < 1048576) ? n4 : 1048576), 256);
        if (g < 1) g = 1;
        if (g > 4096) g = 4096;
        k_zero<<<g, B, 0, stream>>>((float4*)base, n4);
    }

    // ---- layer 1 ----
    {
        int nblk = idiv(N, 1024);
        k_prep1m<<<idiv(E1, 256), B, 0, stream>>>(ei1, ei1 + E1, ust, uen, cntS,
                                                  cl1, mcnt1, mem1, E1, N);
        k_scan_blk<<<nblk, B, 0, stream>>>(cntS, offsS, blksum, N);
        k_scan_tot<<<1, 1024, 0, stream>>>(blksum, nblk);
        k_scan_add_dinv<<<idiv(N, 256), B, 0, stream>>>(offsS, cursorS, blksum, cntS, ust, uen,
                                                        dinv, N);
        k_fillS<<<idiv(E1, 256), B, 0, stream>>>(ei1, ei1 + E1, cursorS, csrS, E1);
        k_gather1v<<<idiv(N * 4, 256), B, 0, stream>>>(ust, uen, ei1 + E1, offsS, cntS, csrS,
                                                       dinv, x, txA, N);
        k_cheb1<<<idiv(N * 8, 256), B, 0, stream>>>(x, txA, W0a, W1a, b1, hbuf, N);
        k_pool1<<<idiv(n1 * 8, 256), B, 0, stream>>>(mcnt1, mem1, hbuf, hp, n1);
    }

    // ---- layer 2 ----
    {
        k_bounds2m<<<idiv(E2, 256), B, 0, stream>>>(ei2, rs2, re2, cl2, mcnt2, mem2, E2, n1);
        k_dinv2<<<idiv(n1, 256), B, 0, stream>>>(rs2, re2, dinv, n1);
        k_gather2v<<<idiv(n1 * 8, 256), B, 0, stream>>>(rs2, re2, ei2 + E2, dinv, hp, txA, n1);
        k_cheb2<<<idiv(n1 * 16, 256), B, 0, stream>>>(hp, txA, W0b, W1b, b2, hbuf, n1);
    }

    // ---- readout ----
    int gb = idiv(n2 * 64, 256);
    if (gb > 256) gb = 256;
    k_gsum2<<<gb, B, 0, stream>>>(hbuf, mcnt2, mem2, b3, gsum, gcnt, n2);
    k_fc12<<<idiv(OUT, 256), B, 0, stream>>>(gsum, gcnt, fcw1, fcb1, fcw2, fcb2,
                                             (float*)d_out, OUT);
}

// Round 18
// 214.209 us; speedup vs baseline: 1.1908x; 1.0543x over previous
//
#include <hip/hip_runtime.h>

static inline int idiv(int a, int b) { return (a + b - 1) / b; }

// bijective XCD-chunk swizzle (8 XCDs)
__device__ __forceinline__ int swz8(int bid, int nb) {
    int q = nb >> 3, r = nb & 7;
    int x = bid & 7, c = bid >> 3;
    return (x < r ? x * (q + 1) : r * (q + 1) + (x - r) * q) + c;
}

__global__ void k_zero(float4* __restrict__ p, long n4) {
    long t = (long)blockIdx.x * blockDim.x + threadIdx.x;
    long stride = (long)gridDim.x * blockDim.x;
    for (; t < n4; t += stride) p[t] = make_float4(0.f, 0.f, 0.f, 0.f);
}

// ---- layer1 prep + members1, 4 edges/thread (int4 src, scalar dst) ----
__global__ void k_prep1m(const int* __restrict__ src, const int* __restrict__ dst,
                         int* __restrict__ ust, int* __restrict__ uen,
                         int* __restrict__ cntS, const int* __restrict__ cl,
                         int* __restrict__ mcnt, int* __restrict__ mem, int E, int N) {
    int t = blockIdx.x * blockDim.x + threadIdx.x;
    int e0 = t << 2;
    // members for nodes e0..e0+3
    if (e0 < N) {
        if (e0 + 3 < N) {
            int4 c4 = *(const int4*)&cl[e0];
            int cc[4] = {c4.x, c4.y, c4.z, c4.w};
#pragma unroll
            for (int i = 0; i < 4; i++) {
                int slot = atomicAdd(&mcnt[cc[i]], 1);
                if (slot < 2) mem[2 * cc[i] + slot] = e0 + i;
            }
        } else {
            for (int i = 0; i < 4 && e0 + i < N; i++) {
                int c = cl[e0 + i];
                int slot = atomicAdd(&mcnt[c], 1);
                if (slot < 2) mem[2 * c + slot] = e0 + i;
            }
        }
    }
    if (e0 >= E) return;
    if (e0 + 3 < E) {
        int4 s4 = *(const int4*)&src[e0];
        int s[4] = {s4.x, s4.y, s4.z, s4.w};
        int d[4] = {dst[e0], dst[e0 + 1], dst[e0 + 2], dst[e0 + 3]};
        bool hasp = e0 > 0;
        int sp = hasp ? src[e0 - 1] : 0, dp = hasp ? dst[e0 - 1] : 0;
        bool hasn = e0 + 4 < E;
        int sn = hasn ? src[e0 + 4] : 0, dn = hasn ? dst[e0 + 4] : 0;
#pragma unroll
        for (int i = 0; i < 4; i++) {
            if (s[i] >= d[i]) continue;
            atomicAdd(&cntS[d[i]], 1);
            bool pvalid = (i > 0) ? true : hasp;
            int psi = (i > 0) ? s[i - 1] : sp, pdi = (i > 0) ? d[i - 1] : dp;
            bool prevup = pvalid && (psi < pdi);
            if (!pvalid || !prevup || psi != s[i]) ust[s[i]] = e0 + i;
            bool nvalid = (i < 3) ? true : hasn;
            int nsi = (i < 3) ? s[i + 1] : sn, ndi = (i < 3) ? d[i + 1] : dn;
            bool nextup = nvalid && (nsi < ndi);
            if (!nvalid || !nextup || nsi != s[i]) uen[s[i]] = e0 + i + 1;
        }
    } else {
        for (int i = 0; i < 4; i++) {
            int e = e0 + i;
            if (e >= E) break;
            int s = src[e], d = dst[e];
            if (s >= d) continue;
            atomicAdd(&cntS[d], 1);
            bool prevup = false; int ps = -1;
            if (e > 0) { ps = src[e - 1]; prevup = (ps < dst[e - 1]); }
            if (e == 0 || !prevup || ps != s) ust[s] = e;
            bool nextup = false; int ns = -1;
            if (e + 1 < E) { ns = src[e + 1]; nextup = (ns < dst[e + 1]); }
            if (e + 1 == E || !nextup || ns != s) uen[s] = e + 1;
        }
    }
}

// ---- layer2 bounds + members2, 4 edges/thread ----
__global__ void k_bounds2m(const int* __restrict__ src, int* __restrict__ rs,
                           int* __restrict__ re, const int* __restrict__ cl,
                           int* __restrict__ mcnt, int* __restrict__ mem, int E, int n1) {
    int t = blockIdx.x * blockDim.x + threadIdx.x;
    int e0 = t << 2;
    if (e0 < n1) {
        if (e0 + 3 < n1) {
            int4 c4 = *(const int4*)&cl[e0];
            int cc[4] = {c4.x, c4.y, c4.z, c4.w};
#pragma unroll
            for (int i = 0; i < 4; i++) {
                int slot = atomicAdd(&mcnt[cc[i]], 1);
                if (slot < 2) mem[2 * cc[i] + slot] = e0 + i;
            }
        } else {
            for (int i = 0; i < 4 && e0 + i < n1; i++) {
                int c = cl[e0 + i];
                int slot = atomicAdd(&mcnt[c], 1);
                if (slot < 2) mem[2 * c + slot] = e0 + i;
            }
        }
    }
    if (e0 >= E) return;
    if (e0 + 3 < E) {
        int4 s4 = *(const int4*)&src[e0];
        int s[4] = {s4.x, s4.y, s4.z, s4.w};
        int sp = (e0 > 0) ? src[e0 - 1] : -1;
        int sn = (e0 + 4 < E) ? src[e0 + 4] : -1;
        bool hasn = e0 + 4 < E;
#pragma unroll
        for (int i = 0; i < 4; i++) {
            int prev = (i > 0) ? s[i - 1] : sp;     // sp=-1 encodes "no prev" (ids >= 0)
            if (e0 + i == 0 || prev != s[i]) rs[s[i]] = e0 + i;
            bool nvalid = (i < 3) ? true : hasn;
            int nxt = (i < 3) ? s[i + 1] : sn;
            if (!nvalid || nxt != s[i]) re[s[i]] = e0 + i + 1;
        }
    } else {
        for (int i = 0; i < 4; i++) {
            int e = e0 + i;
            if (e >= E) break;
            int s = src[e];
            if (e == 0 || src[e - 1] != s) rs[s] = e;
            if (e + 1 == E || src[e + 1] != s) re[s] = e + 1;
        }
    }
}

__global__ void k_dinv2(const int* __restrict__ rs, const int* __restrict__ re,
                        float* __restrict__ dinv, int n) {
    int t = blockIdx.x * blockDim.x + threadIdx.x;
    if (t < n) {
        int deg = re[t] - rs[t];
        dinv[t] = (deg > 0) ? rsqrtf((float)deg) : 0.0f;
    }
}

__global__ void k_scan_blk(const int* __restrict__ cnt, int* __restrict__ offs,
                           int* __restrict__ blksum, int n) {
    __shared__ int ts[256];
    int blk = blockIdx.x;
    int tid = threadIdx.x;
    int i0 = blk * 1024 + tid * 4;
    int a0 = 0, a1 = 0, a2 = 0, a3 = 0;
    if (i0 + 3 < n) {
        int4 v = *(const int4*)&cnt[i0];
        a0 = v.x; a1 = v.y; a2 = v.z; a3 = v.w;
    } else {
        if (i0 + 0 < n) a0 = cnt[i0 + 0];
        if (i0 + 1 < n) a1 = cnt[i0 + 1];
        if (i0 + 2 < n) a2 = cnt[i0 + 2];
    }
    int tsum = a0 + a1 + a2 + a3;
    ts[tid] = tsum;
    __syncthreads();
    for (int off = 1; off < 256; off <<= 1) {
        int v = (tid >= off) ? ts[tid - off] : 0;
        __syncthreads();
        ts[tid] += v;
        __syncthreads();
    }
    int ex = ts[tid] - tsum;
    if (tid == 255) blksum[blk] = ts[255];
    int p0 = ex, p1 = ex + a0, p2 = p1 + a1, p3 = p2 + a2;
    if (i0 + 3 < n) {
        *(int4*)&offs[i0] = make_int4(p0, p1, p2, p3);
    } else {
        if (i0 + 0 < n) offs[i0 + 0] = p0;
        if (i0 + 1 < n) offs[i0 + 1] = p1;
        if (i0 + 2 < n) offs[i0 + 2] = p2;
    }
}

__global__ void k_scan_tot(int* __restrict__ blksum, int nblk) {
    __shared__ int s[1024];
    int tid = threadIdx.x;
    int v = (tid < nblk) ? blksum[tid] : 0;
    s[tid] = v;
    __syncthreads();
    for (int off = 1; off < 1024; off <<= 1) {
        int t = (tid >= off) ? s[tid - off] : 0;
        __syncthreads();
        s[tid] += t;
        __syncthreads();
    }
    if (tid < nblk) blksum[tid] = s[tid] - v;
}

__global__ void k_scan_add_dinv(int* __restrict__ offs, int* __restrict__ cursor,
                                const int* __restrict__ blksum, const int* __restrict__ cntS,
                                const int* __restrict__ ust, const int* __restrict__ uen,
                                float* __restrict__ dinv, int n) {
    int t = blockIdx.x * blockDim.x + threadIdx.x;
    if (t < n) {
        int v = offs[t] + blksum[t >> 10];
        offs[t] = v;
        cursor[t] = v;
        int deg = cntS[t] + uen[t] - ust[t];
        dinv[t] = (deg > 0) ? rsqrtf((float)deg) : 0.0f;
    }
}

// ---- fill small-CSR, 4 edges/thread ----
__global__ void k_fillS(const int* __restrict__ src, const int* __restrict__ dst,
                        int* __restrict__ cursor, int* __restrict__ csr, int E) {
    int t = blockIdx.x * blockDim.x + threadIdx.x;
    int e0 = t << 2;
    if (e0 >= E) return;
    if (e0 + 3 < E) {
        int4 s4 = *(const int4*)&src[e0];
        int s[4] = {s4.x, s4.y, s4.z, s4.w};
        int d[4] = {dst[e0], dst[e0 + 1], dst[e0 + 2], dst[e0 + 3]};
#pragma unroll
        for (int i = 0; i < 4; i++) {
            if (s[i] < d[i]) {
                int pos = atomicAdd(&cursor[d[i]], 1);
                csr[pos] = s[i];
            }
        }
    } else {
        for (int i = 0; i < 4; i++) {
            int e = e0 + i;
            if (e >= E) break;
            int s = src[e], d = dst[e];
            if (s < d) {
                int pos = atomicAdd(&cursor[d], 1);
                csr[pos] = s;
            }
        }
    }
}

// ---- gather1 (F=16): 4-lane group per node; shuffle-shared indices ----
__global__ void k_gather1v(const int* __restrict__ ust, const int* __restrict__ uen,
                           const int* __restrict__ dst1, const int* __restrict__ offsS,
                           const int* __restrict__ cntS, const int* __restrict__ csrS,
                           const float* __restrict__ dinv, const float* __restrict__ xin,
                           float* __restrict__ tx, int n) {
    int vb = swz8(blockIdx.x, gridDim.x);
    int t = vb * blockDim.x + threadIdx.x;
    int d = t >> 2, ln = t & 3, fo = ln << 2;
    if (d >= n) return;
    float ax = 0.f, ay = 0.f, az = 0.f, aw = 0.f;
    int e0 = ust[d], e1 = uen[d];
    for (int j = e0; j < e1; j += 4) {
        int myj = j + ln;
        int s = 0; float w = 0.f;
        if (myj < e1) { s = dst1[myj]; w = dinv[s]; }
#pragma unroll
        for (int k = 0; k < 4; k++) {
            if (j + k >= e1) break;
            int sk = __shfl(s, k, 4);
            float wk = __shfl(w, k, 4);
            float4 v = *(const float4*)&xin[((long)sk << 4) + fo];
            ax += wk * v.x; ay += wk * v.y; az += wk * v.z; aw += wk * v.w;
        }
    }
    int i0 = offsS[d], i1 = i0 + cntS[d];
    for (int j = i0; j < i1; j += 4) {
        int myj = j + ln;
        int s = 0; float w = 0.f;
        if (myj < i1) { s = csrS[myj]; w = dinv[s]; }
#pragma unroll
        for (int k = 0; k < 4; k++) {
            if (j + k >= i1) break;
            int sk = __shfl(s, k, 4);
            float wk = __shfl(w, k, 4);
            float4 v = *(const float4*)&xin[((long)sk << 4) + fo];
            ax += wk * v.x; ay += wk * v.y; az += wk * v.z; aw += wk * v.w;
        }
    }
    float wd = -dinv[d];
    *(float4*)&tx[((long)d << 4) + fo] = make_float4(wd * ax, wd * ay, wd * az, wd * aw);
}

// ---- gather2 (F=32): 8-lane group per node; shuffle-shared indices ----
__global__ void k_gather2v(const int* __restrict__ rs, const int* __restrict__ re,
                           const int* __restrict__ dst2, const float* __restrict__ dinv,
                           const float* __restrict__ xin, float* __restrict__ tx, int n) {
    int vb = swz8(blockIdx.x, gridDim.x);
    int t = vb * blockDim.x + threadIdx.x;
    int d = t >> 3, ln = t & 7, fo = ln << 2;
    if (d >= n) return;
    float ax = 0.f, ay = 0.f, az = 0.f, aw = 0.f;
    int j0 = rs[d], j1 = re[d];
    for (int j = j0; j < j1; j += 8) {
        int myj = j + ln;
        int s = 0; float w = 0.f;
        if (myj < j1) { s = dst2[myj]; w = dinv[s]; }
#pragma unroll
        for (int k = 0; k < 8; k++) {
            if (j + k >= j1) break;
            int sk = __shfl(s, k, 8);
            float wk = __shfl(w, k, 8);
            float4 v = *(const float4*)&xin[((long)sk << 5) + fo];
            ax += wk * v.x; ay += wk * v.y; az += wk * v.z; aw += wk * v.w;
        }
    }
    float wd = -dinv[d];
    *(float4*)&tx[((long)d << 5) + fo] = make_float4(wd * ax, wd * ay, wd * az, wd * aw);
}

// ---- layer1 dense (16->32): 4 outputs/thread, float4, plain store ----
__global__ void k_cheb1(const float* __restrict__ x, const float* __restrict__ tx,
                        const float* __restrict__ W0, const float* __restrict__ W1,
                        const float* __restrict__ b, float* __restrict__ h, int N) {
    int t = blockIdx.x * blockDim.x + threadIdx.x;
    int n = t >> 3, jj = (t & 7) << 2;
    if (n >= N) return;
    const float4* xr = (const float4*)(x + (long)n * 16);
    const float4* tr = (const float4*)(tx + (long)n * 16);
    float4 bv = *(const float4*)(b + jj);
    float a0 = bv.x, a1 = bv.y, a2 = bv.z, a3 = bv.w;
#pragma unroll
    for (int k4 = 0; k4 < 4; k4++) {
        float4 xv = xr[k4];
        float4 tv = tr[k4];
        float xs[4] = {xv.x, xv.y, xv.z, xv.w};
        float ts[4] = {tv.x, tv.y, tv.z, tv.w};
#pragma unroll
        for (int c = 0; c < 4; c++) {
            int k = k4 * 4 + c;
            float4 w0 = *(const float4*)(W0 + k * 32 + jj);
            float4 w1 = *(const float4*)(W1 + k * 32 + jj);
            a0 += xs[c] * w0.x + ts[c] * w1.x;
            a1 += xs[c] * w0.y + ts[c] * w1.y;
            a2 += xs[c] * w0.z + ts[c] * w1.z;
            a3 += xs[c] * w0.w + ts[c] * w1.w;
        }
    }
    *(float4*)(h + ((long)n << 5) + jj) =
        make_float4(fmaxf(a0, 0.f), fmaxf(a1, 0.f), fmaxf(a2, 0.f), fmaxf(a3, 0.f));
}

// ---- pool1 (F=32): float4, plain writes ----
__global__ void k_pool1(const int* __restrict__ mcnt, const int* __restrict__ mem,
                        const float* __restrict__ h, float* __restrict__ hp, int n1) {
    int t = blockIdx.x * blockDim.x + threadIdx.x;
    int c = t >> 3, fo = (t & 7) << 2;
    if (c >= n1) return;
    int m0 = mem[2 * c];
    float4 v = *(const float4*)&h[((long)m0 << 5) + fo];
    if (mcnt[c] > 1) {
        int m1 = mem[2 * c + 1];
        float4 u = *(const float4*)&h[((long)m1 << 5) + fo];
        v.x = fmaxf(v.x, u.x); v.y = fmaxf(v.y, u.y);
        v.z = fmaxf(v.z, u.z); v.w = fmaxf(v.w, u.w);
    }
    *(float4*)&hp[((long)c << 5) + fo] = v;
}

// ---- layer2 dense (32->64): 4 outputs/thread, plain store ----
__global__ void k_cheb2(const float* __restrict__ xp, const float* __restrict__ tx,
                        const float* __restrict__ W0, const float* __restrict__ W1,
                        const float* __restrict__ b, float* __restrict__ h2, int n1) {
    int t = blockIdx.x * blockDim.x + threadIdx.x;
    int n = t >> 4, jj = (t & 15) << 2;
    if (n >= n1) return;
    const float4* xr = (const float4*)(xp + (long)n * 32);
    const float4* tr = (const float4*)(tx + (long)n * 32);
    float4 bv = *(const float4*)(b + jj);
    float a0 = bv.x, a1 = bv.y, a2 = bv.z, a3 = bv.w;
#pragma unroll
    for (int k4 = 0; k4 < 8; k4++) {
        float4 xv = xr[k4];
        float4 tv = tr[k4];
        float xs[4] = {xv.x, xv.y, xv.z, xv.w};
        float ts[4] = {tv.x, tv.y, tv.z, tv.w};
#pragma unroll
        for (int c = 0; c < 4; c++) {
            int k = k4 * 4 + c;
            float4 w0 = *(const float4*)(W0 + k * 64 + jj);
            float4 w1 = *(const float4*)(W1 + k * 64 + jj);
            a0 += xs[c] * w0.x + ts[c] * w1.x;
            a1 += xs[c] * w0.y + ts[c] * w1.y;
            a2 += xs[c] * w0.z + ts[c] * w1.z;
            a3 += xs[c] * w0.w + ts[c] * w1.w;
        }
    }
    *(float4*)(h2 + ((long)n << 6) + jj) =
        make_float4(fmaxf(a0, 0.f), fmaxf(a1, 0.f), fmaxf(a2, 0.f), fmaxf(a3, 0.f));
}

// ---- gsum fused with pool2: float4 member-row reads ----
__global__ void k_gsum2(const float* __restrict__ h2, const int* __restrict__ mcnt,
                        const int* __restrict__ mem, const int* __restrict__ batch,
                        float* __restrict__ gsum, float* __restrict__ gcnt, int n2) {
    __shared__ float s[8 * 64];
    __shared__ float sc[8];
    for (int i = threadIdx.x; i < 512; i += blockDim.x) s[i] = 0.0f;
    if (threadIdx.x < 8) sc[threadIdx.x] = 0.0f;
    __syncthreads();
    long total = (long)n2 * 16;
    long stride = (long)gridDim.x * blockDim.x;
    for (long t = (long)blockIdx.x * blockDim.x + threadIdx.x; t < total; t += stride) {
        int c = (int)(t >> 4), fo = (int)(t & 15) << 2;
        int m0 = mem[2 * c];
        float4 v = *(const float4*)&h2[((long)m0 << 6) + fo];
        if (mcnt[c] > 1) {
            int m1 = mem[2 * c + 1];
            float4 u = *(const float4*)&h2[((long)m1 << 6) + fo];
            v.x = fmaxf(v.x, u.x); v.y = fmaxf(v.y, u.y);
            v.z = fmaxf(v.z, u.z); v.w = fmaxf(v.w, u.w);
        }
        int g = batch[c];
        atomicAdd(&s[g * 64 + fo + 0], v.x);
        atomicAdd(&s[g * 64 + fo + 1], v.y);
        atomicAdd(&s[g * 64 + fo + 2], v.z);
        atomicAdd(&s[g * 64 + fo + 3], v.w);
        if (fo == 0) atomicAdd(&sc[g], 1.0f);
    }
    __syncthreads();
    for (int i = threadIdx.x; i < 512; i += blockDim.x) atomicAdd(&gsum[i], s[i]);
    if (threadIdx.x < 8) atomicAdd(&gcnt[threadIdx.x], sc[threadIdx.x]);
}

// ---- fc1+fc2 fused ----
__global__ void k_fc12(const float* __restrict__ gsum, const float* __restrict__ gcnt,
                       const float* __restrict__ fcw1, const float* __restrict__ fcb1,
                       const float* __restrict__ fcw2, const float* __restrict__ fcb2,
                       float* __restrict__ out, int OUT) {
    __shared__ float sm[8 * 64];
    __shared__ float sg[8 * 128];
    int tid = threadIdx.x;
    for (int i = tid; i < 512; i += blockDim.x) {
        float c = gcnt[i >> 6];
        sm[i] = (c > 0.0f) ? gsum[i] / c : 0.0f;
    }
    __syncthreads();
    for (int e = tid; e < 1024; e += blockDim.x) {
        int gi = e >> 7, j = e & 127;
        float acc = fcb1[j];
#pragma unroll 8
        for (int k = 0; k < 64; k++) acc += sm[gi * 64 + k] * fcw1[k * 128 + j];
        sg[e] = fmaxf(acc, 0.0f);
    }
    __syncthreads();
    int o = blockIdx.x * blockDim.x + tid;
    if (o >= OUT) return;
    float bias = fcb2[o];
    float acc[8];
#pragma unroll
    for (int gi = 0; gi < 8; gi++) acc[gi] = bias;
    for (int k = 0; k < 128; k++) {
        float w = fcw2[(long)k * OUT + o];
#pragma unroll
        for (int gi = 0; gi < 8; gi++) acc[gi] += sg[gi * 128 + k] * w;
    }
#pragma unroll
    for (int gi = 0; gi < 8; gi++) out[(long)gi * OUT + o] = acc[gi];
}

extern "C" void kernel_launch(void* const* d_in, const int* in_sizes, int n_in,
                              void* d_out, int out_size, void* d_ws, size_t ws_size,
                              hipStream_t stream) {
    const float* x    = (const float*)d_in[0];
    const float* W0a  = (const float*)d_in[1];
    const float* W1a  = (const float*)d_in[2];
    const float* b1   = (const float*)d_in[3];
    const float* W0b  = (const float*)d_in[4];
    const float* W1b  = (const float*)d_in[5];
    const float* b2   = (const float*)d_in[6];
    const float* fcw1 = (const float*)d_in[7];
    const float* fcb1 = (const float*)d_in[8];
    const float* fcw2 = (const float*)d_in[9];
    const float* fcb2 = (const float*)d_in[10];
    const int* ei1    = (const int*)d_in[11];
    const int* cl1    = (const int*)d_in[12];
    const int* ei2    = (const int*)d_in[13];
    const int* cl2    = (const int*)d_in[14];
    const int* b3     = (const int*)d_in[15];

    const int N  = in_sizes[12];
    const int E1 = in_sizes[11] / 2;
    const int E2 = in_sizes[13] / 2;
    const int n1 = in_sizes[14];
    const int n2 = in_sizes[15];
    const int G  = 8;
    const int OUT = out_size / G;

    const int nmax = (N > n1) ? N : n1;

    auto rnd = [](size_t b) { return (b + 255) & ~(size_t)255; };
    size_t cntB  = rnd((size_t)N * 4);
    size_t ustB  = rnd((size_t)N * 4);
    size_t uenB  = rnd((size_t)N * 4);
    size_t rs2B  = rnd((size_t)n1 * 4);
    size_t re2B  = rnd((size_t)n1 * 4);
    size_t mc1B  = rnd((size_t)n1 * 4);
    size_t mc2B  = rnd((size_t)n2 * 4);
    size_t smlB  = rnd((512 + 8) * 4);
    size_t offB  = rnd((size_t)N * 4);
    size_t curB  = rnd((size_t)N * 4);
    size_t csrB  = rnd((size_t)(E1 / 2 + 64) * 4);
    size_t dinvB = rnd((size_t)nmax * 4);
    size_t blkB  = rnd((size_t)1024 * 4);
    size_t mem1B = rnd((size_t)n1 * 2 * 4);
    size_t mem2B = rnd((size_t)n2 * 2 * 4);
    size_t hpB   = rnd((size_t)n1 * 32 * 4);
    size_t txB   = rnd((size_t)(((long)N * 16 > (long)n1 * 32) ? (long)N * 16 : (long)n1 * 32) * 4);

    char* base = (char*)d_ws;
    char* p = base;
    int*   cntS   = (int*)p;           p += cntB;
    int*   ust    = (int*)p;           p += ustB;
    int*   uen    = (int*)p;           p += uenB;
    int*   rs2    = (int*)p;           p += rs2B;
    int*   re2    = (int*)p;           p += re2B;
    int*   mcnt1  = (int*)p;           p += mc1B;
    int*   mcnt2  = (int*)p;           p += mc2B;
    float* gsum   = (float*)p;         p += smlB;
    float* gcnt   = gsum + 512;
    size_t zeroB  = (size_t)(p - base);
    int*   offsS  = (int*)p;           p += offB;
    int*   cursorS= (int*)p;           p += curB;
    int*   csrS   = (int*)p;           p += csrB;
    float* dinv   = (float*)p;         p += dinvB;
    int*   blksum = (int*)p;           p += blkB;
    int*   mem1   = (int*)p;           p += mem1B;
    int*   mem2   = (int*)p;           p += mem2B;
    float* hp     = (float*)p;         p += hpB;
    float* txA    = (float*)p;         p += txB;
    float* hbuf   = (float*)p;         // reused: h1 (N*32) then h2 (n1*64)
    (void)ws_size;

    dim3 B(256);
    {
        long n4 = (long)(zeroB / 16);
        int g = idiv((int)((n4 < 1048576) ? n4 : 1048576), 256);
        if (g < 1) g = 1;
        if (g > 4096) g = 4096;
        k_zero<<<g, B, 0, stream>>>((float4*)base, n4);
    }

    // ---- layer 1 ----
    {
        int nblk = idiv(N, 1024);
        int maxEN = (E1 > N) ? E1 : N;
        k_prep1m<<<idiv(maxEN, 1024), B, 0, stream>>>(ei1, ei1 + E1, ust, uen, cntS,
                                                      cl1, mcnt1, mem1, E1, N);
        k_scan_blk<<<nblk, B, 0, stream>>>(cntS, offsS, blksum, N);
        k_scan_tot<<<1, 1024, 0, stream>>>(blksum, nblk);
        k_scan_add_dinv<<<idiv(N, 256), B, 0, stream>>>(offsS, cursorS, blksum, cntS, ust, uen,
                                                        dinv, N);
        k_fillS<<<idiv(E1, 1024), B, 0, stream>>>(ei1, ei1 + E1, cursorS, csrS, E1);
        k_gather1v<<<idiv(N * 4, 256), B, 0, stream>>>(ust, uen, ei1 + E1, offsS, cntS, csrS,
                                                       dinv, x, txA, N);
        k_cheb1<<<idiv(N * 8, 256), B, 0, stream>>>(x, txA, W0a, W1a, b1, hbuf, N);
        k_pool1<<<idiv(n1 * 8, 256), B, 0, stream>>>(mcnt1, mem1, hbuf, hp, n1);
    }

    // ---- layer 2 ----
    {
        int maxEn = (E2 > n1) ? E2 : n1;
        k_bounds2m<<<idiv(maxEn, 1024), B, 0, stream>>>(ei2, rs2, re2, cl2, mcnt2, mem2, E2, n1);
        k_dinv2<<<idiv(n1, 256), B, 0, stream>>>(rs2, re2, dinv, n1);
        k_gather2v<<<idiv(n1 * 8, 256), B, 0, stream>>>(rs2, re2, ei2 + E2, dinv, hp, txA, n1);
        k_cheb2<<<idiv(n1 * 16, 256), B, 0, stream>>>(hp, txA, W0b, W1b, b2, hbuf, n1);
    }

    // ---- readout ----
    int gb = idiv(n2 * 16, 256);
    if (gb > 256) gb = 256;
    k_gsum2<<<gb, B, 0, stream>>>(hbuf, mcnt2, mem2, b3, gsum, gcnt, n2);
    k_fc12<<<idiv(OUT, 256), B, 0, stream>>>(gsum, gcnt, fcw1, fcb1, fcw2, fcb2,
                                             (float*)d_out, OUT);
}

// Round 19
// 212.906 us; speedup vs baseline: 1.1981x; 1.0061x over previous
//
#include <hip/hip_runtime.h>

static inline int idiv(int a, int b) { return (a + b - 1) / b; }

// bijective XCD-chunk swizzle (8 XCDs)
__device__ __forceinline__ int swz8(int bid, int nb) {
    int q = nb >> 3, r = nb & 7;
    int x = bid & 7, c = bid >> 3;
    return (x < r ? x * (q + 1) : r * (q + 1) + (x - r) * q) + c;
}

__global__ void k_zero(float4* __restrict__ p, long n4) {
    long t = (long)blockIdx.x * blockDim.x + threadIdx.x;
    long stride = (long)gridDim.x * blockDim.x;
    for (; t < n4; t += stride) p[t] = make_float4(0.f, 0.f, 0.f, 0.f);
}

// ---- layer1 prep + members1, 4 edges/thread ----
__global__ void k_prep1m(const int* __restrict__ src, const int* __restrict__ dst,
                         int* __restrict__ ust, int* __restrict__ uen,
                         int* __restrict__ cntS, const int* __restrict__ cl,
                         int* __restrict__ mcnt, int* __restrict__ mem, int E, int N) {
    int t = blockIdx.x * blockDim.x + threadIdx.x;
    int e0 = t << 2;
    if (e0 < N) {
        if (e0 + 3 < N) {
            int4 c4 = *(const int4*)&cl[e0];
            int cc[4] = {c4.x, c4.y, c4.z, c4.w};
#pragma unroll
            for (int i = 0; i < 4; i++) {
                int slot = atomicAdd(&mcnt[cc[i]], 1);
                if (slot < 2) mem[2 * cc[i] + slot] = e0 + i;
            }
        } else {
            for (int i = 0; i < 4 && e0 + i < N; i++) {
                int c = cl[e0 + i];
                int slot = atomicAdd(&mcnt[c], 1);
                if (slot < 2) mem[2 * c + slot] = e0 + i;
            }
        }
    }
    if (e0 >= E) return;
    if (e0 + 3 < E) {
        int4 s4 = *(const int4*)&src[e0];
        int s[4] = {s4.x, s4.y, s4.z, s4.w};
        int d[4] = {dst[e0], dst[e0 + 1], dst[e0 + 2], dst[e0 + 3]};
        bool hasp = e0 > 0;
        int sp = hasp ? src[e0 - 1] : 0, dp = hasp ? dst[e0 - 1] : 0;
        bool hasn = e0 + 4 < E;
        int sn = hasn ? src[e0 + 4] : 0, dn = hasn ? dst[e0 + 4] : 0;
#pragma unroll
        for (int i = 0; i < 4; i++) {
            if (s[i] >= d[i]) continue;
            atomicAdd(&cntS[d[i]], 1);
            bool pvalid = (i > 0) ? true : hasp;
            int psi = (i > 0) ? s[i - 1] : sp, pdi = (i > 0) ? d[i - 1] : dp;
            bool prevup = pvalid && (psi < pdi);
            if (!pvalid || !prevup || psi != s[i]) ust[s[i]] = e0 + i;
            bool nvalid = (i < 3) ? true : hasn;
            int nsi = (i < 3) ? s[i + 1] : sn, ndi = (i < 3) ? d[i + 1] : dn;
            bool nextup = nvalid && (nsi < ndi);
            if (!nvalid || !nextup || nsi != s[i]) uen[s[i]] = e0 + i + 1;
        }
    } else {
        for (int i = 0; i < 4; i++) {
            int e = e0 + i;
            if (e >= E) break;
            int s = src[e], d = dst[e];
            if (s >= d) continue;
            atomicAdd(&cntS[d], 1);
            bool prevup = false; int ps = -1;
            if (e > 0) { ps = src[e - 1]; prevup = (ps < dst[e - 1]); }
            if (e == 0 || !prevup || ps != s) ust[s] = e;
            bool nextup = false; int ns = -1;
            if (e + 1 < E) { ns = src[e + 1]; nextup = (ns < dst[e + 1]); }
            if (e + 1 == E || !nextup || ns != s) uen[s] = e + 1;
        }
    }
}

// ---- layer2 bounds + members2 + pool1 fused ----
__global__ void k_bounds2mp(const int* __restrict__ src, int* __restrict__ rs,
                            int* __restrict__ re, const int* __restrict__ cl,
                            int* __restrict__ mcnt2, int* __restrict__ mem2,
                            const int* __restrict__ mcnt1, const int* __restrict__ mem1,
                            const float* __restrict__ h, float* __restrict__ hp,
                            int E, int n1) {
    int t = blockIdx.x * blockDim.x + threadIdx.x;
    // pool1: t in [0, n1*8)
    if (t < n1 * 8) {
        int c = t >> 3, fo = (t & 7) << 2;
        int m0 = mem1[2 * c];
        float4 v = *(const float4*)&h[((long)m0 << 5) + fo];
        if (mcnt1[c] > 1) {
            int m1 = mem1[2 * c + 1];
            float4 u = *(const float4*)&h[((long)m1 << 5) + fo];
            v.x = fmaxf(v.x, u.x); v.y = fmaxf(v.y, u.y);
            v.z = fmaxf(v.z, u.z); v.w = fmaxf(v.w, u.w);
        }
        *(float4*)&hp[((long)c << 5) + fo] = v;
    }
    // members2: t in [0, n1)
    if (t < n1) {
        int c = cl[t];
        int slot = atomicAdd(&mcnt2[c], 1);
        if (slot < 2) mem2[2 * c + slot] = t;
    }
    // bounds2: 4 edges/thread
    int e0 = t << 2;
    if (e0 >= E) return;
    if (e0 + 3 < E) {
        int4 s4 = *(const int4*)&src[e0];
        int s[4] = {s4.x, s4.y, s4.z, s4.w};
        int sp = (e0 > 0) ? src[e0 - 1] : -1;
        int sn = (e0 + 4 < E) ? src[e0 + 4] : -1;
        bool hasn = e0 + 4 < E;
#pragma unroll
        for (int i = 0; i < 4; i++) {
            int prev = (i > 0) ? s[i - 1] : sp;
            if (e0 + i == 0 || prev != s[i]) rs[s[i]] = e0 + i;
            bool nvalid = (i < 3) ? true : hasn;
            int nxt = (i < 3) ? s[i + 1] : sn;
            if (!nvalid || nxt != s[i]) re[s[i]] = e0 + i + 1;
        }
    } else {
        for (int i = 0; i < 4; i++) {
            int e = e0 + i;
            if (e >= E) break;
            int s = src[e];
            if (e == 0 || src[e - 1] != s) rs[s] = e;
            if (e + 1 == E || src[e + 1] != s) re[s] = e + 1;
        }
    }
}

// ---- dinv2 + y2 = dinv2 * hp row (F=32) ----
__global__ void k_dinv2y(const int* __restrict__ rs, const int* __restrict__ re,
                         float* __restrict__ dinv, const float* __restrict__ hp,
                         float* __restrict__ y2, int n) {
    int t = blockIdx.x * blockDim.x + threadIdx.x;
    if (t >= n) return;
    int deg = re[t] - rs[t];
    float w = (deg > 0) ? rsqrtf((float)deg) : 0.0f;
    dinv[t] = w;
    const float4* hr = (const float4*)(hp + (long)t * 32);
    float4* yr = (float4*)(y2 + (long)t * 32);
#pragma unroll
    for (int i = 0; i < 8; i++) {
        float4 v = hr[i];
        yr[i] = make_float4(w * v.x, w * v.y, w * v.z, w * v.w);
    }
}

__global__ void k_scan_blk(const int* __restrict__ cnt, int* __restrict__ offs,
                           int* __restrict__ blksum, int n) {
    __shared__ int ts[256];
    int blk = blockIdx.x;
    int tid = threadIdx.x;
    int i0 = blk * 1024 + tid * 4;
    int a0 = 0, a1 = 0, a2 = 0, a3 = 0;
    if (i0 + 3 < n) {
        int4 v = *(const int4*)&cnt[i0];
        a0 = v.x; a1 = v.y; a2 = v.z; a3 = v.w;
    } else {
        if (i0 + 0 < n) a0 = cnt[i0 + 0];
        if (i0 + 1 < n) a1 = cnt[i0 + 1];
        if (i0 + 2 < n) a2 = cnt[i0 + 2];
    }
    int tsum = a0 + a1 + a2 + a3;
    ts[tid] = tsum;
    __syncthreads();
    for (int off = 1; off < 256; off <<= 1) {
        int v = (tid >= off) ? ts[tid - off] : 0;
        __syncthreads();
        ts[tid] += v;
        __syncthreads();
    }
    int ex = ts[tid] - tsum;
    if (tid == 255) blksum[blk] = ts[255];
    int p0 = ex, p1 = ex + a0, p2 = p1 + a1, p3 = p2 + a2;
    if (i0 + 3 < n) {
        *(int4*)&offs[i0] = make_int4(p0, p1, p2, p3);
    } else {
        if (i0 + 0 < n) offs[i0 + 0] = p0;
        if (i0 + 1 < n) offs[i0 + 1] = p1;
        if (i0 + 2 < n) offs[i0 + 2] = p2;
    }
}

// ---- scan finalize + dinv1 + y1 = dinv1 * x row (F=16); blksum scanned in-LDS ----
__global__ void k_scan_add_dinv_y(int* __restrict__ offs, int* __restrict__ cursor,
                                  const int* __restrict__ blksum, const int* __restrict__ cntS,
                                  const int* __restrict__ ust, const int* __restrict__ uen,
                                  float* __restrict__ dinv, const float* __restrict__ xin,
                                  float* __restrict__ y1, int n, int nblk) {
    __shared__ int s[128];
    __shared__ int orig[128];
    int tid = threadIdx.x;
    if (tid < 128) {
        int v = (tid < nblk) ? blksum[tid] : 0;
        s[tid] = v; orig[tid] = v;
    }
    __syncthreads();
    for (int off = 1; off < 128; off <<= 1) {
        int v = 0;
        if (tid < 128 && tid >= off) v = s[tid - off];
        __syncthreads();
        if (tid < 128) s[tid] += v;
        __syncthreads();
    }
    int t = blockIdx.x * blockDim.x + tid;
    if (t >= n) return;
    int blk = t >> 10;
    int base = s[blk] - orig[blk];  // exclusive prefix
    int v = offs[t] + base;
    offs[t] = v;
    cursor[t] = v;
    int deg = cntS[t] + uen[t] - ust[t];
    float w = (deg > 0) ? rsqrtf((float)deg) : 0.0f;
    dinv[t] = w;
    const float4* xr = (const float4*)(xin + (long)t * 16);
    float4* yr = (float4*)(y1 + (long)t * 16);
#pragma unroll
    for (int i = 0; i < 4; i++) {
        float4 u = xr[i];
        yr[i] = make_float4(w * u.x, w * u.y, w * u.z, w * u.w);
    }
}

// ---- fill small-CSR, 4 edges/thread ----
__global__ void k_fillS(const int* __restrict__ src, const int* __restrict__ dst,
                        int* __restrict__ cursor, int* __restrict__ csr, int E) {
    int t = blockIdx.x * blockDim.x + threadIdx.x;
    int e0 = t << 2;
    if (e0 >= E) return;
    if (e0 + 3 < E) {
        int4 s4 = *(const int4*)&src[e0];
        int s[4] = {s4.x, s4.y, s4.z, s4.w};
        int d[4] = {dst[e0], dst[e0 + 1], dst[e0 + 2], dst[e0 + 3]};
#pragma unroll
        for (int i = 0; i < 4; i++) {
            if (s[i] < d[i]) {
                int pos = atomicAdd(&cursor[d[i]], 1);
                csr[pos] = s[i];
            }
        }
    } else {
        for (int i = 0; i < 4; i++) {
            int e = e0 + i;
            if (e >= E) break;
            int s = src[e], d = dst[e];
            if (s < d) {
                int pos = atomicAdd(&cursor[d], 1);
                csr[pos] = s;
            }
        }
    }
}

// ---- gather1 (F=16): 4-lane group; y1 rows (pre-scaled); idx shuffle-shared ----
__global__ void k_gather1y(const int* __restrict__ ust, const int* __restrict__ uen,
                           const int* __restrict__ dst1, const int* __restrict__ offsS,
                           const int* __restrict__ cntS, const int* __restrict__ csrS,
                           const float* __restrict__ dinv, const float* __restrict__ y1,
                           float* __restrict__ tx, int n) {
    int vb = swz8(blockIdx.x, gridDim.x);
    int t = vb * blockDim.x + threadIdx.x;
    int d = t >> 2, ln = t & 3, fo = ln << 2;
    if (d >= n) return;
    float ax = 0.f, ay = 0.f, az = 0.f, aw = 0.f;
    int e0 = ust[d], e1 = uen[d];
    for (int j = e0; j < e1; j += 4) {
        int myj = j + ln;
        int s = (myj < e1) ? dst1[myj] : 0;
#pragma unroll
        for (int k = 0; k < 4; k++) {
            if (j + k >= e1) break;
            int sk = __shfl(s, k, 4);
            float4 v = *(const float4*)&y1[((long)sk << 4) + fo];
            ax += v.x; ay += v.y; az += v.z; aw += v.w;
        }
    }
    int i0 = offsS[d], i1 = i0 + cntS[d];
    for (int j = i0; j < i1; j += 4) {
        int myj = j + ln;
        int s = (myj < i1) ? csrS[myj] : 0;
#pragma unroll
        for (int k = 0; k < 4; k++) {
            if (j + k >= i1) break;
            int sk = __shfl(s, k, 4);
            float4 v = *(const float4*)&y1[((long)sk << 4) + fo];
            ax += v.x; ay += v.y; az += v.z; aw += v.w;
        }
    }
    float wd = -dinv[d];
    *(float4*)&tx[((long)d << 4) + fo] = make_float4(wd * ax, wd * ay, wd * az, wd * aw);
}

// ---- gather2 (F=32): 8-lane group; y2 rows (pre-scaled); idx shuffle-shared ----
__global__ void k_gather2y(const int* __restrict__ rs, const int* __restrict__ re,
                           const int* __restrict__ dst2, const float* __restrict__ dinv,
                           const float* __restrict__ y2, float* __restrict__ tx, int n) {
    int vb = swz8(blockIdx.x, gridDim.x);
    int t = vb * blockDim.x + threadIdx.x;
    int d = t >> 3, ln = t & 7, fo = ln << 2;
    if (d >= n) return;
    float ax = 0.f, ay = 0.f, az = 0.f, aw = 0.f;
    int j0 = rs[d], j1 = re[d];
    for (int j = j0; j < j1; j += 8) {
        int myj = j + ln;
        int s = (myj < j1) ? dst2[myj] : 0;
#pragma unroll
        for (int k = 0; k < 8; k++) {
            if (j + k >= j1) break;
            int sk = __shfl(s, k, 8);
            float4 v = *(const float4*)&y2[((long)sk << 5) + fo];
            ax += v.x; ay += v.y; az += v.z; aw += v.w;
        }
    }
    float wd = -dinv[d];
    *(float4*)&tx[((long)d << 5) + fo] = make_float4(wd * ax, wd * ay, wd * az, wd * aw);
}

// ---- layer1 dense (16->32): 4 outputs/thread, float4, plain store ----
__global__ void k_cheb1(const float* __restrict__ x, const float* __restrict__ tx,
                        const float* __restrict__ W0, const float* __restrict__ W1,
                        const float* __restrict__ b, float* __restrict__ h, int N) {
    int t = blockIdx.x * blockDim.x + threadIdx.x;
    int n = t >> 3, jj = (t & 7) << 2;
    if (n >= N) return;
    const float4* xr = (const float4*)(x + (long)n * 16);
    const float4* tr = (const float4*)(tx + (long)n * 16);
    float4 bv = *(const float4*)(b + jj);
    float a0 = bv.x, a1 = bv.y, a2 = bv.z, a3 = bv.w;
#pragma unroll
    for (int k4 = 0; k4 < 4; k4++) {
        float4 xv = xr[k4];
        float4 tv = tr[k4];
        float xs[4] = {xv.x, xv.y, xv.z, xv.w};
        float ts[4] = {tv.x, tv.y, tv.z, tv.w};
#pragma unroll
        for (int c = 0; c < 4; c++) {
            int k = k4 * 4 + c;
            float4 w0 = *(const float4*)(W0 + k * 32 + jj);
            float4 w1 = *(const float4*)(W1 + k * 32 + jj);
            a0 += xs[c] * w0.x + ts[c] * w1.x;
            a1 += xs[c] * w0.y + ts[c] * w1.y;
            a2 += xs[c] * w0.z + ts[c] * w1.z;
            a3 += xs[c] * w0.w + ts[c] * w1.w;
        }
    }
    *(float4*)(h + ((long)n << 5) + jj) =
        make_float4(fmaxf(a0, 0.f), fmaxf(a1, 0.f), fmaxf(a2, 0.f), fmaxf(a3, 0.f));
}

// ---- layer2 dense (32->64): 4 outputs/thread, plain store ----
__global__ void k_cheb2(const float* __restrict__ xp, const float* __restrict__ tx,
                        const float* __restrict__ W0, const float* __restrict__ W1,
                        const float* __restrict__ b, float* __restrict__ h2, int n1) {
    int t = blockIdx.x * blockDim.x + threadIdx.x;
    int n = t >> 4, jj = (t & 15) << 2;
    if (n >= n1) return;
    const float4* xr = (const float4*)(xp + (long)n * 32);
    const float4* tr = (const float4*)(tx + (long)n * 32);
    float4 bv = *(const float4*)(b + jj);
    float a0 = bv.x, a1 = bv.y, a2 = bv.z, a3 = bv.w;
#pragma unroll
    for (int k4 = 0; k4 < 8; k4++) {
        float4 xv = xr[k4];
        float4 tv = tr[k4];
        float xs[4] = {xv.x, xv.y, xv.z, xv.w};
        float ts[4] = {tv.x, tv.y, tv.z, tv.w};
#pragma unroll
        for (int c = 0; c < 4; c++) {
            int k = k4 * 4 + c;
            float4 w0 = *(const float4*)(W0 + k * 64 + jj);
            float4 w1 = *(const float4*)(W1 + k * 64 + jj);
            a0 += xs[c] * w0.x + ts[c] * w1.x;
            a1 += xs[c] * w0.y + ts[c] * w1.y;
            a2 += xs[c] * w0.z + ts[c] * w1.z;
            a3 += xs[c] * w0.w + ts[c] * w1.w;
        }
    }
    *(float4*)(h2 + ((long)n << 6) + jj) =
        make_float4(fmaxf(a0, 0.f), fmaxf(a1, 0.f), fmaxf(a2, 0.f), fmaxf(a3, 0.f));
}

// ---- gsum fused with pool2: float4 member-row reads ----
__global__ void k_gsum2(const float* __restrict__ h2, const int* __restrict__ mcnt,
                        const int* __restrict__ mem, const int* __restrict__ batch,
                        float* __restrict__ gsum, float* __restrict__ gcnt, int n2) {
    __shared__ float s[8 * 64];
    __shared__ float sc[8];
    for (int i = threadIdx.x; i < 512; i += blockDim.x) s[i] = 0.0f;
    if (threadIdx.x < 8) sc[threadIdx.x] = 0.0f;
    __syncthreads();
    long total = (long)n2 * 16;
    long stride = (long)gridDim.x * blockDim.x;
    for (long t = (long)blockIdx.x * blockDim.x + threadIdx.x; t < total; t += stride) {
        int c = (int)(t >> 4), fo = (int)(t & 15) << 2;
        int m0 = mem[2 * c];
        float4 v = *(const float4*)&h2[((long)m0 << 6) + fo];
        if (mcnt[c] > 1) {
            int m1 = mem[2 * c + 1];
            float4 u = *(const float4*)&h2[((long)m1 << 6) + fo];
            v.x = fmaxf(v.x, u.x); v.y = fmaxf(v.y, u.y);
            v.z = fmaxf(v.z, u.z); v.w = fmaxf(v.w, u.w);
        }
        int g = batch[c];
        atomicAdd(&s[g * 64 + fo + 0], v.x);
        atomicAdd(&s[g * 64 + fo + 1], v.y);
        atomicAdd(&s[g * 64 + fo + 2], v.z);
        atomicAdd(&s[g * 64 + fo + 3], v.w);
        if (fo == 0) atomicAdd(&sc[g], 1.0f);
    }
    __syncthreads();
    for (int i = threadIdx.x; i < 512; i += blockDim.x) atomicAdd(&gsum[i], s[i]);
    if (threadIdx.x < 8) atomicAdd(&gcnt[threadIdx.x], sc[threadIdx.x]);
}

// ---- fc1+fc2 fused ----
__global__ void k_fc12(const float* __restrict__ gsum, const float* __restrict__ gcnt,
                       const float* __restrict__ fcw1, const float* __restrict__ fcb1,
                       const float* __restrict__ fcw2, const float* __restrict__ fcb2,
                       float* __restrict__ out, int OUT) {
    __shared__ float sm[8 * 64];
    __shared__ float sg[8 * 128];
    int tid = threadIdx.x;
    for (int i = tid; i < 512; i += blockDim.x) {
        float c = gcnt[i >> 6];
        sm[i] = (c > 0.0f) ? gsum[i] / c : 0.0f;
    }
    __syncthreads();
    for (int e = tid; e < 1024; e += blockDim.x) {
        int gi = e >> 7, j = e & 127;
        float acc = fcb1[j];
#pragma unroll 8
        for (int k = 0; k < 64; k++) acc += sm[gi * 64 + k] * fcw1[k * 128 + j];
        sg[e] = fmaxf(acc, 0.0f);
    }
    __syncthreads();
    int o = blockIdx.x * blockDim.x + tid;
    if (o >= OUT) return;
    float bias = fcb2[o];
    float acc[8];
#pragma unroll
    for (int gi = 0; gi < 8; gi++) acc[gi] = bias;
    for (int k = 0; k < 128; k++) {
        float w = fcw2[(long)k * OUT + o];
#pragma unroll
        for (int gi = 0; gi < 8; gi++) acc[gi] += sg[gi * 128 + k] * w;
    }
#pragma unroll
    for (int gi = 0; gi < 8; gi++) out[(long)gi * OUT + o] = acc[gi];
}

extern "C" void kernel_launch(void* const* d_in, const int* in_sizes, int n_in,
                              void* d_out, int out_size, void* d_ws, size_t ws_size,
                              hipStream_t stream) {
    const float* x    = (const float*)d_in[0];
    const float* W0a  = (const float*)d_in[1];
    const float* W1a  = (const float*)d_in[2];
    const float* b1   = (const float*)d_in[3];
    const float* W0b  = (const float*)d_in[4];
    const float* W1b  = (const float*)d_in[5];
    const float* b2   = (const float*)d_in[6];
    const float* fcw1 = (const float*)d_in[7];
    const float* fcb1 = (const float*)d_in[8];
    const float* fcw2 = (const float*)d_in[9];
    const float* fcb2 = (const float*)d_in[10];
    const int* ei1    = (const int*)d_in[11];
    const int* cl1    = (const int*)d_in[12];
    const int* ei2    = (const int*)d_in[13];
    const int* cl2    = (const int*)d_in[14];
    const int* b3     = (const int*)d_in[15];

    const int N  = in_sizes[12];
    const int E1 = in_sizes[11] / 2;
    const int E2 = in_sizes[13] / 2;
    const int n1 = in_sizes[14];
    const int n2 = in_sizes[15];
    const int G  = 8;
    const int OUT = out_size / G;

    const int nmax = (N > n1) ? N : n1;

    auto rnd = [](size_t b) { return (b + 255) & ~(size_t)255; };
    size_t cntB  = rnd((size_t)N * 4);
    size_t ustB  = rnd((size_t)N * 4);
    size_t uenB  = rnd((size_t)N * 4);
    size_t rs2B  = rnd((size_t)n1 * 4);
    size_t re2B  = rnd((size_t)n1 * 4);
    size_t mc1B  = rnd((size_t)n1 * 4);
    size_t mc2B  = rnd((size_t)n2 * 4);
    size_t smlB  = rnd((512 + 8) * 4);
    size_t offB  = rnd((size_t)N * 4);
    size_t curB  = rnd((size_t)N * 4);
    size_t csrB  = rnd((size_t)(E1 / 2 + 64) * 4);
    size_t dinvB = rnd((size_t)nmax * 4);
    size_t blkB  = rnd((size_t)1024 * 4);
    size_t mem1B = rnd((size_t)n1 * 2 * 4);
    size_t mem2B = rnd((size_t)n2 * 2 * 4);
    size_t hpB   = rnd((size_t)n1 * 32 * 4);
    size_t txB   = rnd((size_t)(((long)N * 16 > (long)n1 * 32) ? (long)N * 16 : (long)n1 * 32) * 4);

    char* base = (char*)d_ws;
    char* p = base;
    int*   cntS   = (int*)p;           p += cntB;
    int*   ust    = (int*)p;           p += ustB;
    int*   uen    = (int*)p;           p += uenB;
    int*   rs2    = (int*)p;           p += rs2B;
    int*   re2    = (int*)p;           p += re2B;
    int*   mcnt1  = (int*)p;           p += mc1B;
    int*   mcnt2  = (int*)p;           p += mc2B;
    float* gsum   = (float*)p;         p += smlB;
    float* gcnt   = gsum + 512;
    size_t zeroB  = (size_t)(p - base);
    int*   offsS  = (int*)p;           p += offB;
    int*   cursorS= (int*)p;           p += curB;
    int*   csrS   = (int*)p;           p += csrB;
    float* dinv   = (float*)p;         p += dinvB;
    int*   blksum = (int*)p;           p += blkB;
    int*   mem1   = (int*)p;           p += mem1B;
    int*   mem2   = (int*)p;           p += mem2B;
    float* hp     = (float*)p;         p += hpB;
    float* txA    = (float*)p;         p += txB;
    float* hbuf   = (float*)p;         // phases: y1 (N*16) -> h1 (N*32) -> y2 (n1*32) -> h2 (n1*64)
    (void)ws_size;

    // hbuf phase aliases (liveness: y1 dead before h1 written; y2 dead before h2 written)
    float* y1 = hbuf;
    float* h1 = hbuf;
    float* y2 = hbuf;
    float* h2 = hbuf;

    dim3 B(256);
    {
        long n4 = (long)(zeroB / 16);
        int g = idiv((int)((n4 < 1048576) ? n4 : 1048576), 256);
        if (g < 1) g = 1;
        if (g > 4096) g = 4096;
        k_zero<<<g, B, 0, stream>>>((float4*)base, n4);
    }

    // ---- layer 1 ----
    {
        int nblk = idiv(N, 1024);
        int maxEN = (E1 > N) ? E1 : N;
        k_prep1m<<<idiv(maxEN, 1024), B, 0, stream>>>(ei1, ei1 + E1, ust, uen, cntS,
                                                      cl1, mcnt1, mem1, E1, N);
        k_scan_blk<<<nblk, B, 0, stream>>>(cntS, offsS, blksum, N);
        k_scan_add_dinv_y<<<idiv(N, 256), B, 0, stream>>>(offsS, cursorS, blksum, cntS, ust, uen,
                                                          dinv, x, y1, N, nblk);
        k_fillS<<<idiv(E1, 1024), B, 0, stream>>>(ei1, ei1 + E1, cursorS, csrS, E1);
        k_gather1y<<<idiv(N * 4, 256), B, 0, stream>>>(ust, uen, ei1 + E1, offsS, cntS, csrS,
                                                       dinv, y1, txA, N);
        k_cheb1<<<idiv(N * 8, 256), B, 0, stream>>>(x, txA, W0a, W1a, b1, h1, N);
    }

    // ---- layer 2 ----
    {
        int e4 = idiv(E2, 4);
        int maxT = (e4 > n1 * 8) ? e4 : n1 * 8;
        k_bounds2mp<<<idiv(maxT, 256), B, 0, stream>>>(ei2, rs2, re2, cl2, mcnt2, mem2,
                                                       mcnt1, mem1, h1, hp, E2, n1);
        k_dinv2y<<<idiv(n1, 256), B, 0, stream>>>(rs2, re2, dinv, hp, y2, n1);
        k_gather2y<<<idiv(n1 * 8, 256), B, 0, stream>>>(rs2, re2, ei2 + E2, dinv, y2, txA, n1);
        k_cheb2<<<idiv(n1 * 16, 256), B, 0, stream>>>(hp, txA, W0b, W1b, b2, h2, n1);
    }

    // ---- readout ----
    int gb = idiv(n2 * 16, 256);
    if (gb > 256) gb = 256;
    k_gsum2<<<gb, B, 0, stream>>>(h2, mcnt2, mem2, b3, gsum, gcnt, n2);
    k_fc12<<<idiv(OUT, 256), B, 0, stream>>>(gsum, gcnt, fcw1, fcb1, fcw2, fcb2,
                                             (float*)d_out, OUT);
}

// Round 22
// 212.866 us; speedup vs baseline: 1.1983x; 1.0002x over previous
//
#include <hip/hip_runtime.h>

static inline int idiv(int a, int b) { return (a + b - 1) / b; }

// bijective XCD-chunk swizzle (8 XCDs)
__device__ __forceinline__ int swz8(int bid, int nb) {
    int q = nb >> 3, r = nb & 7;
    int x = bid & 7, c = bid >> 3;
    return (x < r ? x * (q + 1) : r * (q + 1) + (x - r) * q) + c;
}

__global__ void k_zero(float4* __restrict__ p, long n4) {
    long t = (long)blockIdx.x * blockDim.x + threadIdx.x;
    long stride = (long)gridDim.x * blockDim.x;
    for (; t < n4; t += stride) p[t] = make_float4(0.f, 0.f, 0.f, 0.f);
}

// ---- layer1 prep + members1, 4 edges/thread ----
__global__ void k_prep1m(const int* __restrict__ src, const int* __restrict__ dst,
                         int* __restrict__ ust, int* __restrict__ uen,
                         int* __restrict__ cntS, const int* __restrict__ cl,
                         int* __restrict__ mcnt, int* __restrict__ mem, int E, int N) {
    int t = blockIdx.x * blockDim.x + threadIdx.x;
    int e0 = t << 2;
    if (e0 < N) {
        if (e0 + 3 < N) {
            int4 c4 = *(const int4*)&cl[e0];
            int cc[4] = {c4.x, c4.y, c4.z, c4.w};
#pragma unroll
            for (int i = 0; i < 4; i++) {
                int slot = atomicAdd(&mcnt[cc[i]], 1);
                if (slot < 2) mem[2 * cc[i] + slot] = e0 + i;
            }
        } else {
            for (int i = 0; i < 4 && e0 + i < N; i++) {
                int c = cl[e0 + i];
                int slot = atomicAdd(&mcnt[c], 1);
                if (slot < 2) mem[2 * c + slot] = e0 + i;
            }
        }
    }
    if (e0 >= E) return;
    if (e0 + 3 < E) {
        int4 s4 = *(const int4*)&src[e0];
        int s[4] = {s4.x, s4.y, s4.z, s4.w};
        int d[4] = {dst[e0], dst[e0 + 1], dst[e0 + 2], dst[e0 + 3]};
        bool hasp = e0 > 0;
        int sp = hasp ? src[e0 - 1] : 0, dp = hasp ? dst[e0 - 1] : 0;
        bool hasn = e0 + 4 < E;
        int sn = hasn ? src[e0 + 4] : 0, dn = hasn ? dst[e0 + 4] : 0;
#pragma unroll
        for (int i = 0; i < 4; i++) {
            if (s[i] >= d[i]) continue;
            atomicAdd(&cntS[d[i]], 1);
            bool pvalid = (i > 0) ? true : hasp;
            int psi = (i > 0) ? s[i - 1] : sp, pdi = (i > 0) ? d[i - 1] : dp;
            bool prevup = pvalid && (psi < pdi);
            if (!pvalid || !prevup || psi != s[i]) ust[s[i]] = e0 + i;
            bool nvalid = (i < 3) ? true : hasn;
            int nsi = (i < 3) ? s[i + 1] : sn, ndi = (i < 3) ? d[i + 1] : dn;
            bool nextup = nvalid && (nsi < ndi);
            if (!nvalid || !nextup || nsi != s[i]) uen[s[i]] = e0 + i + 1;
        }
    } else {
        for (int i = 0; i < 4; i++) {
            int e = e0 + i;
            if (e >= E) break;
            int s = src[e], d = dst[e];
            if (s >= d) continue;
            atomicAdd(&cntS[d], 1);
            bool prevup = false; int ps = -1;
            if (e > 0) { ps = src[e - 1]; prevup = (ps < dst[e - 1]); }
            if (e == 0 || !prevup || ps != s) ust[s] = e;
            bool nextup = false; int ns = -1;
            if (e + 1 < E) { ns = src[e + 1]; nextup = (ns < dst[e + 1]); }
            if (e + 1 == E || !nextup || ns != s) uen[s] = e + 1;
        }
    }
}

// ---- layer2 bounds + members2 + pool1 fused ----
__global__ void k_bounds2mp(const int* __restrict__ src, int* __restrict__ rs,
                            int* __restrict__ re, const int* __restrict__ cl,
                            int* __restrict__ mcnt2, int* __restrict__ mem2,
                            const int* __restrict__ mcnt1, const int* __restrict__ mem1,
                            const float* __restrict__ h, float* __restrict__ hp,
                            int E, int n1) {
    int t = blockIdx.x * blockDim.x + threadIdx.x;
    if (t < n1 * 8) {
        int c = t >> 3, fo = (t & 7) << 2;
        int m0 = mem1[2 * c];
        float4 v = *(const float4*)&h[((long)m0 << 5) + fo];
        if (mcnt1[c] > 1) {
            int m1 = mem1[2 * c + 1];
            float4 u = *(const float4*)&h[((long)m1 << 5) + fo];
            v.x = fmaxf(v.x, u.x); v.y = fmaxf(v.y, u.y);
            v.z = fmaxf(v.z, u.z); v.w = fmaxf(v.w, u.w);
        }
        *(float4*)&hp[((long)c << 5) + fo] = v;
    }
    if (t < n1) {
        int c = cl[t];
        int slot = atomicAdd(&mcnt2[c], 1);
        if (slot < 2) mem2[2 * c + slot] = t;
    }
    int e0 = t << 2;
    if (e0 >= E) return;
    if (e0 + 3 < E) {
        int4 s4 = *(const int4*)&src[e0];
        int s[4] = {s4.x, s4.y, s4.z, s4.w};
        int sp = (e0 > 0) ? src[e0 - 1] : -1;
        int sn = (e0 + 4 < E) ? src[e0 + 4] : -1;
        bool hasn = e0 + 4 < E;
#pragma unroll
        for (int i = 0; i < 4; i++) {
            int prev = (i > 0) ? s[i - 1] : sp;
            if (e0 + i == 0 || prev != s[i]) rs[s[i]] = e0 + i;
            bool nvalid = (i < 3) ? true : hasn;
            int nxt = (i < 3) ? s[i + 1] : sn;
            if (!nvalid || nxt != s[i]) re[s[i]] = e0 + i + 1;
        }
    } else {
        for (int i = 0; i < 4; i++) {
            int e = e0 + i;
            if (e >= E) break;
            int s = src[e];
            if (e == 0 || src[e - 1] != s) rs[s] = e;
            if (e + 1 == E || src[e + 1] != s) re[s] = e + 1;
        }
    }
}

// ---- dinv2 + y2 = dinv2 * hp row (F=32) ----
__global__ void k_dinv2y(const int* __restrict__ rs, const int* __restrict__ re,
                         float* __restrict__ dinv, const float* __restrict__ hp,
                         float* __restrict__ y2, int n) {
    int t = blockIdx.x * blockDim.x + threadIdx.x;
    if (t >= n) return;
    int deg = re[t] - rs[t];
    float w = (deg > 0) ? rsqrtf((float)deg) : 0.0f;
    dinv[t] = w;
    const float4* hr = (const float4*)(hp + (long)t * 32);
    float4* yr = (float4*)(y2 + (long)t * 32);
#pragma unroll
    for (int i = 0; i < 8; i++) {
        float4 v = hr[i];
        yr[i] = make_float4(w * v.x, w * v.y, w * v.z, w * v.w);
    }
}

__global__ void k_scan_blk(const int* __restrict__ cnt, int* __restrict__ offs,
                           int* __restrict__ blksum, int n) {
    __shared__ int ts[256];
    int blk = blockIdx.x;
    int tid = threadIdx.x;
    int i0 = blk * 1024 + tid * 4;
    int a0 = 0, a1 = 0, a2 = 0, a3 = 0;
    if (i0 + 3 < n) {
        int4 v = *(const int4*)&cnt[i0];
        a0 = v.x; a1 = v.y; a2 = v.z; a3 = v.w;
    } else {
        if (i0 + 0 < n) a0 = cnt[i0 + 0];
        if (i0 + 1 < n) a1 = cnt[i0 + 1];
        if (i0 + 2 < n) a2 = cnt[i0 + 2];
    }
    int tsum = a0 + a1 + a2 + a3;
    ts[tid] = tsum;
    __syncthreads();
    for (int off = 1; off < 256; off <<= 1) {
        int v = (tid >= off) ? ts[tid - off] : 0;
        __syncthreads();
        ts[tid] += v;
        __syncthreads();
    }
    int ex = ts[tid] - tsum;
    if (tid == 255) blksum[blk] = ts[255];
    int p0 = ex, p1 = ex + a0, p2 = p1 + a1, p3 = p2 + a2;
    if (i0 + 3 < n) {
        *(int4*)&offs[i0] = make_int4(p0, p1, p2, p3);
    } else {
        if (i0 + 0 < n) offs[i0 + 0] = p0;
        if (i0 + 1 < n) offs[i0 + 1] = p1;
        if (i0 + 2 < n) offs[i0 + 2] = p2;
    }
}

// ---- scan finalize + dinv1 + y1 = dinv1 * x row (F=16); blksum scanned in-LDS ----
__global__ void k_scan_add_dinv_y(int* __restrict__ offs, int* __restrict__ cursor,
                                  const int* __restrict__ blksum, const int* __restrict__ cntS,
                                  const int* __restrict__ ust, const int* __restrict__ uen,
                                  float* __restrict__ dinv, const float* __restrict__ xin,
                                  float* __restrict__ y1, int n, int nblk) {
    __shared__ int s[128];
    __shared__ int orig[128];
    int tid = threadIdx.x;
    if (tid < 128) {
        int v = (tid < nblk) ? blksum[tid] : 0;
        s[tid] = v; orig[tid] = v;
    }
    __syncthreads();
    for (int off = 1; off < 128; off <<= 1) {
        int v = 0;
        if (tid < 128 && tid >= off) v = s[tid - off];
        __syncthreads();
        if (tid < 128) s[tid] += v;
        __syncthreads();
    }
    int t = blockIdx.x * blockDim.x + tid;
    if (t >= n) return;
    int blk = t >> 10;
    int base = s[blk] - orig[blk];  // exclusive prefix
    int v = offs[t] + base;
    offs[t] = v;
    cursor[t] = v;
    int deg = cntS[t] + uen[t] - ust[t];
    float w = (deg > 0) ? rsqrtf((float)deg) : 0.0f;
    dinv[t] = w;
    const float4* xr = (const float4*)(xin + (long)t * 16);
    float4* yr = (float4*)(y1 + (long)t * 16);
#pragma unroll
    for (int i = 0; i < 4; i++) {
        float4 u = xr[i];
        yr[i] = make_float4(w * u.x, w * u.y, w * u.z, w * u.w);
    }
}

// ---- fill small-CSR, 4 edges/thread ----
__global__ void k_fillS(const int* __restrict__ src, const int* __restrict__ dst,
                        int* __restrict__ cursor, int* __restrict__ csr, int E) {
    int t = blockIdx.x * blockDim.x + threadIdx.x;
    int e0 = t << 2;
    if (e0 >= E) return;
    if (e0 + 3 < E) {
        int4 s4 = *(const int4*)&src[e0];
        int s[4] = {s4.x, s4.y, s4.z, s4.w};
        int d[4] = {dst[e0], dst[e0 + 1], dst[e0 + 2], dst[e0 + 3]};
#pragma unroll
        for (int i = 0; i < 4; i++) {
            if (s[i] < d[i]) {
                int pos = atomicAdd(&cursor[d[i]], 1);
                csr[pos] = s[i];
            }
        }
    } else {
        for (int i = 0; i < 4; i++) {
            int e = e0 + i;
            if (e >= E) break;
            int s = src[e], d = dst[e];
            if (s < d) {
                int pos = atomicAdd(&cursor[d], 1);
                csr[pos] = s;
            }
        }
    }
}

// ---- gather1 (F=16): 4-lane group; y1 rows (pre-scaled); idx shuffle-shared ----
__global__ void k_gather1y(const int* __restrict__ ust, const int* __restrict__ uen,
                           const int* __restrict__ dst1, const int* __restrict__ offsS,
                           const int* __restrict__ cntS, const int* __restrict__ csrS,
                           const float* __restrict__ dinv, const float* __restrict__ y1,
                           float* __restrict__ tx, int n) {
    int vb = swz8(blockIdx.x, gridDim.x);
    int t = vb * blockDim.x + threadIdx.x;
    int d = t >> 2, ln = t & 3, fo = ln << 2;
    if (d >= n) return;
    float ax = 0.f, ay = 0.f, az = 0.f, aw = 0.f;
    int e0 = ust[d], e1 = uen[d];
    for (int j = e0; j < e1; j += 4) {
        int myj = j + ln;
        int s = (myj < e1) ? dst1[myj] : 0;
#pragma unroll
        for (int k = 0; k < 4; k++) {
            if (j + k >= e1) break;
            int sk = __shfl(s, k, 4);
            float4 v = *(const float4*)&y1[((long)sk << 4) + fo];
            ax += v.x; ay += v.y; az += v.z; aw += v.w;
        }
    }
    int i0 = offsS[d], i1 = i0 + cntS[d];
    for (int j = i0; j < i1; j += 4) {
        int myj = j + ln;
        int s = (myj < i1) ? csrS[myj] : 0;
#pragma unroll
        for (int k = 0; k < 4; k++) {
            if (j + k >= i1) break;
            int sk = __shfl(s, k, 4);
            float4 v = *(const float4*)&y1[((long)sk << 4) + fo];
            ax += v.x; ay += v.y; az += v.z; aw += v.w;
        }
    }
    float wd = -dinv[d];
    *(float4*)&tx[((long)d << 4) + fo] = make_float4(wd * ax, wd * ay, wd * az, wd * aw);
}

// ---- gather2 (F=32): 8-lane group; y2 rows (pre-scaled); idx shuffle-shared ----
__global__ void k_gather2y(const int* __restrict__ rs, const int* __restrict__ re,
                           const int* __restrict__ dst2, const float* __restrict__ dinv,
                           const float* __restrict__ y2, float* __restrict__ tx, int n) {
    int vb = swz8(blockIdx.x, gridDim.x);
    int t = vb * blockDim.x + threadIdx.x;
    int d = t >> 3, ln = t & 7, fo = ln << 2;
    if (d >= n) return;
    float ax = 0.f, ay = 0.f, az = 0.f, aw = 0.f;
    int j0 = rs[d], j1 = re[d];
    for (int j = j0; j < j1; j += 8) {
        int myj = j + ln;
        int s = (myj < j1) ? dst2[myj] : 0;
#pragma unroll
        for (int k = 0; k < 8; k++) {
            if (j + k >= j1) break;
            int sk = __shfl(s, k, 8);
            float4 v = *(const float4*)&y2[((long)sk << 5) + fo];
            ax += v.x; ay += v.y; az += v.z; aw += v.w;
        }
    }
    float wd = -dinv[d];
    *(float4*)&tx[((long)d << 5) + fo] = make_float4(wd * ax, wd * ay, wd * az, wd * aw);
}

// ---- layer1 dense (16->32): 4 outputs/thread, float4, plain store ----
__global__ void k_cheb1(const float* __restrict__ x, const float* __restrict__ tx,
                        const float* __restrict__ W0, const float* __restrict__ W1,
                        const float* __restrict__ b, float* __restrict__ h, int N) {
    int t = blockIdx.x * blockDim.x + threadIdx.x;
    int n = t >> 3, jj = (t & 7) << 2;
    if (n >= N) return;
    const float4* xr = (const float4*)(x + (long)n * 16);
    const float4* tr = (const float4*)(tx + (long)n * 16);
    float4 bv = *(const float4*)(b + jj);
    float a0 = bv.x, a1 = bv.y, a2 = bv.z, a3 = bv.w;
#pragma unroll
    for (int k4 = 0; k4 < 4; k4++) {
        float4 xv = xr[k4];
        float4 tv = tr[k4];
        float xs[4] = {xv.x, xv.y, xv.z, xv.w};
        float ts[4] = {tv.x, tv.y, tv.z, tv.w};
#pragma unroll
        for (int c = 0; c < 4; c++) {
            int k = k4 * 4 + c;
            float4 w0 = *(const float4*)(W0 + k * 32 + jj);
            float4 w1 = *(const float4*)(W1 + k * 32 + jj);
            a0 += xs[c] * w0.x + ts[c] * w1.x;
            a1 += xs[c] * w0.y + ts[c] * w1.y;
            a2 += xs[c] * w0.z + ts[c] * w1.z;
            a3 += xs[c] * w0.w + ts[c] * w1.w;
        }
    }
    *(float4*)(h + ((long)n << 5) + jj) =
        make_float4(fmaxf(a0, 0.f), fmaxf(a1, 0.f), fmaxf(a2, 0.f), fmaxf(a3, 0.f));
}

// ---- layer2 dense (32->64): 4 outputs/thread, plain store ----
__global__ void k_cheb2(const float* __restrict__ xp, const float* __restrict__ tx,
                        const float* __restrict__ W0, const float* __restrict__ W1,
                        const float* __restrict__ b, float* __restrict__ h2, int n1) {
    int t = blockIdx.x * blockDim.x + threadIdx.x;
    int n = t >> 4, jj = (t & 15) << 2;
    if (n >= n1) return;
    const float4* xr = (const float4*)(xp + (long)n * 32);
    const float4* tr = (const float4*)(tx + (long)n * 32);
    float4 bv = *(const float4*)(b + jj);
    float a0 = bv.x, a1 = bv.y, a2 = bv.z, a3 = bv.w;
#pragma unroll
    for (int k4 = 0; k4 < 8; k4++) {
        float4 xv = xr[k4];
        float4 tv = tr[k4];
        float xs[4] = {xv.x, xv.y, xv.z, xv.w};
        float ts[4] = {tv.x, tv.y, tv.z, tv.w};
#pragma unroll
        for (int c = 0; c < 4; c++) {
            int k = k4 * 4 + c;
            float4 w0 = *(const float4*)(W0 + k * 64 + jj);
            float4 w1 = *(const float4*)(W1 + k * 64 + jj);
            a0 += xs[c] * w0.x + ts[c] * w1.x;
            a1 += xs[c] * w0.y + ts[c] * w1.y;
            a2 += xs[c] * w0.z + ts[c] * w1.z;
            a3 += xs[c] * w0.w + ts[c] * w1.w;
        }
    }
    *(float4*)(h2 + ((long)n << 6) + jj) =
        make_float4(fmaxf(a0, 0.f), fmaxf(a1, 0.f), fmaxf(a2, 0.f), fmaxf(a3, 0.f));
}

// ---- gsum fused with pool2: float4 member-row reads ----
__global__ void k_gsum2(const float* __restrict__ h2, const int* __restrict__ mcnt,
                        const int* __restrict__ mem, const int* __restrict__ batch,
                        float* __restrict__ gsum, float* __restrict__ gcnt, int n2) {
    __shared__ float s[8 * 64];
    __shared__ float sc[8];
    for (int i = threadIdx.x; i < 512; i += blockDim.x) s[i] = 0.0f;
    if (threadIdx.x < 8) sc[threadIdx.x] = 0.0f;
    __syncthreads();
    long total = (long)n2 * 16;
    long stride = (long)gridDim.x * blockDim.x;
    for (long t = (long)blockIdx.x * blockDim.x + threadIdx.x; t < total; t += stride) {
        int c = (int)(t >> 4), fo = (int)(t & 15) << 2;
        int m0 = mem[2 * c];
        float4 v = *(const float4*)&h2[((long)m0 << 6) + fo];
        if (mcnt[c] > 1) {
            int m1 = mem[2 * c + 1];
            float4 u = *(const float4*)&h2[((long)m1 << 6) + fo];
            v.x = fmaxf(v.x, u.x); v.y = fmaxf(v.y, u.y);
            v.z = fmaxf(v.z, u.z); v.w = fmaxf(v.w, u.w);
        }
        int g = batch[c];
        atomicAdd(&s[g * 64 + fo + 0], v.x);
        atomicAdd(&s[g * 64 + fo + 1], v.y);
        atomicAdd(&s[g * 64 + fo + 2], v.z);
        atomicAdd(&s[g * 64 + fo + 3], v.w);
        if (fo == 0) atomicAdd(&sc[g], 1.0f);
    }
    __syncthreads();
    for (int i = threadIdx.x; i < 512; i += blockDim.x) atomicAdd(&gsum[i], s[i]);
    if (threadIdx.x < 8) atomicAdd(&gcnt[threadIdx.x], sc[threadIdx.x]);
}

// ---- fc1+fc2 fused ----
__global__ void k_fc12(const float* __restrict__ gsum, const float* __restrict__ gcnt,
                       const float* __restrict__ fcw1, const float* __restrict__ fcb1,
                       const float* __restrict__ fcw2, const float* __restrict__ fcb2,
                       float* __restrict__ out, int OUT) {
    __shared__ float sm[8 * 64];
    __shared__ float sg[8 * 128];
    int tid = threadIdx.x;
    for (int i = tid; i < 512; i += blockDim.x) {
        float c = gcnt[i >> 6];
        sm[i] = (c > 0.0f) ? gsum[i] / c : 0.0f;
    }
    __syncthreads();
    for (int e = tid; e < 1024; e += blockDim.x) {
        int gi = e >> 7, j = e & 127;
        float acc = fcb1[j];
#pragma unroll 8
        for (int k = 0; k < 64; k++) acc += sm[gi * 64 + k] * fcw1[k * 128 + j];
        sg[e] = fmaxf(acc, 0.0f);
    }
    __syncthreads();
    int o = blockIdx.x * blockDim.x + tid;
    if (o >= OUT) return;
    float bias = fcb2[o];
    float acc[8];
#pragma unroll
    for (int gi = 0; gi < 8; gi++) acc[gi] = bias;
    for (int k = 0; k < 128; k++) {
        float w = fcw2[(long)k * OUT + o];
#pragma unroll
        for (int gi = 0; gi < 8; gi++) acc[gi] += sg[gi * 128 + k] * w;
    }
#pragma unroll
    for (int gi = 0; gi < 8; gi++) out[(long)gi * OUT + o] = acc[gi];
}

extern "C" void kernel_launch(void* const* d_in, const int* in_sizes, int n_in,
                              void* d_out, int out_size, void* d_ws, size_t ws_size,
                              hipStream_t stream) {
    const float* x    = (const float*)d_in[0];
    const float* W0a  = (const float*)d_in[1];
    const float* W1a  = (const float*)d_in[2];
    const float* b1   = (const float*)d_in[3];
    const float* W0b  = (const float*)d_in[4];
    const float* W1b  = (const float*)d_in[5];
    const float* b2   = (const float*)d_in[6];
    const float* fcw1 = (const float*)d_in[7];
    const float* fcb1 = (const float*)d_in[8];
    const float* fcw2 = (const float*)d_in[9];
    const float* fcb2 = (const float*)d_in[10];
    const int* ei1    = (const int*)d_in[11];
    const int* cl1    = (const int*)d_in[12];
    const int* ei2    = (const int*)d_in[13];
    const int* cl2    = (const int*)d_in[14];
    const int* b3     = (const int*)d_in[15];

    const int N  = in_sizes[12];
    const int E1 = in_sizes[11] / 2;
    const int E2 = in_sizes[13] / 2;
    const int n1 = in_sizes[14];
    const int n2 = in_sizes[15];
    const int G  = 8;
    const int OUT = out_size / G;

    const int nmax = (N > n1) ? N : n1;

    auto rnd = [](size_t b) { return (b + 255) & ~(size_t)255; };
    size_t cntB  = rnd((size_t)N * 4);
    size_t ustB  = rnd((size_t)N * 4);
    size_t uenB  = rnd((size_t)N * 4);
    size_t rs2B  = rnd((size_t)n1 * 4);
    size_t re2B  = rnd((size_t)n1 * 4);
    size_t mc1B  = rnd((size_t)n1 * 4);
    size_t mc2B  = rnd((size_t)n2 * 4);
    size_t smlB  = rnd((512 + 8) * 4);
    size_t offB  = rnd((size_t)N * 4);
    size_t curB  = rnd((size_t)N * 4);
    size_t csrB  = rnd((size_t)(E1 / 2 + 64) * 4);
    size_t dinvB = rnd((size_t)nmax * 4);
    size_t blkB  = rnd((size_t)1024 * 4);
    size_t mem1B = rnd((size_t)n1 * 2 * 4);
    size_t mem2B = rnd((size_t)n2 * 2 * 4);
    size_t hpB   = rnd((size_t)n1 * 32 * 4);
    size_t txB   = rnd((size_t)(((long)N * 16 > (long)n1 * 32) ? (long)N * 16 : (long)n1 * 32) * 4);

    char* base = (char*)d_ws;
    char* p = base;
    int*   cntS   = (int*)p;           p += cntB;
    int*   ust    = (int*)p;           p += ustB;
    int*   uen    = (int*)p;           p += uenB;
    int*   rs2    = (int*)p;           p += rs2B;
    int*   re2    = (int*)p;           p += re2B;
    int*   mcnt1  = (int*)p;           p += mc1B;
    int*   mcnt2  = (int*)p;           p += mc2B;
    float* gsum   = (float*)p;         p += smlB;
    float* gcnt   = gsum + 512;
    size_t zeroB  = (size_t)(p - base);
    int*   offsS  = (int*)p;           p += offB;
    int*   cursorS= (int*)p;           p += curB;
    int*   csrS   = (int*)p;           p += csrB;
    float* dinv   = (float*)p;         p += dinvB;
    int*   blksum = (int*)p;           p += blkB;
    int*   mem1   = (int*)p;           p += mem1B;
    int*   mem2   = (int*)p;           p += mem2B;
    float* hp     = (float*)p;         p += hpB;
    float* txA    = (float*)p;         p += txB;
    float* hbuf   = (float*)p;         // phases: y1 (N*16) -> h1 (N*32) -> y2 (n1*32) -> h2 (n1*64)
    (void)ws_size;

    float* y1 = hbuf;
    float* h1 = hbuf;
    float* y2 = hbuf;
    float* h2 = hbuf;

    dim3 B(256);
    {
        long n4 = (long)(zeroB / 16);
        int g = idiv((int)((n4 < 1048576) ? n4 : 1048576), 256);
        if (g < 1) g = 1;
        if (g > 4096) g = 4096;
        k_zero<<<g, B, 0, stream>>>((float4*)base, n4);
    }

    // ---- layer 1 ----
    {
        int nblk = idiv(N, 1024);
        int maxEN = (E1 > N) ? E1 : N;
        k_prep1m<<<idiv(maxEN, 1024), B, 0, stream>>>(ei1, ei1 + E1, ust, uen, cntS,
                                                      cl1, mcnt1, mem1, E1, N);
        k_scan_blk<<<nblk, B, 0, stream>>>(cntS, offsS, blksum, N);
        k_scan_add_dinv_y<<<idiv(N, 256), B, 0, stream>>>(offsS, cursorS, blksum, cntS, ust, uen,
                                                          dinv, x, y1, N, nblk);
        k_fillS<<<idiv(E1, 1024), B, 0, stream>>>(ei1, ei1 + E1, cursorS, csrS, E1);
        k_gather1y<<<idiv(N * 4, 256), B, 0, stream>>>(ust, uen, ei1 + E1, offsS, cntS, csrS,
                                                       dinv, y1, txA, N);
        k_cheb1<<<idiv(N * 8, 256), B, 0, stream>>>(x, txA, W0a, W1a, b1, h1, N);
    }

    // ---- layer 2 ----
    {
        int e4 = idiv(E2, 4);
        int maxT = (e4 > n1 * 8) ? e4 : n1 * 8;
        k_bounds2mp<<<idiv(maxT, 256), B, 0, stream>>>(ei2, rs2, re2, cl2, mcnt2, mem2,
                                                       mcnt1, mem1, h1, hp, E2, n1);
        k_dinv2y<<<idiv(n1, 256), B, 0, stream>>>(rs2, re2, dinv, hp, y2, n1);
        k_gather2y<<<idiv(n1 * 8, 256), B, 0, stream>>>(rs2, re2, ei2 + E2, dinv, y2, txA, n1);
        k_cheb2<<<idiv(n1 * 16, 256), B, 0, stream>>>(hp, txA, W0b, W1b, b2, h2, n1);
    }

    // ---- readout ----
    int gb = idiv(n2 * 16, 256);
    if (gb > 256) gb = 256;
    k_gsum2<<<gb, B, 0, stream>>>(h2, mcnt2, mem2, b3, gsum, gcnt, n2);
    k_fc12<<<idiv(OUT, 256), B, 0, stream>>>(gsum, gcnt, fcw1, fcb1, fcw2, fcb2,
                                             (float*)d_out, OUT);
}

// Round 23
// 212.129 us; speedup vs baseline: 1.2025x; 1.0035x over previous
//
#include <hip/hip_runtime.h>

static inline int idiv(int a, int b) { return (a + b - 1) / b; }

// bijective XCD-chunk swizzle (8 XCDs)
__device__ __forceinline__ int swz8(int bid, int nb) {
    int q = nb >> 3, r = nb & 7;
    int x = bid & 7, c = bid >> 3;
    return (x < r ? x * (q + 1) : r * (q + 1) + (x - r) * q) + c;
}

__global__ void k_zero(float4* __restrict__ p, long n4) {
    long t = (long)blockIdx.x * blockDim.x + threadIdx.x;
    long stride = (long)gridDim.x * blockDim.x;
    for (; t < n4; t += stride) p[t] = make_float4(0.f, 0.f, 0.f, 0.f);
}

// ---- layer1 prep + members1, 4 edges/thread ----
__global__ void k_prep1m(const int* __restrict__ src, const int* __restrict__ dst,
                         int* __restrict__ ust, int* __restrict__ uen,
                         int* __restrict__ cntS, const int* __restrict__ cl,
                         int* __restrict__ mcnt, int* __restrict__ mem, int E, int N) {
    int t = blockIdx.x * blockDim.x + threadIdx.x;
    int e0 = t << 2;
    if (e0 < N) {
        if (e0 + 3 < N) {
            int4 c4 = *(const int4*)&cl[e0];
            int cc[4] = {c4.x, c4.y, c4.z, c4.w};
#pragma unroll
            for (int i = 0; i < 4; i++) {
                int slot = atomicAdd(&mcnt[cc[i]], 1);
                if (slot < 2) mem[2 * cc[i] + slot] = e0 + i;
            }
        } else {
            for (int i = 0; i < 4 && e0 + i < N; i++) {
                int c = cl[e0 + i];
                int slot = atomicAdd(&mcnt[c], 1);
                if (slot < 2) mem[2 * c + slot] = e0 + i;
            }
        }
    }
    if (e0 >= E) return;
    if (e0 + 3 < E) {
        int4 s4 = *(const int4*)&src[e0];
        int s[4] = {s4.x, s4.y, s4.z, s4.w};
        int d[4] = {dst[e0], dst[e0 + 1], dst[e0 + 2], dst[e0 + 3]};
        bool hasp = e0 > 0;
        int sp = hasp ? src[e0 - 1] : 0, dp = hasp ? dst[e0 - 1] : 0;
        bool hasn = e0 + 4 < E;
        int sn = hasn ? src[e0 + 4] : 0, dn = hasn ? dst[e0 + 4] : 0;
#pragma unroll
        for (int i = 0; i < 4; i++) {
            if (s[i] >= d[i]) continue;
            atomicAdd(&cntS[d[i]], 1);
            bool pvalid = (i > 0) ? true : hasp;
            int psi = (i > 0) ? s[i - 1] : sp, pdi = (i > 0) ? d[i - 1] : dp;
            bool prevup = pvalid && (psi < pdi);
            if (!pvalid || !prevup || psi != s[i]) ust[s[i]] = e0 + i;
            bool nvalid = (i < 3) ? true : hasn;
            int nsi = (i < 3) ? s[i + 1] : sn, ndi = (i < 3) ? d[i + 1] : dn;
            bool nextup = nvalid && (nsi < ndi);
            if (!nvalid || !nextup || nsi != s[i]) uen[s[i]] = e0 + i + 1;
        }
    } else {
        for (int i = 0; i < 4; i++) {
            int e = e0 + i;
            if (e >= E) break;
            int s = src[e], d = dst[e];
            if (s >= d) continue;
            atomicAdd(&cntS[d], 1);
            bool prevup = false; int ps = -1;
            if (e > 0) { ps = src[e - 1]; prevup = (ps < dst[e - 1]); }
            if (e == 0 || !prevup || ps != s) ust[s] = e;
            bool nextup = false; int ns = -1;
            if (e + 1 < E) { ns = src[e + 1]; nextup = (ns < dst[e + 1]); }
            if (e + 1 == E || !nextup || ns != s) uen[s] = e + 1;
        }
    }
}

// ---- layer2 bounds + members2 + pool1 fused ----
__global__ void k_bounds2mp(const int* __restrict__ src, int* __restrict__ rs,
                            int* __restrict__ re, const int* __restrict__ cl,
                            int* __restrict__ mcnt2, int* __restrict__ mem2,
                            const int* __restrict__ mcnt1, const int* __restrict__ mem1,
                            const float* __restrict__ h, float* __restrict__ hp,
                            int E, int n1) {
    int t = blockIdx.x * blockDim.x + threadIdx.x;
    if (t < n1 * 8) {
        int c = t >> 3, fo = (t & 7) << 2;
        int m0 = mem1[2 * c];
        float4 v = *(const float4*)&h[((long)m0 << 5) + fo];
        if (mcnt1[c] > 1) {
            int m1 = mem1[2 * c + 1];
            float4 u = *(const float4*)&h[((long)m1 << 5) + fo];
            v.x = fmaxf(v.x, u.x); v.y = fmaxf(v.y, u.y);
            v.z = fmaxf(v.z, u.z); v.w = fmaxf(v.w, u.w);
        }
        *(float4*)&hp[((long)c << 5) + fo] = v;
    }
    if (t < n1) {
        int c = cl[t];
        int slot = atomicAdd(&mcnt2[c], 1);
        if (slot < 2) mem2[2 * c + slot] = t;
    }
    int e0 = t << 2;
    if (e0 >= E) return;
    if (e0 + 3 < E) {
        int4 s4 = *(const int4*)&src[e0];
        int s[4] = {s4.x, s4.y, s4.z, s4.w};
        int sp = (e0 > 0) ? src[e0 - 1] : -1;
        int sn = (e0 + 4 < E) ? src[e0 + 4] : -1;
        bool hasn = e0 + 4 < E;
#pragma unroll
        for (int i = 0; i < 4; i++) {
            int prev = (i > 0) ? s[i - 1] : sp;
            if (e0 + i == 0 || prev != s[i]) rs[s[i]] = e0 + i;
            bool nvalid = (i < 3) ? true : hasn;
            int nxt = (i < 3) ? s[i + 1] : sn;
            if (!nvalid || nxt != s[i]) re[s[i]] = e0 + i + 1;
        }
    } else {
        for (int i = 0; i < 4; i++) {
            int e = e0 + i;
            if (e >= E) break;
            int s = src[e];
            if (e == 0 || src[e - 1] != s) rs[s] = e;
            if (e + 1 == E || src[e + 1] != s) re[s] = e + 1;
        }
    }
}

// ---- dinv2 + y2 = dinv2 * hp row (F=32) ----
__global__ void k_dinv2y(const int* __restrict__ rs, const int* __restrict__ re,
                         float* __restrict__ dinv, const float* __restrict__ hp,
                         float* __restrict__ y2, int n) {
    int t = blockIdx.x * blockDim.x + threadIdx.x;
    if (t >= n) return;
    int deg = re[t] - rs[t];
    float w = (deg > 0) ? rsqrtf((float)deg) : 0.0f;
    dinv[t] = w;
    const float4* hr = (const float4*)(hp + (long)t * 32);
    float4* yr = (float4*)(y2 + (long)t * 32);
#pragma unroll
    for (int i = 0; i < 8; i++) {
        float4 v = hr[i];
        yr[i] = make_float4(w * v.x, w * v.y, w * v.z, w * v.w);
    }
}

__global__ void k_scan_blk(const int* __restrict__ cnt, int* __restrict__ offs,
                           int* __restrict__ blksum, int n) {
    __shared__ int ts[256];
    int blk = blockIdx.x;
    int tid = threadIdx.x;
    int i0 = blk * 1024 + tid * 4;
    int a0 = 0, a1 = 0, a2 = 0, a3 = 0;
    if (i0 + 3 < n) {
        int4 v = *(const int4*)&cnt[i0];
        a0 = v.x; a1 = v.y; a2 = v.z; a3 = v.w;
    } else {
        if (i0 + 0 < n) a0 = cnt[i0 + 0];
        if (i0 + 1 < n) a1 = cnt[i0 + 1];
        if (i0 + 2 < n) a2 = cnt[i0 + 2];
    }
    int tsum = a0 + a1 + a2 + a3;
    ts[tid] = tsum;
    __syncthreads();
    for (int off = 1; off < 256; off <<= 1) {
        int v = (tid >= off) ? ts[tid - off] : 0;
        __syncthreads();
        ts[tid] += v;
        __syncthreads();
    }
    int ex = ts[tid] - tsum;
    if (tid == 255) blksum[blk] = ts[255];
    int p0 = ex, p1 = ex + a0, p2 = p1 + a1, p3 = p2 + a2;
    if (i0 + 3 < n) {
        *(int4*)&offs[i0] = make_int4(p0, p1, p2, p3);
    } else {
        if (i0 + 0 < n) offs[i0 + 0] = p0;
        if (i0 + 1 < n) offs[i0 + 1] = p1;
        if (i0 + 2 < n) offs[i0 + 2] = p2;
    }
}

// ---- scan finalize + dinv1 + y1 = dinv1 * x row (F=16); blksum scanned in-LDS ----
__global__ void k_scan_add_dinv_y(int* __restrict__ offs, int* __restrict__ cursor,
                                  const int* __restrict__ blksum, const int* __restrict__ cntS,
                                  const int* __restrict__ ust, const int* __restrict__ uen,
                                  float* __restrict__ dinv, const float* __restrict__ xin,
                                  float* __restrict__ y1, int n, int nblk) {
    __shared__ int s[128];
    __shared__ int orig[128];
    int tid = threadIdx.x;
    if (tid < 128) {
        int v = (tid < nblk) ? blksum[tid] : 0;
        s[tid] = v; orig[tid] = v;
    }
    __syncthreads();
    for (int off = 1; off < 128; off <<= 1) {
        int v = 0;
        if (tid < 128 && tid >= off) v = s[tid - off];
        __syncthreads();
        if (tid < 128) s[tid] += v;
        __syncthreads();
    }
    int t = blockIdx.x * blockDim.x + tid;
    if (t >= n) return;
    int blk = t >> 10;
    int base = s[blk] - orig[blk];  // exclusive prefix
    int v = offs[t] + base;
    offs[t] = v;
    cursor[t] = v;
    int deg = cntS[t] + uen[t] - ust[t];
    float w = (deg > 0) ? rsqrtf((float)deg) : 0.0f;
    dinv[t] = w;
    const float4* xr = (const float4*)(xin + (long)t * 16);
    float4* yr = (float4*)(y1 + (long)t * 16);
#pragma unroll
    for (int i = 0; i < 4; i++) {
        float4 u = xr[i];
        yr[i] = make_float4(w * u.x, w * u.y, w * u.z, w * u.w);
    }
}

// ---- fill small-CSR: 1 edge/thread (max TLP to hide atomic return latency) ----
__global__ void k_fillS(const int* __restrict__ src, const int* __restrict__ dst,
                        int* __restrict__ cursor, int* __restrict__ csr, int E) {
    int e = blockIdx.x * blockDim.x + threadIdx.x;
    if (e >= E) return;
    int s = src[e], d = dst[e];
    if (s < d) {
        int pos = atomicAdd(&cursor[d], 1);
        csr[pos] = s;
    }
}

// ---- gather1 (F=16): 4-lane group; y1 rows (pre-scaled); idx shuffle-shared ----
__global__ void k_gather1y(const int* __restrict__ ust, const int* __restrict__ uen,
                           const int* __restrict__ dst1, const int* __restrict__ offsS,
                           const int* __restrict__ cntS, const int* __restrict__ csrS,
                           const float* __restrict__ dinv, const float* __restrict__ y1,
                           float* __restrict__ tx, int n) {
    int vb = swz8(blockIdx.x, gridDim.x);
    int t = vb * blockDim.x + threadIdx.x;
    int d = t >> 2, ln = t & 3, fo = ln << 2;
    if (d >= n) return;
    float ax = 0.f, ay = 0.f, az = 0.f, aw = 0.f;
    int e0 = ust[d], e1 = uen[d];
    for (int j = e0; j < e1; j += 4) {
        int myj = j + ln;
        int s = (myj < e1) ? dst1[myj] : 0;
#pragma unroll
        for (int k = 0; k < 4; k++) {
            if (j + k >= e1) break;
            int sk = __shfl(s, k, 4);
            float4 v = *(const float4*)&y1[((long)sk << 4) + fo];
            ax += v.x; ay += v.y; az += v.z; aw += v.w;
        }
    }
    int i0 = offsS[d], i1 = i0 + cntS[d];
    for (int j = i0; j < i1; j += 4) {
        int myj = j + ln;
        int s = (myj < i1) ? csrS[myj] : 0;
#pragma unroll
        for (int k = 0; k < 4; k++) {
            if (j + k >= i1) break;
            int sk = __shfl(s, k, 4);
            float4 v = *(const float4*)&y1[((long)sk << 4) + fo];
            ax += v.x; ay += v.y; az += v.z; aw += v.w;
        }
    }
    float wd = -dinv[d];
    *(float4*)&tx[((long)d << 4) + fo] = make_float4(wd * ax, wd * ay, wd * az, wd * aw);
}

// ---- gather2 (F=32): 8-lane group; y2 rows (pre-scaled); idx shuffle-shared ----
__global__ void k_gather2y(const int* __restrict__ rs, const int* __restrict__ re,
                           const int* __restrict__ dst2, const float* __restrict__ dinv,
                           const float* __restrict__ y2, float* __restrict__ tx, int n) {
    int vb = swz8(blockIdx.x, gridDim.x);
    int t = vb * blockDim.x + threadIdx.x;
    int d = t >> 3, ln = t & 7, fo = ln << 2;
    if (d >= n) return;
    float ax = 0.f, ay = 0.f, az = 0.f, aw = 0.f;
    int j0 = rs[d], j1 = re[d];
    for (int j = j0; j < j1; j += 8) {
        int myj = j + ln;
        int s = (myj < j1) ? dst2[myj] : 0;
#pragma unroll
        for (int k = 0; k < 8; k++) {
            if (j + k >= j1) break;
            int sk = __shfl(s, k, 8);
            float4 v = *(const float4*)&y2[((long)sk << 5) + fo];
            ax += v.x; ay += v.y; az += v.z; aw += v.w;
        }
    }
    float wd = -dinv[d];
    *(float4*)&tx[((long)d << 5) + fo] = make_float4(wd * ax, wd * ay, wd * az, wd * aw);
}

// ---- layer1 dense (16->32): 4 outputs/thread, float4, plain store ----
__global__ void k_cheb1(const float* __restrict__ x, const float* __restrict__ tx,
                        const float* __restrict__ W0, const float* __restrict__ W1,
                        const float* __restrict__ b, float* __restrict__ h, int N) {
    int t = blockIdx.x * blockDim.x + threadIdx.x;
    int n = t >> 3, jj = (t & 7) << 2;
    if (n >= N) return;
    const float4* xr = (const float4*)(x + (long)n * 16);
    const float4* tr = (const float4*)(tx + (long)n * 16);
    float4 bv = *(const float4*)(b + jj);
    float a0 = bv.x, a1 = bv.y, a2 = bv.z, a3 = bv.w;
#pragma unroll
    for (int k4 = 0; k4 < 4; k4++) {
        float4 xv = xr[k4];
        float4 tv = tr[k4];
        float xs[4] = {xv.x, xv.y, xv.z, xv.w};
        float ts[4] = {tv.x, tv.y, tv.z, tv.w};
#pragma unroll
        for (int c = 0; c < 4; c++) {
            int k = k4 * 4 + c;
            float4 w0 = *(const float4*)(W0 + k * 32 + jj);
            float4 w1 = *(const float4*)(W1 + k * 32 + jj);
            a0 += xs[c] * w0.x + ts[c] * w1.x;
            a1 += xs[c] * w0.y + ts[c] * w1.y;
            a2 += xs[c] * w0.z + ts[c] * w1.z;
            a3 += xs[c] * w0.w + ts[c] * w1.w;
        }
    }
    *(float4*)(h + ((long)n << 5) + jj) =
        make_float4(fmaxf(a0, 0.f), fmaxf(a1, 0.f), fmaxf(a2, 0.f), fmaxf(a3, 0.f));
}

// ---- layer2 dense (32->64): 4 outputs/thread, plain store ----
__global__ void k_cheb2(const float* __restrict__ xp, const float* __restrict__ tx,
                        const float* __restrict__ W0, const float* __restrict__ W1,
                        const float* __restrict__ b, float* __restrict__ h2, int n1) {
    int t = blockIdx.x * blockDim.x + threadIdx.x;
    int n = t >> 4, jj = (t & 15) << 2;
    if (n >= n1) return;
    const float4* xr = (const float4*)(xp + (long)n * 32);
    const float4* tr = (const float4*)(tx + (long)n * 32);
    float4 bv = *(const float4*)(b + jj);
    float a0 = bv.x, a1 = bv.y, a2 = bv.z, a3 = bv.w;
#pragma unroll
    for (int k4 = 0; k4 < 8; k4++) {
        float4 xv = xr[k4];
        float4 tv = tr[k4];
        float xs[4] = {xv.x, xv.y, xv.z, xv.w};
        float ts[4] = {tv.x, tv.y, tv.z, tv.w};
#pragma unroll
        for (int c = 0; c < 4; c++) {
            int k = k4 * 4 + c;
            float4 w0 = *(const float4*)(W0 + k * 64 + jj);
            float4 w1 = *(const float4*)(W1 + k * 64 + jj);
            a0 += xs[c] * w0.x + ts[c] * w1.x;
            a1 += xs[c] * w0.y + ts[c] * w1.y;
            a2 += xs[c] * w0.z + ts[c] * w1.z;
            a3 += xs[c] * w0.w + ts[c] * w1.w;
        }
    }
    *(float4*)(h2 + ((long)n << 6) + jj) =
        make_float4(fmaxf(a0, 0.f), fmaxf(a1, 0.f), fmaxf(a2, 0.f), fmaxf(a3, 0.f));
}

// ---- gsum fused with pool2: float4 member-row reads ----
__global__ void k_gsum2(const float* __restrict__ h2, const int* __restrict__ mcnt,
                        const int* __restrict__ mem, const int* __restrict__ batch,
                        float* __restrict__ gsum, float* __restrict__ gcnt, int n2) {
    __shared__ float s[8 * 64];
    __shared__ float sc[8];
    for (int i = threadIdx.x; i < 512; i += blockDim.x) s[i] = 0.0f;
    if (threadIdx.x < 8) sc[threadIdx.x] = 0.0f;
    __syncthreads();
    long total = (long)n2 * 16;
    long stride = (long)gridDim.x * blockDim.x;
    for (long t = (long)blockIdx.x * blockDim.x + threadIdx.x; t < total; t += stride) {
        int c = (int)(t >> 4), fo = (int)(t & 15) << 2;
        int m0 = mem[2 * c];
        float4 v = *(const float4*)&h2[((long)m0 << 6) + fo];
        if (mcnt[c] > 1) {
            int m1 = mem[2 * c + 1];
            float4 u = *(const float4*)&h2[((long)m1 << 6) + fo];
            v.x = fmaxf(v.x, u.x); v.y = fmaxf(v.y, u.y);
            v.z = fmaxf(v.z, u.z); v.w = fmaxf(v.w, u.w);
        }
        int g = batch[c];
        atomicAdd(&s[g * 64 + fo + 0], v.x);
        atomicAdd(&s[g * 64 + fo + 1], v.y);
        atomicAdd(&s[g * 64 + fo + 2], v.z);
        atomicAdd(&s[g * 64 + fo + 3], v.w);
        if (fo == 0) atomicAdd(&sc[g], 1.0f);
    }
    __syncthreads();
    for (int i = threadIdx.x; i < 512; i += blockDim.x) atomicAdd(&gsum[i], s[i]);
    if (threadIdx.x < 8) atomicAdd(&gcnt[threadIdx.x], sc[threadIdx.x]);
}

// ---- fc1+fc2 fused ----
__global__ void k_fc12(const float* __restrict__ gsum, const float* __restrict__ gcnt,
                       const float* __restrict__ fcw1, const float* __restrict__ fcb1,
                       const float* __restrict__ fcw2, const float* __restrict__ fcb2,
                       float* __restrict__ out, int OUT) {
    __shared__ float sm[8 * 64];
    __shared__ float sg[8 * 128];
    int tid = threadIdx.x;
    for (int i = tid; i < 512; i += blockDim.x) {
        float c = gcnt[i >> 6];
        sm[i] = (c > 0.0f) ? gsum[i] / c : 0.0f;
    }
    __syncthreads();
    for (int e = tid; e < 1024; e += blockDim.x) {
        int gi = e >> 7, j = e & 127;
        float acc = fcb1[j];
#pragma unroll 8
        for (int k = 0; k < 64; k++) acc += sm[gi * 64 + k] * fcw1[k * 128 + j];
        sg[e] = fmaxf(acc, 0.0f);
    }
    __syncthreads();
    int o = blockIdx.x * blockDim.x + tid;
    if (o >= OUT) return;
    float bias = fcb2[o];
    float acc[8];
#pragma unroll
    for (int gi = 0; gi < 8; gi++) acc[gi] = bias;
    for (int k = 0; k < 128; k++) {
        float w = fcw2[(long)k * OUT + o];
#pragma unroll
        for (int gi = 0; gi < 8; gi++) acc[gi] += sg[gi * 128 + k] * w;
    }
#pragma unroll
    for (int gi = 0; gi < 8; gi++) out[(long)gi * OUT + o] = acc[gi];
}

extern "C" void kernel_launch(void* const* d_in, const int* in_sizes, int n_in,
                              void* d_out, int out_size, void* d_ws, size_t ws_size,
                              hipStream_t stream) {
    const float* x    = (const float*)d_in[0];
    const float* W0a  = (const float*)d_in[1];
    const float* W1a  = (const float*)d_in[2];
    const float* b1   = (const float*)d_in[3];
    const float* W0b  = (const float*)d_in[4];
    const float* W1b  = (const float*)d_in[5];
    const float* b2   = (const float*)d_in[6];
    const float* fcw1 = (const float*)d_in[7];
    const float* fcb1 = (const float*)d_in[8];
    const float* fcw2 = (const float*)d_in[9];
    const float* fcb2 = (const float*)d_in[10];
    const int* ei1    = (const int*)d_in[11];
    const int* cl1    = (const int*)d_in[12];
    const int* ei2    = (const int*)d_in[13];
    const int* cl2    = (const int*)d_in[14];
    const int* b3     = (const int*)d_in[15];

    const int N  = in_sizes[12];
    const int E1 = in_sizes[11] / 2;
    const int E2 = in_sizes[13] / 2;
    const int n1 = in_sizes[14];
    const int n2 = in_sizes[15];
    const int G  = 8;
    const int OUT = out_size / G;

    const int nmax = (N > n1) ? N : n1;

    auto rnd = [](size_t b) { return (b + 255) & ~(size_t)255; };
    size_t cntB  = rnd((size_t)N * 4);
    size_t ustB  = rnd((size_t)N * 4);
    size_t uenB  = rnd((size_t)N * 4);
    size_t rs2B  = rnd((size_t)n1 * 4);
    size_t re2B  = rnd((size_t)n1 * 4);
    size_t mc1B  = rnd((size_t)n1 * 4);
    size_t mc2B  = rnd((size_t)n2 * 4);
    size_t smlB  = rnd((512 + 8) * 4);
    size_t offB  = rnd((size_t)N * 4);
    size_t curB  = rnd((size_t)N * 4);
    size_t csrB  = rnd((size_t)(E1 / 2 + 64) * 4);
    size_t dinvB = rnd((size_t)nmax * 4);
    size_t blkB  = rnd((size_t)1024 * 4);
    size_t mem1B = rnd((size_t)n1 * 2 * 4);
    size_t mem2B = rnd((size_t)n2 * 2 * 4);
    size_t hpB   = rnd((size_t)n1 * 32 * 4);
    size_t txB   = rnd((size_t)(((long)N * 16 > (long)n1 * 32) ? (long)N * 16 : (long)n1 * 32) * 4);

    char* base = (char*)d_ws;
    char* p = base;
    int*   cntS   = (int*)p;           p += cntB;
    int*   ust    = (int*)p;           p += ustB;
    int*   uen    = (int*)p;           p += uenB;
    int*   rs2    = (int*)p;           p += rs2B;
    int*   re2    = (int*)p;           p += re2B;
    int*   mcnt1  = (int*)p;           p += mc1B;
    int*   mcnt2  = (int*)p;           p += mc2B;
    float* gsum   = (float*)p;         p += smlB;
    float* gcnt   = gsum + 512;
    size_t zeroB  = (size_t)(p - base);
    int*   offsS  = (int*)p;           p += offB;
    int*   cursorS= (int*)p;           p += curB;
    int*   csrS   = (int*)p;           p += csrB;
    float* dinv   = (float*)p;         p += dinvB;
    int*   blksum = (int*)p;           p += blkB;
    int*   mem1   = (int*)p;           p += mem1B;
    int*   mem2   = (int*)p;           p += mem2B;
    float* hp     = (float*)p;         p += hpB;
    float* txA    = (float*)p;         p += txB;
    float* hbuf   = (float*)p;         // phases: y1 (N*16) -> h1 (N*32) -> y2 (n1*32) -> h2 (n1*64)
    (void)ws_size;

    float* y1 = hbuf;
    float* h1 = hbuf;
    float* y2 = hbuf;
    float* h2 = hbuf;

    dim3 B(256);
    {
        long n4 = (long)(zeroB / 16);
        int g = idiv((int)((n4 < 1048576) ? n4 : 1048576), 256);
        if (g < 1) g = 1;
        if (g > 4096) g = 4096;
        k_zero<<<g, B, 0, stream>>>((float4*)base, n4);
    }

    // ---- layer 1 ----
    {
        int nblk = idiv(N, 1024);
        int maxEN = (E1 > N) ? E1 : N;
        k_prep1m<<<idiv(maxEN, 1024), B, 0, stream>>>(ei1, ei1 + E1, ust, uen, cntS,
                                                      cl1, mcnt1, mem1, E1, N);
        k_scan_blk<<<nblk, B, 0, stream>>>(cntS, offsS, blksum, N);
        k_scan_add_dinv_y<<<idiv(N, 256), B, 0, stream>>>(offsS, cursorS, blksum, cntS, ust, uen,
                                                          dinv, x, y1, N, nblk);
        k_fillS<<<idiv(E1, 256), B, 0, stream>>>(ei1, ei1 + E1, cursorS, csrS, E1);
        k_gather1y<<<idiv(N * 4, 256), B, 0, stream>>>(ust, uen, ei1 + E1, offsS, cntS, csrS,
                                                       dinv, y1, txA, N);
        k_cheb1<<<idiv(N * 8, 256), B, 0, stream>>>(x, txA, W0a, W1a, b1, h1, N);
    }

    // ---- layer 2 ----
    {
        int e4 = idiv(E2, 4);
        int maxT = (e4 > n1 * 8) ? e4 : n1 * 8;
        k_bounds2mp<<<idiv(maxT, 256), B, 0, stream>>>(ei2, rs2, re2, cl2, mcnt2, mem2,
                                                       mcnt1, mem1, h1, hp, E2, n1);
        k_dinv2y<<<idiv(n1, 256), B, 0, stream>>>(rs2, re2, dinv, hp, y2, n1);
        k_gather2y<<<idiv(n1 * 8, 256), B, 0, stream>>>(rs2, re2, ei2 + E2, dinv, y2, txA, n1);
        k_cheb2<<<idiv(n1 * 16, 256), B, 0, stream>>>(hp, txA, W0b, W1b, b2, h2, n1);
    }

    // ---- readout ----
    int gb = idiv(n2 * 16, 256);
    if (gb > 256) gb = 256;
    k_gsum2<<<gb, B, 0, stream>>>(h2, mcnt2, mem2, b3, gsum, gcnt, n2);
    k_fc12<<<idiv(OUT, 256), B, 0, stream>>>(gsum, gcnt, fcw1, fcb1, fcw2, fcb2,
                                             (float*)d_out, OUT);
}

// Round 24
// 201.411 us; speedup vs baseline: 1.2665x; 1.0532x over previous
//
#include <hip/hip_runtime.h>

static inline int idiv(int a, int b) { return (a + b - 1) / b; }

// bijective XCD-chunk swizzle (8 XCDs)
__device__ __forceinline__ int swz8(int bid, int nb) {
    int q = nb >> 3, r = nb & 7;
    int x = bid & 7, c = bid >> 3;
    return (x < r ? x * (q + 1) : r * (q + 1) + (x - r) * q) + c;
}

__global__ void k_zero(float4* __restrict__ p, long n4) {
    long t = (long)blockIdx.x * blockDim.x + threadIdx.x;
    long stride = (long)gridDim.x * blockDim.x;
    for (; t < n4; t += stride) p[t] = make_float4(0.f, 0.f, 0.f, 0.f);
}

// ---- layer1 prep + members1, 4 edges/thread ----
__global__ void k_prep1m(const int* __restrict__ src, const int* __restrict__ dst,
                         int* __restrict__ ust, int* __restrict__ uen,
                         int* __restrict__ cntS, const int* __restrict__ cl,
                         int* __restrict__ mcnt, int* __restrict__ mem, int E, int N) {
    int t = blockIdx.x * blockDim.x + threadIdx.x;
    int e0 = t << 2;
    if (e0 < N) {
        if (e0 + 3 < N) {
            int4 c4 = *(const int4*)&cl[e0];
            int cc[4] = {c4.x, c4.y, c4.z, c4.w};
#pragma unroll
            for (int i = 0; i < 4; i++) {
                int slot = atomicAdd(&mcnt[cc[i]], 1);
                if (slot < 2) mem[2 * cc[i] + slot] = e0 + i;
            }
        } else {
            for (int i = 0; i < 4 && e0 + i < N; i++) {
                int c = cl[e0 + i];
                int slot = atomicAdd(&mcnt[c], 1);
                if (slot < 2) mem[2 * c + slot] = e0 + i;
            }
        }
    }
    if (e0 >= E) return;
    if (e0 + 3 < E) {
        int4 s4 = *(const int4*)&src[e0];
        int s[4] = {s4.x, s4.y, s4.z, s4.w};
        int d[4] = {dst[e0], dst[e0 + 1], dst[e0 + 2], dst[e0 + 3]};
        bool hasp = e0 > 0;
        int sp = hasp ? src[e0 - 1] : 0, dp = hasp ? dst[e0 - 1] : 0;
        bool hasn = e0 + 4 < E;
        int sn = hasn ? src[e0 + 4] : 0, dn = hasn ? dst[e0 + 4] : 0;
#pragma unroll
        for (int i = 0; i < 4; i++) {
            if (s[i] >= d[i]) continue;
            atomicAdd(&cntS[d[i]], 1);
            bool pvalid = (i > 0) ? true : hasp;
            int psi = (i > 0) ? s[i - 1] : sp, pdi = (i > 0) ? d[i - 1] : dp;
            bool prevup = pvalid && (psi < pdi);
            if (!pvalid || !prevup || psi != s[i]) ust[s[i]] = e0 + i;
            bool nvalid = (i < 3) ? true : hasn;
            int nsi = (i < 3) ? s[i + 1] : sn, ndi = (i < 3) ? d[i + 1] : dn;
            bool nextup = nvalid && (nsi < ndi);
            if (!nvalid || !nextup || nsi != s[i]) uen[s[i]] = e0 + i + 1;
        }
    } else {
        for (int i = 0; i < 4; i++) {
            int e = e0 + i;
            if (e >= E) break;
            int s = src[e], d = dst[e];
            if (s >= d) continue;
            atomicAdd(&cntS[d], 1);
            bool prevup = false; int ps = -1;
            if (e > 0) { ps = src[e - 1]; prevup = (ps < dst[e - 1]); }
            if (e == 0 || !prevup || ps != s) ust[s] = e;
            bool nextup = false; int ns = -1;
            if (e + 1 < E) { ns = src[e + 1]; nextup = (ns < dst[e + 1]); }
            if (e + 1 == E || !nextup || ns != s) uen[s] = e + 1;
        }
    }
}

// ---- layer2 bounds + members2 + pool1 fused ----
__global__ void k_bounds2mp(const int* __restrict__ src, int* __restrict__ rs,
                            int* __restrict__ re, const int* __restrict__ cl,
                            int* __restrict__ mcnt2, int* __restrict__ mem2,
                            const int* __restrict__ mcnt1, const int* __restrict__ mem1,
                            const float* __restrict__ h, float* __restrict__ hp,
                            int E, int n1) {
    int t = blockIdx.x * blockDim.x + threadIdx.x;
    if (t < n1 * 8) {
        int c = t >> 3, fo = (t & 7) << 2;
        int m0 = mem1[2 * c];
        float4 v = *(const float4*)&h[((long)m0 << 5) + fo];
        if (mcnt1[c] > 1) {
            int m1 = mem1[2 * c + 1];
            float4 u = *(const float4*)&h[((long)m1 << 5) + fo];
            v.x = fmaxf(v.x, u.x); v.y = fmaxf(v.y, u.y);
            v.z = fmaxf(v.z, u.z); v.w = fmaxf(v.w, u.w);
        }
        *(float4*)&hp[((long)c << 5) + fo] = v;
    }
    if (t < n1) {
        int c = cl[t];
        int slot = atomicAdd(&mcnt2[c], 1);
        if (slot < 2) mem2[2 * c + slot] = t;
    }
    int e0 = t << 2;
    if (e0 >= E) return;
    if (e0 + 3 < E) {
        int4 s4 = *(const int4*)&src[e0];
        int s[4] = {s4.x, s4.y, s4.z, s4.w};
        int sp = (e0 > 0) ? src[e0 - 1] : -1;
        int sn = (e0 + 4 < E) ? src[e0 + 4] : -1;
        bool hasn = e0 + 4 < E;
#pragma unroll
        for (int i = 0; i < 4; i++) {
            int prev = (i > 0) ? s[i - 1] : sp;
            if (e0 + i == 0 || prev != s[i]) rs[s[i]] = e0 + i;
            bool nvalid = (i < 3) ? true : hasn;
            int nxt = (i < 3) ? s[i + 1] : sn;
            if (!nvalid || nxt != s[i]) re[s[i]] = e0 + i + 1;
        }
    } else {
        for (int i = 0; i < 4; i++) {
            int e = e0 + i;
            if (e >= E) break;
            int s = src[e];
            if (e == 0 || src[e - 1] != s) rs[s] = e;
            if (e + 1 == E || src[e + 1] != s) re[s] = e + 1;
        }
    }
}

// ---- dinv2 + y2 = dinv2 * hp row (F=32) ----
__global__ void k_dinv2y(const int* __restrict__ rs, const int* __restrict__ re,
                         float* __restrict__ dinv, const float* __restrict__ hp,
                         float* __restrict__ y2, int n) {
    int t = blockIdx.x * blockDim.x + threadIdx.x;
    if (t >= n) return;
    int deg = re[t] - rs[t];
    float w = (deg > 0) ? rsqrtf((float)deg) : 0.0f;
    dinv[t] = w;
    const float4* hr = (const float4*)(hp + (long)t * 32);
    float4* yr = (float4*)(y2 + (long)t * 32);
#pragma unroll
    for (int i = 0; i < 8; i++) {
        float4 v = hr[i];
        yr[i] = make_float4(w * v.x, w * v.y, w * v.z, w * v.w);
    }
}

__global__ void k_scan_blk(const int* __restrict__ cnt, int* __restrict__ offs,
                           int* __restrict__ blksum, int n) {
    __shared__ int ts[256];
    int blk = blockIdx.x;
    int tid = threadIdx.x;
    int i0 = blk * 1024 + tid * 4;
    int a0 = 0, a1 = 0, a2 = 0, a3 = 0;
    if (i0 + 3 < n) {
        int4 v = *(const int4*)&cnt[i0];
        a0 = v.x; a1 = v.y; a2 = v.z; a3 = v.w;
    } else {
        if (i0 + 0 < n) a0 = cnt[i0 + 0];
        if (i0 + 1 < n) a1 = cnt[i0 + 1];
        if (i0 + 2 < n) a2 = cnt[i0 + 2];
    }
    int tsum = a0 + a1 + a2 + a3;
    ts[tid] = tsum;
    __syncthreads();
    for (int off = 1; off < 256; off <<= 1) {
        int v = (tid >= off) ? ts[tid - off] : 0;
        __syncthreads();
        ts[tid] += v;
        __syncthreads();
    }
    int ex = ts[tid] - tsum;
    if (tid == 255) blksum[blk] = ts[255];
    int p0 = ex, p1 = ex + a0, p2 = p1 + a1, p3 = p2 + a2;
    if (i0 + 3 < n) {
        *(int4*)&offs[i0] = make_int4(p0, p1, p2, p3);
    } else {
        if (i0 + 0 < n) offs[i0 + 0] = p0;
        if (i0 + 1 < n) offs[i0 + 1] = p1;
        if (i0 + 2 < n) offs[i0 + 2] = p2;
    }
}

// ---- scan finalize + dinv1 + y1 = dinv1 * x row (F=16) ----
__global__ void k_scan_add_dinv_y(int* __restrict__ offs, int* __restrict__ cursor,
                                  const int* __restrict__ blksum, const int* __restrict__ cntS,
                                  const int* __restrict__ ust, const int* __restrict__ uen,
                                  float* __restrict__ dinv, const float* __restrict__ xin,
                                  float* __restrict__ y1, int n, int nblk) {
    __shared__ int s[128];
    __shared__ int orig[128];
    int tid = threadIdx.x;
    if (tid < 128) {
        int v = (tid < nblk) ? blksum[tid] : 0;
        s[tid] = v; orig[tid] = v;
    }
    __syncthreads();
    for (int off = 1; off < 128; off <<= 1) {
        int v = 0;
        if (tid < 128 && tid >= off) v = s[tid - off];
        __syncthreads();
        if (tid < 128) s[tid] += v;
        __syncthreads();
    }
    int t = blockIdx.x * blockDim.x + tid;
    if (t >= n) return;
    int blk = t >> 10;
    int base = s[blk] - orig[blk];
    int v = offs[t] + base;
    offs[t] = v;
    cursor[t] = v;
    int deg = cntS[t] + uen[t] - ust[t];
    float w = (deg > 0) ? rsqrtf((float)deg) : 0.0f;
    dinv[t] = w;
    const float4* xr = (const float4*)(xin + (long)t * 16);
    float4* yr = (float4*)(y1 + (long)t * 16);
#pragma unroll
    for (int i = 0; i < 4; i++) {
        float4 u = xr[i];
        yr[i] = make_float4(w * u.x, w * u.y, w * u.z, w * u.w);
    }
}

// ---- fill small-CSR: 1 edge/thread ----
__global__ void k_fillS(const int* __restrict__ src, const int* __restrict__ dst,
                        int* __restrict__ cursor, int* __restrict__ csr, int E) {
    int e = blockIdx.x * blockDim.x + threadIdx.x;
    if (e >= E) return;
    int s = src[e], d = dst[e];
    if (s < d) {
        int pos = atomicAdd(&cursor[d], 1);
        csr[pos] = s;
    }
}

// ---- FUSED gather1+cheb1: 4-lane group per node; tx row via LDS; 8 outputs/lane ----
__global__ void k_gc1(const int* __restrict__ ust, const int* __restrict__ uen,
                      const int* __restrict__ dst1, const int* __restrict__ offsS,
                      const int* __restrict__ cntS, const int* __restrict__ csrS,
                      const float* __restrict__ dinv, const float* __restrict__ y1,
                      const float* __restrict__ x, const float* __restrict__ W0,
                      const float* __restrict__ W1, const float* __restrict__ b,
                      float* __restrict__ h, int n) {
    __shared__ float stx[64 * 16];  // 64 groups x 16 tx floats
    int vb = swz8(blockIdx.x, gridDim.x);
    int t = vb * blockDim.x + threadIdx.x;
    int d = t >> 2, ln = t & 3, fo = ln << 2;
    int g = threadIdx.x >> 2;
    bool act = (d < n);
    float ax = 0.f, ay = 0.f, az = 0.f, aw = 0.f;
    if (act) {
        int e0 = ust[d], e1 = uen[d];
        for (int j = e0; j < e1; j += 4) {
            int myj = j + ln;
            int s = (myj < e1) ? dst1[myj] : 0;
#pragma unroll
            for (int k = 0; k < 4; k++) {
                if (j + k >= e1) break;
                int sk = __shfl(s, k, 4);
                float4 v = *(const float4*)&y1[((long)sk << 4) + fo];
                ax += v.x; ay += v.y; az += v.z; aw += v.w;
            }
        }
        int i0 = offsS[d], i1 = i0 + cntS[d];
        for (int j = i0; j < i1; j += 4) {
            int myj = j + ln;
            int s = (myj < i1) ? csrS[myj] : 0;
#pragma unroll
            for (int k = 0; k < 4; k++) {
                if (j + k >= i1) break;
                int sk = __shfl(s, k, 4);
                float4 v = *(const float4*)&y1[((long)sk << 4) + fo];
                ax += v.x; ay += v.y; az += v.z; aw += v.w;
            }
        }
        float wd = -dinv[d];
        ax *= wd; ay *= wd; az *= wd; aw *= wd;
    }
    stx[g * 16 + fo + 0] = ax;
    stx[g * 16 + fo + 1] = ay;
    stx[g * 16 + fo + 2] = az;
    stx[g * 16 + fo + 3] = aw;
    __syncthreads();
    if (!act) return;
    // dense: this lane computes outputs j0..j0+7
    int j0 = ln << 3;
    const float4* xr = (const float4*)(x + (long)d * 16);
    float4 b0 = *(const float4*)(b + j0);
    float4 b1v = *(const float4*)(b + j0 + 4);
    float a0 = b0.x, a1 = b0.y, a2 = b0.z, a3 = b0.w;
    float a4 = b1v.x, a5 = b1v.y, a6 = b1v.z, a7 = b1v.w;
#pragma unroll
    for (int k4 = 0; k4 < 4; k4++) {
        float4 xv = xr[k4];
        float xs[4] = {xv.x, xv.y, xv.z, xv.w};
#pragma unroll
        for (int c = 0; c < 4; c++) {
            int k = k4 * 4 + c;
            float tk = stx[g * 16 + k];
            float4 wa = *(const float4*)(W0 + k * 32 + j0);
            float4 wb = *(const float4*)(W0 + k * 32 + j0 + 4);
            float4 va = *(const float4*)(W1 + k * 32 + j0);
            float4 vb2 = *(const float4*)(W1 + k * 32 + j0 + 4);
            a0 += xs[c] * wa.x + tk * va.x;
            a1 += xs[c] * wa.y + tk * va.y;
            a2 += xs[c] * wa.z + tk * va.z;
            a3 += xs[c] * wa.w + tk * va.w;
            a4 += xs[c] * wb.x + tk * vb2.x;
            a5 += xs[c] * wb.y + tk * vb2.y;
            a6 += xs[c] * wb.z + tk * vb2.z;
            a7 += xs[c] * wb.w + tk * vb2.w;
        }
    }
    float* hr = h + ((long)d << 5) + j0;
    *(float4*)(hr + 0) = make_float4(fmaxf(a0, 0.f), fmaxf(a1, 0.f), fmaxf(a2, 0.f), fmaxf(a3, 0.f));
    *(float4*)(hr + 4) = make_float4(fmaxf(a4, 0.f), fmaxf(a5, 0.f), fmaxf(a6, 0.f), fmaxf(a7, 0.f));
}

// ---- FUSED gather2+cheb2: 8-lane group per node; tx row via LDS; 8 outputs/lane ----
__global__ void k_gc2(const int* __restrict__ rs, const int* __restrict__ re,
                      const int* __restrict__ dst2, const float* __restrict__ dinv,
                      const float* __restrict__ y2, const float* __restrict__ xp,
                      const float* __restrict__ W0, const float* __restrict__ W1,
                      const float* __restrict__ b, float* __restrict__ h2, int n) {
    __shared__ float stx[32 * 32];  // 32 groups x 32 tx floats
    int vb = swz8(blockIdx.x, gridDim.x);
    int t = vb * blockDim.x + threadIdx.x;
    int d = t >> 3, ln = t & 7, fo = ln << 2;
    int g = threadIdx.x >> 3;
    bool act = (d < n);
    float ax = 0.f, ay = 0.f, az = 0.f, aw = 0.f;
    if (act) {
        int j0r = rs[d], j1 = re[d];
        for (int j = j0r; j < j1; j += 8) {
            int myj = j + ln;
            int s = (myj < j1) ? dst2[myj] : 0;
#pragma unroll
            for (int k = 0; k < 8; k++) {
                if (j + k >= j1) break;
                int sk = __shfl(s, k, 8);
                float4 v = *(const float4*)&y2[((long)sk << 5) + fo];
                ax += v.x; ay += v.y; az += v.z; aw += v.w;
            }
        }
        float wd = -dinv[d];
        ax *= wd; ay *= wd; az *= wd; aw *= wd;
    }
    stx[g * 32 + fo + 0] = ax;
    stx[g * 32 + fo + 1] = ay;
    stx[g * 32 + fo + 2] = az;
    stx[g * 32 + fo + 3] = aw;
    __syncthreads();
    if (!act) return;
    int j0 = ln << 3;
    const float4* xr = (const float4*)(xp + (long)d * 32);
    float4 b0 = *(const float4*)(b + j0);
    float4 b1v = *(const float4*)(b + j0 + 4);
    float a0 = b0.x, a1 = b0.y, a2 = b0.z, a3 = b0.w;
    float a4 = b1v.x, a5 = b1v.y, a6 = b1v.z, a7 = b1v.w;
#pragma unroll
    for (int k4 = 0; k4 < 8; k4++) {
        float4 xv = xr[k4];
        float xs[4] = {xv.x, xv.y, xv.z, xv.w};
#pragma unroll
        for (int c = 0; c < 4; c++) {
            int k = k4 * 4 + c;
            float tk = stx[g * 32 + k];
            float4 wa = *(const float4*)(W0 + k * 64 + j0);
            float4 wb = *(const float4*)(W0 + k * 64 + j0 + 4);
            float4 va = *(const float4*)(W1 + k * 64 + j0);
            float4 vb2 = *(const float4*)(W1 + k * 64 + j0 + 4);
            a0 += xs[c] * wa.x + tk * va.x;
            a1 += xs[c] * wa.y + tk * va.y;
            a2 += xs[c] * wa.z + tk * va.z;
            a3 += xs[c] * wa.w + tk * va.w;
            a4 += xs[c] * wb.x + tk * vb2.x;
            a5 += xs[c] * wb.y + tk * vb2.y;
            a6 += xs[c] * wb.z + tk * vb2.z;
            a7 += xs[c] * wb.w + tk * vb2.w;
        }
    }
    float* hr = h2 + ((long)d << 6) + j0;
    *(float4*)(hr + 0) = make_float4(fmaxf(a0, 0.f), fmaxf(a1, 0.f), fmaxf(a2, 0.f), fmaxf(a3, 0.f));
    *(float4*)(hr + 4) = make_float4(fmaxf(a4, 0.f), fmaxf(a5, 0.f), fmaxf(a6, 0.f), fmaxf(a7, 0.f));
}

// ---- gsum fused with pool2: float4 member-row reads ----
__global__ void k_gsum2(const float* __restrict__ h2, const int* __restrict__ mcnt,
                        const int* __restrict__ mem, const int* __restrict__ batch,
                        float* __restrict__ gsum, float* __restrict__ gcnt, int n2) {
    __shared__ float s[8 * 64];
    __shared__ float sc[8];
    for (int i = threadIdx.x; i < 512; i += blockDim.x) s[i] = 0.0f;
    if (threadIdx.x < 8) sc[threadIdx.x] = 0.0f;
    __syncthreads();
    long total = (long)n2 * 16;
    long stride = (long)gridDim.x * blockDim.x;
    for (long t = (long)blockIdx.x * blockDim.x + threadIdx.x; t < total; t += stride) {
        int c = (int)(t >> 4), fo = (int)(t & 15) << 2;
        int m0 = mem[2 * c];
        float4 v = *(const float4*)&h2[((long)m0 << 6) + fo];
        if (mcnt[c] > 1) {
            int m1 = mem[2 * c + 1];
            float4 u = *(const float4*)&h2[((long)m1 << 6) + fo];
            v.x = fmaxf(v.x, u.x); v.y = fmaxf(v.y, u.y);
            v.z = fmaxf(v.z, u.z); v.w = fmaxf(v.w, u.w);
        }
        int g = batch[c];
        atomicAdd(&s[g * 64 + fo + 0], v.x);
        atomicAdd(&s[g * 64 + fo + 1], v.y);
        atomicAdd(&s[g * 64 + fo + 2], v.z);
        atomicAdd(&s[g * 64 + fo + 3], v.w);
        if (fo == 0) atomicAdd(&sc[g], 1.0f);
    }
    __syncthreads();
    for (int i = threadIdx.x; i < 512; i += blockDim.x) atomicAdd(&gsum[i], s[i]);
    if (threadIdx.x < 8) atomicAdd(&gcnt[threadIdx.x], sc[threadIdx.x]);
}

// ---- fc1+fc2 fused ----
__global__ void k_fc12(const float* __restrict__ gsum, const float* __restrict__ gcnt,
                       const float* __restrict__ fcw1, const float* __restrict__ fcb1,
                       const float* __restrict__ fcw2, const float* __restrict__ fcb2,
                       float* __restrict__ out, int OUT) {
    __shared__ float sm[8 * 64];
    __shared__ float sg[8 * 128];
    int tid = threadIdx.x;
    for (int i = tid; i < 512; i += blockDim.x) {
        float c = gcnt[i >> 6];
        sm[i] = (c > 0.0f) ? gsum[i] / c : 0.0f;
    }
    __syncthreads();
    for (int e = tid; e < 1024; e += blockDim.x) {
        int gi = e >> 7, j = e & 127;
        float acc = fcb1[j];
#pragma unroll 8
        for (int k = 0; k < 64; k++) acc += sm[gi * 64 + k] * fcw1[k * 128 + j];
        sg[e] = fmaxf(acc, 0.0f);
    }
    __syncthreads();
    int o = blockIdx.x * blockDim.x + tid;
    if (o >= OUT) return;
    float bias = fcb2[o];
    float acc[8];
#pragma unroll
    for (int gi = 0; gi < 8; gi++) acc[gi] = bias;
    for (int k = 0; k < 128; k++) {
        float w = fcw2[(long)k * OUT + o];
#pragma unroll
        for (int gi = 0; gi < 8; gi++) acc[gi] += sg[gi * 128 + k] * w;
    }
#pragma unroll
    for (int gi = 0; gi < 8; gi++) out[(long)gi * OUT + o] = acc[gi];
}

extern "C" void kernel_launch(void* const* d_in, const int* in_sizes, int n_in,
                              void* d_out, int out_size, void* d_ws, size_t ws_size,
                              hipStream_t stream) {
    const float* x    = (const float*)d_in[0];
    const float* W0a  = (const float*)d_in[1];
    const float* W1a  = (const float*)d_in[2];
    const float* b1   = (const float*)d_in[3];
    const float* W0b  = (const float*)d_in[4];
    const float* W1b  = (const float*)d_in[5];
    const float* b2   = (const float*)d_in[6];
    const float* fcw1 = (const float*)d_in[7];
    const float* fcb1 = (const float*)d_in[8];
    const float* fcw2 = (const float*)d_in[9];
    const float* fcb2 = (const float*)d_in[10];
    const int* ei1    = (const int*)d_in[11];
    const int* cl1    = (const int*)d_in[12];
    const int* ei2    = (const int*)d_in[13];
    const int* cl2    = (const int*)d_in[14];
    const int* b3     = (const int*)d_in[15];

    const int N  = in_sizes[12];
    const int E1 = in_sizes[11] / 2;
    const int E2 = in_sizes[13] / 2;
    const int n1 = in_sizes[14];
    const int n2 = in_sizes[15];
    const int G  = 8;
    const int OUT = out_size / G;

    const int nmax = (N > n1) ? N : n1;

    auto rnd = [](size_t b) { return (b + 255) & ~(size_t)255; };
    size_t cntB  = rnd((size_t)N * 4);
    size_t ustB  = rnd((size_t)N * 4);
    size_t uenB  = rnd((size_t)N * 4);
    size_t rs2B  = rnd((size_t)n1 * 4);
    size_t re2B  = rnd((size_t)n1 * 4);
    size_t mc1B  = rnd((size_t)n1 * 4);
    size_t mc2B  = rnd((size_t)n2 * 4);
    size_t smlB  = rnd((512 + 8) * 4);
    size_t offB  = rnd((size_t)N * 4);
    size_t curB  = rnd((size_t)N * 4);
    size_t csrB  = rnd((size_t)(E1 / 2 + 64) * 4);
    size_t dinvB = rnd((size_t)nmax * 4);
    size_t blkB  = rnd((size_t)1024 * 4);
    size_t mem1B = rnd((size_t)n1 * 2 * 4);
    size_t mem2B = rnd((size_t)n2 * 2 * 4);
    size_t hpB   = rnd((size_t)n1 * 32 * 4);

    char* base = (char*)d_ws;
    char* p = base;
    int*   cntS   = (int*)p;           p += cntB;
    int*   ust    = (int*)p;           p += ustB;
    int*   uen    = (int*)p;           p += uenB;
    int*   rs2    = (int*)p;           p += rs2B;
    int*   re2    = (int*)p;           p += re2B;
    int*   mcnt1  = (int*)p;           p += mc1B;
    int*   mcnt2  = (int*)p;           p += mc2B;
    float* gsum   = (float*)p;         p += smlB;
    float* gcnt   = gsum + 512;
    size_t zeroB  = (size_t)(p - base);
    int*   offsS  = (int*)p;           p += offB;
    int*   cursorS= (int*)p;           p += curB;
    int*   csrS   = (int*)p;           p += csrB;
    float* dinv   = (float*)p;         p += dinvB;
    int*   blksum = (int*)p;           p += blkB;
    int*   mem1   = (int*)p;           p += mem1B;
    int*   mem2   = (int*)p;           p += mem2B;
    float* hp     = (float*)p;         p += hpB;
    float* hbuf   = (float*)p;         // phases: y1 (N*16) -> h1 (N*32) -> y2 (n1*32) -> h2 (n1*64)
    (void)ws_size;

    float* y1 = hbuf;
    float* h1 = hbuf;
    float* y2 = hbuf;
    float* h2 = hbuf;

    dim3 B(256);
    {
        long n4 = (long)(zeroB / 16);
        int g = idiv((int)((n4 < 1048576) ? n4 : 1048576), 256);
        if (g < 1) g = 1;
        if (g > 4096) g = 4096;
        k_zero<<<g, B, 0, stream>>>((float4*)base, n4);
    }

    // ---- layer 1 ----
    {
        int nblk = idiv(N, 1024);
        int maxEN = (E1 > N) ? E1 : N;
        k_prep1m<<<idiv(maxEN, 1024), B, 0, stream>>>(ei1, ei1 + E1, ust, uen, cntS,
                                                      cl1, mcnt1, mem1, E1, N);
        k_scan_blk<<<nblk, B, 0, stream>>>(cntS, offsS, blksum, N);
        k_scan_add_dinv_y<<<idiv(N, 256), B, 0, stream>>>(offsS, cursorS, blksum, cntS, ust, uen,
                                                          dinv, x, y1, N, nblk);
        k_fillS<<<idiv(E1, 256), B, 0, stream>>>(ei1, ei1 + E1, cursorS, csrS, E1);
        k_gc1<<<idiv(N * 4, 256), B, 0, stream>>>(ust, uen, ei1 + E1, offsS, cntS, csrS,
                                                  dinv, y1, x, W0a, W1a, b1, h1, N);
    }

    // ---- layer 2 ----
    {
        int e4 = idiv(E2, 4);
        int maxT = (e4 > n1 * 8) ? e4 : n1 * 8;
        k_bounds2mp<<<idiv(maxT, 256), B, 0, stream>>>(ei2, rs2, re2, cl2, mcnt2, mem2,
                                                       mcnt1, mem1, h1, hp, E2, n1);
        k_dinv2y<<<idiv(n1, 256), B, 0, stream>>>(rs2, re2, dinv, hp, y2, n1);
        k_gc2<<<idiv(n1 * 8, 256), B, 0, stream>>>(rs2, re2, ei2 + E2, dinv, y2, hp,
                                                   W0b, W1b, b2, h2, n1);
    }

    // ---- readout ----
    int gb = idiv(n2 * 16, 256);
    if (gb > 256) gb = 256;
    k_gsum2<<<gb, B, 0, stream>>>(h2, mcnt2, mem2, b3, gsum, gcnt, n2);
    k_fc12<<<idiv(OUT, 256), B, 0, stream>>>(gsum, gcnt, fcw1, fcb1, fcw2, fcb2,
                                             (float*)d_out, OUT);
}

// Round 25
// 201.031 us; speedup vs baseline: 1.2689x; 1.0019x over previous
//
#include <hip/hip_runtime.h>

static inline int idiv(int a, int b) { return (a + b - 1) / b; }

// bijective XCD-chunk swizzle (8 XCDs)
__device__ __forceinline__ int swz8(int bid, int nb) {
    int q = nb >> 3, r = nb & 7;
    int x = bid & 7, c = bid >> 3;
    return (x < r ? x * (q + 1) : r * (q + 1) + (x - r) * q) + c;
}

__global__ void k_zero(float4* __restrict__ p, long n4) {
    long t = (long)blockIdx.x * blockDim.x + threadIdx.x;
    long stride = (long)gridDim.x * blockDim.x;
    for (; t < n4; t += stride) p[t] = make_float4(0.f, 0.f, 0.f, 0.f);
}

// ---- layer1 prep + members1, 4 edges/thread ----
__global__ void k_prep1m(const int* __restrict__ src, const int* __restrict__ dst,
                         int* __restrict__ ust, int* __restrict__ uen,
                         int* __restrict__ cntS, const int* __restrict__ cl,
                         int* __restrict__ mcnt, int* __restrict__ mem, int E, int N) {
    int t = blockIdx.x * blockDim.x + threadIdx.x;
    int e0 = t << 2;
    if (e0 < N) {
        if (e0 + 3 < N) {
            int4 c4 = *(const int4*)&cl[e0];
            int cc[4] = {c4.x, c4.y, c4.z, c4.w};
#pragma unroll
            for (int i = 0; i < 4; i++) {
                int slot = atomicAdd(&mcnt[cc[i]], 1);
                if (slot < 2) mem[2 * cc[i] + slot] = e0 + i;
            }
        } else {
            for (int i = 0; i < 4 && e0 + i < N; i++) {
                int c = cl[e0 + i];
                int slot = atomicAdd(&mcnt[c], 1);
                if (slot < 2) mem[2 * c + slot] = e0 + i;
            }
        }
    }
    if (e0 >= E) return;
    if (e0 + 3 < E) {
        int4 s4 = *(const int4*)&src[e0];
        int s[4] = {s4.x, s4.y, s4.z, s4.w};
        int d[4] = {dst[e0], dst[e0 + 1], dst[e0 + 2], dst[e0 + 3]};
        bool hasp = e0 > 0;
        int sp = hasp ? src[e0 - 1] : 0, dp = hasp ? dst[e0 - 1] : 0;
        bool hasn = e0 + 4 < E;
        int sn = hasn ? src[e0 + 4] : 0, dn = hasn ? dst[e0 + 4] : 0;
#pragma unroll
        for (int i = 0; i < 4; i++) {
            if (s[i] >= d[i]) continue;
            atomicAdd(&cntS[d[i]], 1);
            bool pvalid = (i > 0) ? true : hasp;
            int psi = (i > 0) ? s[i - 1] : sp, pdi = (i > 0) ? d[i - 1] : dp;
            bool prevup = pvalid && (psi < pdi);
            if (!pvalid || !prevup || psi != s[i]) ust[s[i]] = e0 + i;
            bool nvalid = (i < 3) ? true : hasn;
            int nsi = (i < 3) ? s[i + 1] : sn, ndi = (i < 3) ? d[i + 1] : dn;
            bool nextup = nvalid && (nsi < ndi);
            if (!nvalid || !nextup || nsi != s[i]) uen[s[i]] = e0 + i + 1;
        }
    } else {
        for (int i = 0; i < 4; i++) {
            int e = e0 + i;
            if (e >= E) break;
            int s = src[e], d = dst[e];
            if (s >= d) continue;
            atomicAdd(&cntS[d], 1);
            bool prevup = false; int ps = -1;
            if (e > 0) { ps = src[e - 1]; prevup = (ps < dst[e - 1]); }
            if (e == 0 || !prevup || ps != s) ust[s] = e;
            bool nextup = false; int ns = -1;
            if (e + 1 < E) { ns = src[e + 1]; nextup = (ns < dst[e + 1]); }
            if (e + 1 == E || !nextup || ns != s) uen[s] = e + 1;
        }
    }
}

// ---- layer2 bounds + members2 + pool1 fused ----
__global__ void k_bounds2mp(const int* __restrict__ src, int* __restrict__ rs,
                            int* __restrict__ re, const int* __restrict__ cl,
                            int* __restrict__ mcnt2, int* __restrict__ mem2,
                            const int* __restrict__ mcnt1, const int* __restrict__ mem1,
                            const float* __restrict__ h, float* __restrict__ hp,
                            int E, int n1) {
    int t = blockIdx.x * blockDim.x + threadIdx.x;
    if (t < n1 * 8) {
        int c = t >> 3, fo = (t & 7) << 2;
        int m0 = mem1[2 * c];
        float4 v = *(const float4*)&h[((long)m0 << 5) + fo];
        if (mcnt1[c] > 1) {
            int m1 = mem1[2 * c + 1];
            float4 u = *(const float4*)&h[((long)m1 << 5) + fo];
            v.x = fmaxf(v.x, u.x); v.y = fmaxf(v.y, u.y);
            v.z = fmaxf(v.z, u.z); v.w = fmaxf(v.w, u.w);
        }
        *(float4*)&hp[((long)c << 5) + fo] = v;
    }
    if (t < n1) {
        int c = cl[t];
        int slot = atomicAdd(&mcnt2[c], 1);
        if (slot < 2) mem2[2 * c + slot] = t;
    }
    int e0 = t << 2;
    if (e0 >= E) return;
    if (e0 + 3 < E) {
        int4 s4 = *(const int4*)&src[e0];
        int s[4] = {s4.x, s4.y, s4.z, s4.w};
        int sp = (e0 > 0) ? src[e0 - 1] : -1;
        int sn = (e0 + 4 < E) ? src[e0 + 4] : -1;
        bool hasn = e0 + 4 < E;
#pragma unroll
        for (int i = 0; i < 4; i++) {
            int prev = (i > 0) ? s[i - 1] : sp;
            if (e0 + i == 0 || prev != s[i]) rs[s[i]] = e0 + i;
            bool nvalid = (i < 3) ? true : hasn;
            int nxt = (i < 3) ? s[i + 1] : sn;
            if (!nvalid || nxt != s[i]) re[s[i]] = e0 + i + 1;
        }
    } else {
        for (int i = 0; i < 4; i++) {
            int e = e0 + i;
            if (e >= E) break;
            int s = src[e];
            if (e == 0 || src[e - 1] != s) rs[s] = e;
            if (e + 1 == E || src[e + 1] != s) re[s] = e + 1;
        }
    }
}

// ---- dinv2 + y2 = dinv2 * hp row (F=32) ----
__global__ void k_dinv2y(const int* __restrict__ rs, const int* __restrict__ re,
                         float* __restrict__ dinv, const float* __restrict__ hp,
                         float* __restrict__ y2, int n) {
    int t = blockIdx.x * blockDim.x + threadIdx.x;
    if (t >= n) return;
    int deg = re[t] - rs[t];
    float w = (deg > 0) ? rsqrtf((float)deg) : 0.0f;
    dinv[t] = w;
    const float4* hr = (const float4*)(hp + (long)t * 32);
    float4* yr = (float4*)(y2 + (long)t * 32);
#pragma unroll
    for (int i = 0; i < 8; i++) {
        float4 v = hr[i];
        yr[i] = make_float4(w * v.x, w * v.y, w * v.z, w * v.w);
    }
}

__global__ void k_scan_blk(const int* __restrict__ cnt, int* __restrict__ offs,
                           int* __restrict__ blksum, int n) {
    __shared__ int ts[256];
    int blk = blockIdx.x;
    int tid = threadIdx.x;
    int i0 = blk * 1024 + tid * 4;
    int a0 = 0, a1 = 0, a2 = 0, a3 = 0;
    if (i0 + 3 < n) {
        int4 v = *(const int4*)&cnt[i0];
        a0 = v.x; a1 = v.y; a2 = v.z; a3 = v.w;
    } else {
        if (i0 + 0 < n) a0 = cnt[i0 + 0];
        if (i0 + 1 < n) a1 = cnt[i0 + 1];
        if (i0 + 2 < n) a2 = cnt[i0 + 2];
    }
    int tsum = a0 + a1 + a2 + a3;
    ts[tid] = tsum;
    __syncthreads();
    for (int off = 1; off < 256; off <<= 1) {
        int v = (tid >= off) ? ts[tid - off] : 0;
        __syncthreads();
        ts[tid] += v;
        __syncthreads();
    }
    int ex = ts[tid] - tsum;
    if (tid == 255) blksum[blk] = ts[255];
    int p0 = ex, p1 = ex + a0, p2 = p1 + a1, p3 = p2 + a2;
    if (i0 + 3 < n) {
        *(int4*)&offs[i0] = make_int4(p0, p1, p2, p3);
    } else {
        if (i0 + 0 < n) offs[i0 + 0] = p0;
        if (i0 + 1 < n) offs[i0 + 1] = p1;
        if (i0 + 2 < n) offs[i0 + 2] = p2;
    }
}

// ---- scan finalize + dinv1 + y1 = dinv1 * x row (F=16) ----
__global__ void k_scan_add_dinv_y(int* __restrict__ offs, int* __restrict__ cursor,
                                  const int* __restrict__ blksum, const int* __restrict__ cntS,
                                  const int* __restrict__ ust, const int* __restrict__ uen,
                                  float* __restrict__ dinv, const float* __restrict__ xin,
                                  float* __restrict__ y1, int n, int nblk) {
    __shared__ int s[128];
    __shared__ int orig[128];
    int tid = threadIdx.x;
    if (tid < 128) {
        int v = (tid < nblk) ? blksum[tid] : 0;
        s[tid] = v; orig[tid] = v;
    }
    __syncthreads();
    for (int off = 1; off < 128; off <<= 1) {
        int v = 0;
        if (tid < 128 && tid >= off) v = s[tid - off];
        __syncthreads();
        if (tid < 128) s[tid] += v;
        __syncthreads();
    }
    int t = blockIdx.x * blockDim.x + tid;
    if (t >= n) return;
    int blk = t >> 10;
    int base = s[blk] - orig[blk];
    int v = offs[t] + base;
    offs[t] = v;
    cursor[t] = v;
    int deg = cntS[t] + uen[t] - ust[t];
    float w = (deg > 0) ? rsqrtf((float)deg) : 0.0f;
    dinv[t] = w;
    const float4* xr = (const float4*)(xin + (long)t * 16);
    float4* yr = (float4*)(y1 + (long)t * 16);
#pragma unroll
    for (int i = 0; i < 4; i++) {
        float4 u = xr[i];
        yr[i] = make_float4(w * u.x, w * u.y, w * u.z, w * u.w);
    }
}

// ---- fill small-CSR: 1 edge/thread ----
__global__ void k_fillS(const int* __restrict__ src, const int* __restrict__ dst,
                        int* __restrict__ cursor, int* __restrict__ csr, int E) {
    int e = blockIdx.x * blockDim.x + threadIdx.x;
    if (e >= E) return;
    int s = src[e], d = dst[e];
    if (s < d) {
        int pos = atomicAdd(&cursor[d], 1);
        csr[pos] = s;
    }
}

// ---- FUSED gather1+cheb1: padded LDS (stride 17), dual-accumulator gather ----
__global__ void k_gc1(const int* __restrict__ ust, const int* __restrict__ uen,
                      const int* __restrict__ dst1, const int* __restrict__ offsS,
                      const int* __restrict__ cntS, const int* __restrict__ csrS,
                      const float* __restrict__ dinv, const float* __restrict__ y1,
                      const float* __restrict__ x, const float* __restrict__ W0,
                      const float* __restrict__ W1, const float* __restrict__ b,
                      float* __restrict__ h, int n) {
    __shared__ float stx[64 * 17];  // 64 groups, stride 17 (bank-conflict-free reads)
    int vb = swz8(blockIdx.x, gridDim.x);
    int t = vb * blockDim.x + threadIdx.x;
    int d = t >> 2, ln = t & 3, fo = ln << 2;
    int g = threadIdx.x >> 2;
    bool act = (d < n);
    float ax = 0.f, ay = 0.f, az = 0.f, aw = 0.f;
    float bx = 0.f, by = 0.f, bz = 0.f, bw = 0.f;
    if (act) {
        int e0 = ust[d], e1 = uen[d];
        for (int j = e0; j < e1; j += 8) {
            int mA = j + ln, mB = j + 4 + ln;
            int sA = (mA < e1) ? dst1[mA] : 0;
            int sB = (mB < e1) ? dst1[mB] : 0;
#pragma unroll
            for (int k = 0; k < 4; k++) {
                if (j + k >= e1) break;
                int sk = __shfl(sA, k, 4);
                float4 v = *(const float4*)&y1[((long)sk << 4) + fo];
                ax += v.x; ay += v.y; az += v.z; aw += v.w;
            }
#pragma unroll
            for (int k = 0; k < 4; k++) {
                if (j + 4 + k >= e1) break;
                int sk = __shfl(sB, k, 4);
                float4 v = *(const float4*)&y1[((long)sk << 4) + fo];
                bx += v.x; by += v.y; bz += v.z; bw += v.w;
            }
        }
        int i0 = offsS[d], i1 = i0 + cntS[d];
        for (int j = i0; j < i1; j += 8) {
            int mA = j + ln, mB = j + 4 + ln;
            int sA = (mA < i1) ? csrS[mA] : 0;
            int sB = (mB < i1) ? csrS[mB] : 0;
#pragma unroll
            for (int k = 0; k < 4; k++) {
                if (j + k >= i1) break;
                int sk = __shfl(sA, k, 4);
                float4 v = *(const float4*)&y1[((long)sk << 4) + fo];
                ax += v.x; ay += v.y; az += v.z; aw += v.w;
            }
#pragma unroll
            for (int k = 0; k < 4; k++) {
                if (j + 4 + k >= i1) break;
                int sk = __shfl(sB, k, 4);
                float4 v = *(const float4*)&y1[((long)sk << 4) + fo];
                bx += v.x; by += v.y; bz += v.z; bw += v.w;
            }
        }
        float wd = -dinv[d];
        ax = wd * (ax + bx); ay = wd * (ay + by);
        az = wd * (az + bz); aw = wd * (aw + bw);
    }
    stx[g * 17 + fo + 0] = ax;
    stx[g * 17 + fo + 1] = ay;
    stx[g * 17 + fo + 2] = az;
    stx[g * 17 + fo + 3] = aw;
    __syncthreads();
    if (!act) return;
    int j0 = ln << 3;
    const float4* xr = (const float4*)(x + (long)d * 16);
    float4 b0 = *(const float4*)(b + j0);
    float4 b1v = *(const float4*)(b + j0 + 4);
    float a0 = b0.x, a1 = b0.y, a2 = b0.z, a3 = b0.w;
    float a4 = b1v.x, a5 = b1v.y, a6 = b1v.z, a7 = b1v.w;
#pragma unroll
    for (int k4 = 0; k4 < 4; k4++) {
        float4 xv = xr[k4];
        float xs[4] = {xv.x, xv.y, xv.z, xv.w};
#pragma unroll
        for (int c = 0; c < 4; c++) {
            int k = k4 * 4 + c;
            float tk = stx[g * 17 + k];
            float4 wa = *(const float4*)(W0 + k * 32 + j0);
            float4 wb = *(const float4*)(W0 + k * 32 + j0 + 4);
            float4 va = *(const float4*)(W1 + k * 32 + j0);
            float4 vb2 = *(const float4*)(W1 + k * 32 + j0 + 4);
            a0 += xs[c] * wa.x + tk * va.x;
            a1 += xs[c] * wa.y + tk * va.y;
            a2 += xs[c] * wa.z + tk * va.z;
            a3 += xs[c] * wa.w + tk * va.w;
            a4 += xs[c] * wb.x + tk * vb2.x;
            a5 += xs[c] * wb.y + tk * vb2.y;
            a6 += xs[c] * wb.z + tk * vb2.z;
            a7 += xs[c] * wb.w + tk * vb2.w;
        }
    }
    float* hr = h + ((long)d << 5) + j0;
    *(float4*)(hr + 0) = make_float4(fmaxf(a0, 0.f), fmaxf(a1, 0.f), fmaxf(a2, 0.f), fmaxf(a3, 0.f));
    *(float4*)(hr + 4) = make_float4(fmaxf(a4, 0.f), fmaxf(a5, 0.f), fmaxf(a6, 0.f), fmaxf(a7, 0.f));
}

// ---- FUSED gather2+cheb2: padded LDS (stride 33), dual-accumulator gather ----
__global__ void k_gc2(const int* __restrict__ rs, const int* __restrict__ re,
                      const int* __restrict__ dst2, const float* __restrict__ dinv,
                      const float* __restrict__ y2, const float* __restrict__ xp,
                      const float* __restrict__ W0, const float* __restrict__ W1,
                      const float* __restrict__ b, float* __restrict__ h2, int n) {
    __shared__ float stx[32 * 33];  // 32 groups, stride 33
    int vb = swz8(blockIdx.x, gridDim.x);
    int t = vb * blockDim.x + threadIdx.x;
    int d = t >> 3, ln = t & 7, fo = ln << 2;
    int g = threadIdx.x >> 3;
    bool act = (d < n);
    float ax = 0.f, ay = 0.f, az = 0.f, aw = 0.f;
    float bx = 0.f, by = 0.f, bz = 0.f, bw = 0.f;
    if (act) {
        int j0r = rs[d], j1 = re[d];
        for (int j = j0r; j < j1; j += 16) {
            int mA = j + ln, mB = j + 8 + ln;
            int sA = (mA < j1) ? dst2[mA] : 0;
            int sB = (mB < j1) ? dst2[mB] : 0;
#pragma unroll
            for (int k = 0; k < 8; k++) {
                if (j + k >= j1) break;
                int sk = __shfl(sA, k, 8);
                float4 v = *(const float4*)&y2[((long)sk << 5) + fo];
                ax += v.x; ay += v.y; az += v.z; aw += v.w;
            }
#pragma unroll
            for (int k = 0; k < 8; k++) {
                if (j + 8 + k >= j1) break;
                int sk = __shfl(sB, k, 8);
                float4 v = *(const float4*)&y2[((long)sk << 5) + fo];
                bx += v.x; by += v.y; bz += v.z; bw += v.w;
            }
        }
        float wd = -dinv[d];
        ax = wd * (ax + bx); ay = wd * (ay + by);
        az = wd * (az + bz); aw = wd * (aw + bw);
    }
    stx[g * 33 + fo + 0] = ax;
    stx[g * 33 + fo + 1] = ay;
    stx[g * 33 + fo + 2] = az;
    stx[g * 33 + fo + 3] = aw;
    __syncthreads();
    if (!act) return;
    int j0 = ln << 3;
    const float4* xr = (const float4*)(xp + (long)d * 32);
    float4 b0 = *(const float4*)(b + j0);
    float4 b1v = *(const float4*)(b + j0 + 4);
    float a0 = b0.x, a1 = b0.y, a2 = b0.z, a3 = b0.w;
    float a4 = b1v.x, a5 = b1v.y, a6 = b1v.z, a7 = b1v.w;
#pragma unroll
    for (int k4 = 0; k4 < 8; k4++) {
        float4 xv = xr[k4];
        float xs[4] = {xv.x, xv.y, xv.z, xv.w};
#pragma unroll
        for (int c = 0; c < 4; c++) {
            int k = k4 * 4 + c;
            float tk = stx[g * 33 + k];
            float4 wa = *(const float4*)(W0 + k * 64 + j0);
            float4 wb = *(const float4*)(W0 + k * 64 + j0 + 4);
            float4 va = *(const float4*)(W1 + k * 64 + j0);
            float4 vb2 = *(const float4*)(W1 + k * 64 + j0 + 4);
            a0 += xs[c] * wa.x + tk * va.x;
            a1 += xs[c] * wa.y + tk * va.y;
            a2 += xs[c] * wa.z + tk * va.z;
            a3 += xs[c] * wa.w + tk * va.w;
            a4 += xs[c] * wb.x + tk * vb2.x;
            a5 += xs[c] * wb.y + tk * vb2.y;
            a6 += xs[c] * wb.z + tk * vb2.z;
            a7 += xs[c] * wb.w + tk * vb2.w;
        }
    }
    float* hr = h2 + ((long)d << 6) + j0;
    *(float4*)(hr + 0) = make_float4(fmaxf(a0, 0.f), fmaxf(a1, 0.f), fmaxf(a2, 0.f), fmaxf(a3, 0.f));
    *(float4*)(hr + 4) = make_float4(fmaxf(a4, 0.f), fmaxf(a5, 0.f), fmaxf(a6, 0.f), fmaxf(a7, 0.f));
}

// ---- gsum fused with pool2: float4 member-row reads ----
__global__ void k_gsum2(const float* __restrict__ h2, const int* __restrict__ mcnt,
                        const int* __restrict__ mem, const int* __restrict__ batch,
                        float* __restrict__ gsum, float* __restrict__ gcnt, int n2) {
    __shared__ float s[8 * 64];
    __shared__ float sc[8];
    for (int i = threadIdx.x; i < 512; i += blockDim.x) s[i] = 0.0f;
    if (threadIdx.x < 8) sc[threadIdx.x] = 0.0f;
    __syncthreads();
    long total = (long)n2 * 16;
    long stride = (long)gridDim.x * blockDim.x;
    for (long t = (long)blockIdx.x * blockDim.x + threadIdx.x; t < total; t += stride) {
        int c = (int)(t >> 4), fo = (int)(t & 15) << 2;
        int m0 = mem[2 * c];
        float4 v = *(const float4*)&h2[((long)m0 << 6) + fo];
        if (mcnt[c] > 1) {
            int m1 = mem[2 * c + 1];
            float4 u = *(const float4*)&h2[((long)m1 << 6) + fo];
            v.x = fmaxf(v.x, u.x); v.y = fmaxf(v.y, u.y);
            v.z = fmaxf(v.z, u.z); v.w = fmaxf(v.w, u.w);
        }
        int g = batch[c];
        atomicAdd(&s[g * 64 + fo + 0], v.x);
        atomicAdd(&s[g * 64 + fo + 1], v.y);
        atomicAdd(&s[g * 64 + fo + 2], v.z);
        atomicAdd(&s[g * 64 + fo + 3], v.w);
        if (fo == 0) atomicAdd(&sc[g], 1.0f);
    }
    __syncthreads();
    for (int i = threadIdx.x; i < 512; i += blockDim.x) atomicAdd(&gsum[i], s[i]);
    if (threadIdx.x < 8) atomicAdd(&gcnt[threadIdx.x], sc[threadIdx.x]);
}

// ---- fc1+fc2 fused ----
__global__ void k_fc12(const float* __restrict__ gsum, const float* __restrict__ gcnt,
                       const float* __restrict__ fcw1, const float* __restrict__ fcb1,
                       const float* __restrict__ fcw2, const float* __restrict__ fcb2,
                       float* __restrict__ out, int OUT) {
    __shared__ float sm[8 * 64];
    __shared__ float sg[8 * 128];
    int tid = threadIdx.x;
    for (int i = tid; i < 512; i += blockDim.x) {
        float c = gcnt[i >> 6];
        sm[i] = (c > 0.0f) ? gsum[i] / c : 0.0f;
    }
    __syncthreads();
    for (int e = tid; e < 1024; e += blockDim.x) {
        int gi = e >> 7, j = e & 127;
        float acc = fcb1[j];
#pragma unroll 8
        for (int k = 0; k < 64; k++) acc += sm[gi * 64 + k] * fcw1[k * 128 + j];
        sg[e] = fmaxf(acc, 0.0f);
    }
    __syncthreads();
    int o = blockIdx.x * blockDim.x + tid;
    if (o >= OUT) return;
    float bias = fcb2[o];
    float acc[8];
#pragma unroll
    for (int gi = 0; gi < 8; gi++) acc[gi] = bias;
    for (int k = 0; k < 128; k++) {
        float w = fcw2[(long)k * OUT + o];
#pragma unroll
        for (int gi = 0; gi < 8; gi++) acc[gi] += sg[gi * 128 + k] * w;
    }
#pragma unroll
    for (int gi = 0; gi < 8; gi++) out[(long)gi * OUT + o] = acc[gi];
}

extern "C" void kernel_launch(void* const* d_in, const int* in_sizes, int n_in,
                              void* d_out, int out_size, void* d_ws, size_t ws_size,
                              hipStream_t stream) {
    const float* x    = (const float*)d_in[0];
    const float* W0a  = (const float*)d_in[1];
    const float* W1a  = (const float*)d_in[2];
    const float* b1   = (const float*)d_in[3];
    const float* W0b  = (const float*)d_in[4];
    const float* W1b  = (const float*)d_in[5];
    const float* b2   = (const float*)d_in[6];
    const float* fcw1 = (const float*)d_in[7];
    const float* fcb1 = (const float*)d_in[8];
    const float* fcw2 = (const float*)d_in[9];
    const float* fcb2 = (const float*)d_in[10];
    const int* ei1    = (const int*)d_in[11];
    const int* cl1    = (const int*)d_in[12];
    const int* ei2    = (const int*)d_in[13];
    const int* cl2    = (const int*)d_in[14];
    const int* b3     = (const int*)d_in[15];

    const int N  = in_sizes[12];
    const int E1 = in_sizes[11] / 2;
    const int E2 = in_sizes[13] / 2;
    const int n1 = in_sizes[14];
    const int n2 = in_sizes[15];
    const int G  = 8;
    const int OUT = out_size / G;

    const int nmax = (N > n1) ? N : n1;

    auto rnd = [](size_t b) { return (b + 255) & ~(size_t)255; };
    size_t cntB  = rnd((size_t)N * 4);
    size_t ustB  = rnd((size_t)N * 4);
    size_t uenB  = rnd((size_t)N * 4);
    size_t rs2B  = rnd((size_t)n1 * 4);
    size_t re2B  = rnd((size_t)n1 * 4);
    size_t mc1B  = rnd((size_t)n1 * 4);
    size_t mc2B  = rnd((size_t)n2 * 4);
    size_t smlB  = rnd((512 + 8) * 4);
    size_t offB  = rnd((size_t)N * 4);
    size_t curB  = rnd((size_t)N * 4);
    size_t csrB  = rnd((size_t)(E1 / 2 + 64) * 4);
    size_t dinvB = rnd((size_t)nmax * 4);
    size_t blkB  = rnd((size_t)1024 * 4);
    size_t mem1B = rnd((size_t)n1 * 2 * 4);
    size_t mem2B = rnd((size_t)n2 * 2 * 4);
    size_t hpB   = rnd((size_t)n1 * 32 * 4);

    char* base = (char*)d_ws;
    char* p = base;
    int*   cntS   = (int*)p;           p += cntB;
    int*   ust    = (int*)p;           p += ustB;
    int*   uen    = (int*)p;           p += uenB;
    int*   rs2    = (int*)p;           p += rs2B;
    int*   re2    = (int*)p;           p += re2B;
    int*   mcnt1  = (int*)p;           p += mc1B;
    int*   mcnt2  = (int*)p;           p += mc2B;
    float* gsum   = (float*)p;         p += smlB;
    float* gcnt   = gsum + 512;
    size_t zeroB  = (size_t)(p - base);
    int*   offsS  = (int*)p;           p += offB;
    int*   cursorS= (int*)p;           p += curB;
    int*   csrS   = (int*)p;           p += csrB;
    float* dinv   = (float*)p;         p += dinvB;
    int*   blksum = (int*)p;           p += blkB;
    int*   mem1   = (int*)p;           p += mem1B;
    int*   mem2   = (int*)p;           p += mem2B;
    float* hp     = (float*)p;         p += hpB;
    float* hbuf   = (float*)p;         // phases: y1 (N*16) -> h1 (N*32) -> y2 (n1*32) -> h2 (n1*64)
    (void)ws_size;

    float* y1 = hbuf;
    float* h1 = hbuf;
    float* y2 = hbuf;
    float* h2 = hbuf;

    dim3 B(256);
    {
        long n4 = (long)(zeroB / 16);
        int g = idiv((int)((n4 < 1048576) ? n4 : 1048576), 256);
        if (g < 1) g = 1;
        if (g > 4096) g = 4096;
        k_zero<<<g, B, 0, stream>>>((float4*)base, n4);
    }

    // ---- layer 1 ----
    {
        int nblk = idiv(N, 1024);
        int maxEN = (E1 > N) ? E1 : N;
        k_prep1m<<<idiv(maxEN, 1024), B, 0, stream>>>(ei1, ei1 + E1, ust, uen, cntS,
                                                      cl1, mcnt1, mem1, E1, N);
        k_scan_blk<<<nblk, B, 0, stream>>>(cntS, offsS, blksum, N);
        k_scan_add_dinv_y<<<idiv(N, 256), B, 0, stream>>>(offsS, cursorS, blksum, cntS, ust, uen,
                                                          dinv, x, y1, N, nblk);
        k_fillS<<<idiv(E1, 256), B, 0, stream>>>(ei1, ei1 + E1, cursorS, csrS, E1);
        k_gc1<<<idiv(N * 4, 256), B, 0, stream>>>(ust, uen, ei1 + E1, offsS, cntS, csrS,
                                                  dinv, y1, x, W0a, W1a, b1, h1, N);
    }

    // ---- layer 2 ----
    {
        int e4 = idiv(E2, 4);
        int maxT = (e4 > n1 * 8) ? e4 : n1 * 8;
        k_bounds2mp<<<idiv(maxT, 256), B, 0, stream>>>(ei2, rs2, re2, cl2, mcnt2, mem2,
                                                       mcnt1, mem1, h1, hp, E2, n1);
        k_dinv2y<<<idiv(n1, 256), B, 0, stream>>>(rs2, re2, dinv, hp, y2, n1);
        k_gc2<<<idiv(n1 * 8, 256), B, 0, stream>>>(rs2, re2, ei2 + E2, dinv, y2, hp,
                                                   W0b, W1b, b2, h2, n1);
    }

    // ---- readout ----
    int gb = idiv(n2 * 16, 256);
    if (gb > 256) gb = 256;
    k_gsum2<<<gb, B, 0, stream>>>(h2, mcnt2, mem2, b3, gsum, gcnt, n2);
    k_fc12<<<idiv(OUT, 256), B, 0, stream>>>(gsum, gcnt, fcw1, fcb1, fcw2, fcb2,
                                             (float*)d_out, OUT);
}